// Round 3
// baseline (435.978 us; speedup 1.0000x reference)
//
#include <hip/hip_runtime.h>

typedef unsigned short u16;
typedef unsigned int u32;
typedef __attribute__((ext_vector_type(8))) short short8;
typedef __attribute__((ext_vector_type(4))) float floatx4;

#define P_PAIRS 160000
#define N_ATOMS 10000

#define OFF_WMLP  0      // stored TRANSPOSED: [50][64], (o,k) at o*64+k
#define OFF_BMLP  3200
#define OFF_WE1   3250
#define OFF_BE1   6930
#define OFF_WE2   6962
#define OFF_BE2   7986
#define OFF_WATT  8018
#define OFF_BATT  8242
#define OFF_WN1   8249
#define OFF_BN1   17465
#define OFF_WN2   17497
#define OFF_BN2   18521
#define OFF_WP1   18553
#define OFF_BP1   25721
#define OFF_WP2   25753
#define OFF_BP2   26777
#define OFF_WV1   26809
#define OFF_BV1   27833
#define OFF_WV2   27865
#define OFF_WVMIX 27897
#define WF_TOTAL  28121

__device__ __forceinline__ float b2f(u16 u){ return __uint_as_float(((u32)u) << 16); }
__device__ __forceinline__ u16 f2b(float f){
  u32 u = __float_as_uint(f);
  u32 r = (u + 0x7FFFu + ((u >> 16) & 1u)) >> 16;
  return (u16)r;
}
__device__ __forceinline__ float siluf(float v){ return v / (1.f + __expf(-v)); }
__device__ __forceinline__ float ldw(const void* p, int o, int bf){
  return bf ? b2f(((const u16*)p)[o]) : ((const float*)p)[o];
}

__global__ void k_code(float* out, float code){
  if (threadIdx.x == 0 && blockIdx.x == 0) out[0] = code;
}

// ---------------- dtype detection ----------------
__global__ void k_detect(const u32* __restrict__ hw, const u32* __restrict__ plw,
                         int* __restrict__ flags){
  if (threadIdx.x == 0 && blockIdx.x == 0){
    int bf = 0;
    for (int k = 0; k < 64; ++k){
      u32 e = (hw[k] >> 7) & 0xFFu;
      if (e >= 100u && e <= 140u) bf++;
    }
    flags[0] = (bf >= 48) ? 1 : 0;
    int z = 0;
    for (int k = 0; k < 64; ++k) if (plw[2*k+1] == 0u) z++;
    flags[1] = (z >= 60) ? 1 : 0;
  }
}

// ---------------- input normalization ----------------
__global__ void k_norm(const void* __restrict__ h_raw, const void* __restrict__ x_raw,
                       const void* __restrict__ v_raw, const void* __restrict__ pl_raw,
                       const int* __restrict__ flags, float* __restrict__ hf,
                       float* __restrict__ xf, float* __restrict__ vf, int* __restrict__ pli){
  int t = blockIdx.x * 256 + threadIdx.x;
  int bf = flags[0], i64 = flags[1];
  if (t < 320000){
    hf[t] = ldw(h_raw, t, bf);
  } else if (t < 350000){
    int i = t - 320000;
    xf[i] = ldw(x_raw, i, bf);
  } else if (t < 380000){
    int i = t - 350000;
    vf[i] = ldw(v_raw, i, bf);
  } else if (t < 700000){
    int k = t - 380000;
    const int* p32 = (const int*)pl_raw;
    pli[k] = i64 ? p32[2*(size_t)k] : p32[k];
  }
}

// ---------------- weight conversion -> fp32 (WMLP stored transposed) --------
__global__ void k_convert(const void* w_mlp, const void* b_mlp, const void* w_e1, const void* b_e1,
  const void* w_e2, const void* b_e2, const void* w_att, const void* b_att,
  const void* w_n1, const void* b_n1, const void* w_n2, const void* b_n2,
  const void* w_p1, const void* b_p1, const void* w_p2, const void* b_p2,
  const void* w_v1, const void* b_v1, const void* w_v2, const void* w_vmix,
  const int* __restrict__ flags, float* __restrict__ Wf){
  int t = blockIdx.x * 256 + threadIdx.x;
  if (t >= WF_TOTAL) return;
  int bf = flags[0];
  if (t < 3200){
    int k = t / 50, o = t - k * 50;           // src (k,o) row-major [64][50]
    Wf[OFF_WMLP + o * 64 + k] = ldw(w_mlp, t, bf);
    return;
  }
  const void* src; int o;
  if      (t < 3250)  { src = b_mlp;  o = t - 3200; }
  else if (t < 6930)  { src = w_e1;   o = t - 3250; }
  else if (t < 6962)  { src = b_e1;   o = t - 6930; }
  else if (t < 7986)  { src = w_e2;   o = t - 6962; }
  else if (t < 8018)  { src = b_e2;   o = t - 7986; }
  else if (t < 8242)  { src = w_att;  o = t - 8018; }
  else if (t < 8249)  { src = b_att;  o = t - 8242; }
  else if (t < 17465) { src = w_n1;   o = t - 8249; }
  else if (t < 17497) { src = b_n1;   o = t - 17465; }
  else if (t < 18521) { src = w_n2;   o = t - 17497; }
  else if (t < 18553) { src = b_n2;   o = t - 18521; }
  else if (t < 25721) { src = w_p1;   o = t - 18553; }
  else if (t < 25753) { src = b_p1;   o = t - 25721; }
  else if (t < 26777) { src = w_p2;   o = t - 25753; }
  else if (t < 26809) { src = b_p2;   o = t - 26777; }
  else if (t < 27833) { src = w_v1;   o = t - 26809; }
  else if (t < 27865) { src = b_v1;   o = t - 27833; }
  else if (t < 27897) { src = w_v2;   o = t - 27865; }
  else                { src = w_vmix; o = t - 27897; }
  Wf[t] = ldw(src, o, bf);
}

// wT[n][k] = w_xmix[k][n] as bf16 (B^T operand for MFMA)
__global__ void k_transpose(const void* __restrict__ wx, const int* __restrict__ flags,
                            u16* __restrict__ wT){
  int t = blockIdx.x * 256 + threadIdx.x;
  if (t >= 224 * 224) return;
  int n = t / 224, k = t - n * 224;
  wT[t] = f2b(ldw(wx, k * 224 + n, flags[0]));
}

// ---------------- per-atom projections (factorized edge model) --------------
__global__ void k_atompre(const float* __restrict__ h, const float* __restrict__ Wf,
                          float* __restrict__ prei, float* __restrict__ prej){
  int a = blockIdx.x;
  int r = threadIdx.x;
  __shared__ float hs[32];
  if (r < 32) hs[r] = h[(size_t)a * 32 + r];
  __syncthreads();
  if (r < 50){
    const float* wm = Wf + OFF_WMLP + r * 64;
    float acc = Wf[OFF_BMLP + r];
    #pragma unroll
    for (int k = 0; k < 32; ++k) acc += hs[k] * wm[k];
    prei[(size_t)a * 84 + r] = acc;
  } else if (r < 100){
    int kk = r - 50;
    const float* wm = Wf + OFF_WMLP + kk * 64 + 32;
    float acc = 0.f;
    #pragma unroll
    for (int k = 0; k < 32; ++k) acc += hs[k] * wm[k];
    prej[(size_t)a * 84 + kk] = acc;
  } else if (r < 132){
    int o = r - 100;
    float acc = Wf[OFF_BE1 + o];
    #pragma unroll
    for (int k = 0; k < 32; ++k) acc += hs[k] * Wf[OFF_WE1 + k * 32 + o];
    prei[(size_t)a * 84 + 52 + o] = acc;
  } else if (r < 164){
    int o = r - 132;
    float acc = 0.f;
    #pragma unroll
    for (int k = 0; k < 32; ++k) acc += hs[k] * Wf[OFF_WE1 + (32 + k) * 32 + o];
    prej[(size_t)a * 84 + 52 + o] = acc;
  }
}

// ---------------- counting sort ----------------
__global__ void k_hist(const int* __restrict__ pl, int* __restrict__ counts){
  int p = blockIdx.x * 256 + threadIdx.x;
  atomicAdd(&counts[pl[p]], 1);
}

__global__ void k_scan(const int* __restrict__ counts, int* __restrict__ offs, int* __restrict__ cursor){
  __shared__ int part[256];
  int t = threadIdx.x;
  int sum = 0;
  for (int k = 0; k < 40; ++k){
    int idx = t * 40 + k;
    if (idx < N_ATOMS) sum += counts[idx];
  }
  part[t] = sum;
  __syncthreads();
  if (t == 0){
    int run = 0;
    for (int q = 0; q < 256; ++q){ int tmp = part[q]; part[q] = run; run += tmp; }
  }
  __syncthreads();
  int run = part[t];
  for (int k = 0; k < 40; ++k){
    int idx = t * 40 + k;
    if (idx < N_ATOMS){ offs[idx] = run; cursor[idx] = run; run += counts[idx]; }
  }
  if (t == 0) offs[N_ATOMS] = P_PAIRS;
}

__global__ void k_scatter(const int* __restrict__ pl, int* __restrict__ cursor,
                          int* __restrict__ perm, int* __restrict__ aid){
  int p = blockIdx.x * 256 + threadIdx.x;
  int i = pl[p];
  int pos = atomicAdd(&cursor[i], 1);
  perm[pos] = p;
  aid[pos] = i;
}

// ------- per-pair edge model (factorized: per-atom projections gathered) ----
__global__ __launch_bounds__(256, 1) void k_pair(const float* __restrict__ x,
    const int* __restrict__ pl, const int* __restrict__ perm, const float* __restrict__ Wf,
    const float* __restrict__ prei, const float* __restrict__ prej,
    u16* __restrict__ edge, float* __restrict__ logits, float* __restrict__ dirs){
  int tid = threadIdx.x;
  int s = blockIdx.x * 256 + tid;            // sorted slot
  int p = perm[s];
  int i = pl[p], j = pl[P_PAIRS + p];
  float r0 = x[j*3+0] - x[i*3+0];
  float r1 = x[j*3+1] - x[i*3+1];
  float r2 = x[j*3+2] - x[i*3+2];
  float d = sqrtf(r0*r0 + r1*r1 + r2*r2);
  float rinv = 1.f / (d + 1e-5f);
  dirs[s*3+0] = r0*rinv; dirs[s*3+1] = r1*rinv; dirs[s*3+2] = r2*rinv;

  const float4* pi4 = (const float4*)(prei + (size_t)i * 84);
  const float4* pj4 = (const float4*)(prej + (size_t)j * 84);

  // tb[kk] = b_mlp[kk] + h_i@Wtop[kk] + h_j@Wbot[kk]   (filt dots, pre-summed)
  float tb[52];
  #pragma unroll
  for (int q = 0; q < 13; ++q){
    float4 aa = pi4[q], bb = pj4[q];
    tb[q*4+0] = aa.x + bb.x; tb[q*4+1] = aa.y + bb.y;
    tb[q*4+2] = aa.z + bb.z; tb[q*4+3] = aa.w + bb.w;
  }
  // u[o] = b_e1[o] + h_cat @ WE1[0:64] (pre-summed) ...
  float u[32];
  #pragma unroll
  for (int q = 0; q < 8; ++q){
    float4 aa = pi4[13+q], bb = pj4[13+q];
    u[q*4+0] = aa.x + bb.x; u[q*4+1] = aa.y + bb.y;
    u[q*4+2] = aa.z + bb.z; u[q*4+3] = aa.w + bb.w;
  }
  // ... + d * WE1[114]
  {
    const float* wr = Wf + OFF_WE1 + 114 * 32;
    #pragma unroll
    for (int o = 0; o < 32; ++o) u[o] += d * wr[o];
  }
  // fused filt: per kk compute scalar filt from tb, accumulate into u
  for (int kk = 0; kk < 50; ++kk){
    float c = (float)kk * (5.0f / 49.0f);
    float dd = d - c;
    float filt = tb[kk] * __expf(-10.0f * dd * dd);
    const float* we = Wf + OFF_WE1 + (64 + kk) * 32;
    #pragma unroll
    for (int o = 0; o < 32; ++o) u[o] += filt * we[o];
  }
  #pragma unroll
  for (int o = 0; o < 32; ++o) u[o] = siluf(u[o]);
  // edge = u @ w_e2 + b
  float eg[32];
  #pragma unroll
  for (int o = 0; o < 32; ++o) eg[o] = Wf[OFF_BE2 + o];
  #pragma unroll
  for (int k = 0; k < 32; ++k){
    const float* wr = Wf + OFF_WE2 + k * 32;
    #pragma unroll
    for (int o = 0; o < 32; ++o) eg[o] += u[k] * wr[o];
  }
  {
    u32 st[16];
    #pragma unroll
    for (int o = 0; o < 16; ++o)
      st[o] = (u32)f2b(eg[2*o]) | ((u32)f2b(eg[2*o+1]) << 16);
    #pragma unroll
    for (int q = 0; q < 4; ++q){
      uint4 vv; vv.x = st[4*q]; vv.y = st[4*q+1]; vv.z = st[4*q+2]; vv.w = st[4*q+3];
      *(uint4*)(edge + (size_t)s * 32 + q * 8) = vv;
    }
  }
  float lg[7];
  #pragma unroll
  for (int o = 0; o < 7; ++o) lg[o] = Wf[OFF_BATT + o];
  #pragma unroll
  for (int k = 0; k < 32; ++k){
    const float* wr = Wf + OFF_WATT + k * 7;
    #pragma unroll
    for (int o = 0; o < 7; ++o) lg[o] += eg[k] * wr[o];
  }
  #pragma unroll
  for (int o = 0; o < 7; ++o){
    float vv = lg[o];
    float cl = vv > 0.f ? vv : 2.f * expm1f(0.5f * vv);
    logits[s*7+o] = cl;
  }
}

// -------- segment softmax + hsem accumulation (16-lane group per atom) ------
// hsem[a][c] = sum_s edge[s][c/7] * att[s][c%7]; lane L owns c = 14L..14L+13,
// so f = {2L, 2L+1} exactly -> one u32 edge load per pair, no gathers.
__global__ __launch_bounds__(256) void k_att(const int* __restrict__ offs,
    const float* __restrict__ logits, const u16* __restrict__ edge,
    float* __restrict__ atts, float* __restrict__ hsem){
  int a = blockIdx.x * 16 + (threadIdx.x >> 4);   // N = 625*16
  int lane = threadIdx.x & 15;
  int off = offs[a], end = offs[a+1];
  float m[7];
  #pragma unroll
  for (int hh = 0; hh < 7; ++hh) m[hh] = -1e30f;
  for (int s = off + lane; s < end; s += 16){
    #pragma unroll
    for (int hh = 0; hh < 7; ++hh) m[hh] = fmaxf(m[hh], logits[s*7+hh]);
  }
  #pragma unroll
  for (int hh = 0; hh < 7; ++hh){
    float v = m[hh];
    #pragma unroll
    for (int msk = 8; msk >= 1; msk >>= 1) v = fmaxf(v, __shfl_xor(v, msk));
    m[hh] = v;
  }
  float sm[7] = {0,0,0,0,0,0,0};
  for (int s = off + lane; s < end; s += 16){
    #pragma unroll
    for (int hh = 0; hh < 7; ++hh){
      float e = __expf(logits[s*7+hh] - m[hh]);
      sm[hh] += e;
      atts[s*7+hh] = e;
    }
  }
  #pragma unroll
  for (int hh = 0; hh < 7; ++hh){
    float v = sm[hh];
    #pragma unroll
    for (int msk = 8; msk >= 1; msk >>= 1) v += __shfl_xor(v, msk);
    sm[hh] = 1.f / v;
  }
  for (int s = off + lane; s < end; s += 16){
    #pragma unroll
    for (int hh = 0; hh < 7; ++hh) atts[s*7+hh] *= sm[hh];
  }
  __syncthreads();   // drain atts stores (vmcnt) so the re-reads below are safe
  float acc[14] = {0,0,0,0,0,0,0,0,0,0,0,0,0,0};
  for (int s = off; s < end; ++s){
    u32 ev = *(const u32*)(edge + (size_t)s * 32 + lane * 2);
    float e0 = b2f((u16)(ev & 0xFFFFu));
    float e1 = b2f((u16)(ev >> 16));
    const float* ap = atts + (size_t)s * 7;
    #pragma unroll
    for (int hh = 0; hh < 7; ++hh){
      float at = ap[hh];
      acc[hh]     += e0 * at;
      acc[7 + hh] += e1 * at;
    }
  }
  float* hp = hsem + (size_t)a * 224 + lane * 14;
  #pragma unroll
  for (int jj = 0; jj < 14; ++jj) hp[jj] = acc[jj];
}

// -------- MFMA GEMM -> tanh tile in LDS -> comb accumulation (no xmix) ------
// LDS: [xth 29696 | overlaps As 10240 + Bs 17920] [eL 8192] [aL 3584] [daL 2048]
#define G3_AS   0
#define G3_BS   10240
#define G3_EL   29696
#define G3_AL   37888
#define G3_DA   41472
#define G3_TOT  43520

__global__ __launch_bounds__(256) void k_gemm3(const u16* __restrict__ edge,
    const float* __restrict__ atts, const u16* __restrict__ BT,
    const float* __restrict__ dirs, const int* __restrict__ aid,
    float* __restrict__ comb){
  __shared__ __attribute__((aligned(16))) char smem[G3_TOT];
  u16*   As  = (u16*)(smem + G3_AS);
  u16*   Bs  = (u16*)(smem + G3_BS);
  u16*   xth = (u16*)smem;                 // [128][116] bf16, reuses As/Bs space
  u16*   eL  = (u16*)(smem + G3_EL);
  float* aL  = (float*)(smem + G3_AL);
  float4* daL = (float4*)(smem + G3_DA);   // {dir0,dir1,dir2,aid-as-bits}
  int tid = threadIdx.x;
  int wave = tid >> 6, lane = tid & 63, l15 = lane & 15, quad = lane >> 4;
  int row0 = blockIdx.x * 128;

  for (int e = tid; e < 896; e += 256) aL[e] = atts[(size_t)row0*7 + e];
  for (int e = tid; e < 512; e += 256){
    int r = e >> 2, q = e & 3;
    *(uint4*)(eL + r*32 + q*8) = *(const uint4*)(edge + (size_t)(row0 + r)*32 + q*8);
  }
  if (tid < 128){
    int s = row0 + tid;
    float4 t;
    t.x = dirs[s*3+0]; t.y = dirs[s*3+1]; t.z = dirs[s*3+2];
    t.w = __int_as_float(aid[s]);
    daL[tid] = t;
  }
  floatx4 acc[2][14];
  #pragma unroll
  for (int mt = 0; mt < 2; ++mt)
    #pragma unroll
    for (int nt = 0; nt < 14; ++nt)
      acc[mt][nt] = (floatx4){0.f, 0.f, 0.f, 0.f};
  __syncthreads();

  for (int kt = 0; kt < 7; ++kt){
    int kk = kt * 32;
    for (int e = tid; e < 896; e += 256){
      int r = e >> 2, q = e & 3;
      *(uint4*)(Bs + r*40 + q*8) = *(const uint4*)(BT + (size_t)r*224 + kk + q*8);
    }
    for (int e = tid; e < 2048; e += 256){
      int r = e >> 4, c2 = (e & 15) * 2;
      int kc = kk + c2;
      int f0 = kc / 7,  h0 = kc - f0 * 7;
      int kc1 = kc + 1;
      int f1 = kc1 / 7, h1 = kc1 - f1 * 7;
      float v0 = b2f(eL[r*32 + f0]) * aL[r*7 + h0];
      float v1 = b2f(eL[r*32 + f1]) * aL[r*7 + h1];
      ((u32*)As)[r*20 + (e & 15)] = (u32)f2b(v0) | ((u32)f2b(v1) << 16);
    }
    __syncthreads();
    short8 a0 = *(const short8*)(As + (wave*32 + l15)*40 + quad*8);
    short8 a1 = *(const short8*)(As + (wave*32 + 16 + l15)*40 + quad*8);
    #pragma unroll
    for (int nt = 0; nt < 14; ++nt){
      short8 b = *(const short8*)(Bs + (nt*16 + l15)*40 + quad*8);
      acc[0][nt] = __builtin_amdgcn_mfma_f32_16x16x32_bf16(a0, b, acc[0][nt], 0, 0, 0);
      acc[1][nt] = __builtin_amdgcn_mfma_f32_16x16x32_bf16(a1, b, acc[1][nt], 0, 0, 0);
    }
    __syncthreads();
  }
  // epilogue: two 112-column halves; tanh -> xth (LOCAL cols 0..111);
  // comb += dirs (x) xth per atom (GLOBAL channel c0 = half*112 + local)
  #pragma unroll
  for (int half = 0; half < 2; ++half){
    __syncthreads();
    #pragma unroll
    for (int mt = 0; mt < 2; ++mt)
      #pragma unroll
      for (int nt2 = 0; nt2 < 7; ++nt2)
        #pragma unroll
        for (int reg = 0; reg < 4; ++reg){
          int r = wave*32 + mt*16 + quad*4 + reg;
          int c = nt2*16 + l15;
          float vv = acc[mt][half*7 + nt2][reg];
          vv = fminf(fmaxf(vv, -15.f), 15.f);
          float e2 = __expf(2.f * vv);
          xth[r*116 + c] = f2b((e2 - 1.f) / (e2 + 1.f));
        }
    __syncthreads();
    if (lane < 56){
      int cl = lane * 2;               // local column in xth
      int c0 = half * 112 + cl;        // global channel for comb
      float a00=0.f,a01=0.f,a02=0.f,a10=0.f,a11=0.f,a12=0.f;
      int r = wave*32, rend = r + 32;
      int cur = __float_as_int(daL[r].w);
      for (; r < rend; ++r){
        float4 da = daL[r];
        int ar = __float_as_int(da.w);
        if (ar != cur){
          size_t cb = ((size_t)cur*3)*224 + c0;
          atomicAdd(&comb[cb],     a00); atomicAdd(&comb[cb+1],   a10);
          atomicAdd(&comb[cb+224], a01); atomicAdd(&comb[cb+225], a11);
          atomicAdd(&comb[cb+448], a02); atomicAdd(&comb[cb+449], a12);
          a00=a01=a02=a10=a11=a12=0.f;
          cur = ar;
        }
        u32 xv = *(const u32*)(xth + r*116 + cl);
        float x0 = b2f((u16)(xv & 0xFFFFu)), x1 = b2f((u16)(xv >> 16));
        a00 += da.x*x0; a01 += da.y*x0; a02 += da.z*x0;
        a10 += da.x*x1; a11 += da.y*x1; a12 += da.z*x1;
      }
      size_t cb = ((size_t)cur*3)*224 + c0;
      atomicAdd(&comb[cb],     a00); atomicAdd(&comb[cb+1],   a10);
      atomicAdd(&comb[cb+224], a01); atomicAdd(&comb[cb+225], a11);
      atomicAdd(&comb[cb+448], a02); atomicAdd(&comb[cb+449], a12);
    }
  }
}

// ---------------- final: wave per atom, precomputed hsem/comb ----------------
__global__ __launch_bounds__(256) void k_final4(const float* __restrict__ h,
    const float* __restrict__ x, const float* __restrict__ v,
    const float* __restrict__ Wf, const int* __restrict__ offs,
    const float* __restrict__ hsem, const float* __restrict__ comb,
    float* __restrict__ out){
  __shared__ float s_in[4][288];     // [0:32)=h, [32:256)=hsem, [256:288)=sp
  __shared__ float s_nsq[4][224];
  __shared__ float s_u1[4][32], s_g[4][32], s_un[4][32];
  int wv_ = threadIdx.x >> 6, lane = threadIdx.x & 63;
  int a = blockIdx.x * 4 + wv_;                 // N = 2500*4
  int cnt = offs[a+1] - offs[a];
  float inv = 1.f / fmaxf((float)cnt, 1.f);
  float pv0 = 0.f, pv1 = 0.f, pv2 = 0.f;
  if (lane < 56){
    int c4 = lane * 4;
    float4 hs = *(const float4*)(hsem + (size_t)a*224 + c4);
    float4 cX = *(const float4*)(comb + ((size_t)a*3 + 0)*224 + c4);
    float4 cY = *(const float4*)(comb + ((size_t)a*3 + 1)*224 + c4);
    float4 cZ = *(const float4*)(comb + ((size_t)a*3 + 2)*224 + c4);
    float hx[4] = {hs.x, hs.y, hs.z, hs.w};
    float mx[4] = {cX.x*inv, cX.y*inv, cX.z*inv, cX.w*inv};
    float my[4] = {cY.x*inv, cY.y*inv, cY.z*inv, cY.w*inv};
    float mz[4] = {cZ.x*inv, cZ.y*inv, cZ.z*inv, cZ.w*inv};
    #pragma unroll
    for (int j = 0; j < 4; ++j){
      int c = c4 + j;
      s_nsq[wv_][c] = mx[j]*mx[j] + my[j]*my[j] + mz[j]*mz[j];
      s_in[wv_][32 + c] = hx[j];
      float wvx = Wf[OFF_WVMIX + c];
      pv0 += wvx*mx[j]; pv1 += wvx*my[j]; pv2 += wvx*mz[j];
    }
  } else {
    int k4 = (lane - 56) * 4;
    float4 hv = *(const float4*)(h + (size_t)a*32 + k4);
    s_in[wv_][k4+0] = hv.x; s_in[wv_][k4+1] = hv.y;
    s_in[wv_][k4+2] = hv.z; s_in[wv_][k4+3] = hv.w;
  }
  #pragma unroll
  for (int m = 32; m >= 1; m >>= 1){
    pv0 += __shfl_xor(pv0, m); pv1 += __shfl_xor(pv1, m); pv2 += __shfl_xor(pv2, m);
  }
  __syncthreads();
  int o = lane & 31, kh = lane >> 5;
  // p1 (K=224), K-split across wave halves
  {
    float u = 0.f;
    const float* q = &s_nsq[wv_][kh*112];
    const float* w = Wf + OFF_WP1 + (kh*112)*32 + o;
    #pragma unroll 4
    for (int kk = 0; kk < 112; ++kk) u += q[kk] * w[kk*32];
    u += __shfl_xor(u, 32);
    if (lane < 32) s_u1[wv_][o] = siluf(u + Wf[OFF_BP1 + o]);
  }
  // g = silu(h @ Wv1 + b), K=32 split 16/16
  {
    float g = 0.f;
    const float* q = &s_in[wv_][kh*16];
    const float* w = Wf + OFF_WV1 + (kh*16)*32 + o;
    #pragma unroll
    for (int kk = 0; kk < 16; ++kk) g += q[kk] * w[kk*32];
    g += __shfl_xor(g, 32);
    if (lane < 32) s_g[wv_][o] = siluf(g + Wf[OFF_BV1 + o]);
  }
  __syncthreads();
  float zpart = (lane < 32) ? s_g[wv_][lane] * Wf[OFF_WV2 + lane] : 0.f;
  #pragma unroll
  for (int m = 32; m >= 1; m >>= 1) zpart += __shfl_xor(zpart, m);
  float sc = 2.f / (1.f + __expf(-zpart));
  // p2 (K=32) split 16/16 -> s_in[256..288)
  {
    float u = 0.f;
    const float* q = &s_u1[wv_][kh*16];
    const float* w = Wf + OFF_WP2 + (kh*16)*32 + o;
    #pragma unroll
    for (int kk = 0; kk < 16; ++kk) u += q[kk] * w[kk*32];
    u += __shfl_xor(u, 32);
    if (lane < 32) s_in[wv_][256 + o] = siluf(u + Wf[OFF_BP2 + o]);
  }
  __syncthreads();
  // n1 (K=288) split 144/144, uniform via staged s_in
  {
    float u = 0.f;
    const float* q = &s_in[wv_][kh*144];
    const float* w = Wf + OFF_WN1 + (kh*144)*32 + o;
    #pragma unroll 4
    for (int kk = 0; kk < 144; ++kk) u += q[kk] * w[kk*32];
    u += __shfl_xor(u, 32);
    if (lane < 32) s_un[wv_][o] = siluf(u + Wf[OFF_BN1 + o]);
  }
  __syncthreads();
  if (lane < 32){
    float u = Wf[OFF_BN2 + lane];
    #pragma unroll
    for (int k = 0; k < 32; ++k) u += s_un[wv_][k] * Wf[OFF_WN2 + k*32 + lane];
    out[a*32 + lane] = s_in[wv_][lane] + siluf(u);
  }
  if (lane < 3){
    float vup = sc * v[a*3+lane] + ((lane == 0) ? pv0 : (lane == 1) ? pv1 : pv2);
    float xup = x[a*3+lane] + vup;
    out[N_ATOMS*32 + a*3 + lane] = xup;
    out[N_ATOMS*32 + N_ATOMS*3 + a*3 + lane] = vup;
  }
}

// ---------------- workspace layout ----------------
static constexpr size_t al256(size_t x){ return (x + 255) & ~(size_t)255; }
static constexpr size_t WS_FLAGS   = 0;
static constexpr size_t WS_COUNTS  = al256(WS_FLAGS + 8);
static constexpr size_t WS_OFFSETS = al256(WS_COUNTS + (size_t)N_ATOMS * 4);
static constexpr size_t WS_CURSOR  = al256(WS_OFFSETS + (size_t)(N_ATOMS + 1) * 4);
static constexpr size_t WS_PERM    = al256(WS_CURSOR + (size_t)N_ATOMS * 4);
static constexpr size_t WS_PLI     = al256(WS_PERM + (size_t)P_PAIRS * 4);
static constexpr size_t WS_HF      = al256(WS_PLI + (size_t)2 * P_PAIRS * 4);
static constexpr size_t WS_XF      = al256(WS_HF + (size_t)N_ATOMS * 32 * 4);
static constexpr size_t WS_VF      = al256(WS_XF + (size_t)N_ATOMS * 3 * 4);
static constexpr size_t WS_WF      = al256(WS_VF + (size_t)N_ATOMS * 3 * 4);
static constexpr size_t WS_WT      = al256(WS_WF + (size_t)WF_TOTAL * 4);
static constexpr size_t WS_EDGE    = al256(WS_WT + (size_t)224 * 224 * 2);
static constexpr size_t WS_ATTS    = al256(WS_EDGE + (size_t)P_PAIRS * 32 * 2);
static constexpr size_t WS_DIRS    = al256(WS_ATTS + (size_t)P_PAIRS * 7 * 4);
static constexpr size_t WS_LOGITS  = al256(WS_DIRS + (size_t)P_PAIRS * 3 * 4);
// shared region (old xmix space). Lifetimes (launch order) make aliases safe:
//   logits [0, 4.48M)            : written k_pair, read k_att
//   prei/prej [4.48M, 11.2M)     : written k_atompre, read k_pair (then dead)
//   hsem [4.48M, 13.44M)         : written k_att (after k_pair), read k_final4
//   comb [13.44M, 40.32M)        : memset at top, atomicAdd k_gemm3, read k_final4
//   aid  [40.32M, 40.96M)        : written k_scatter, read k_gemm3
static constexpr size_t WS_PREI    = al256(WS_LOGITS + (size_t)P_PAIRS * 7 * 4);
static constexpr size_t WS_PREJ    = al256(WS_PREI + (size_t)N_ATOMS * 84 * 4);
static constexpr size_t WS_HSEM    = WS_LOGITS + 4480000;
static constexpr size_t WS_COMB    = WS_HSEM + (size_t)N_ATOMS * 224 * 4;          // +8.96M
static constexpr size_t WS_AID     = WS_COMB + (size_t)N_ATOMS * 3 * 224 * 4;      // +26.88M
static constexpr size_t WS_END     = WS_AID + (size_t)P_PAIRS * 4;
static_assert(WS_PREJ + (size_t)N_ATOMS * 84 * 4 <= WS_COMB, "pre tables within hsem region only");
static_assert(WS_HSEM % 256 == 0 && WS_COMB % 256 == 0 && WS_AID % 256 == 0, "alignment");

extern "C" void kernel_launch(void* const* d_in, const int* in_sizes, int n_in,
                              void* d_out, int out_size, void* d_ws, size_t ws_size,
                              hipStream_t stream){
  (void)in_sizes; (void)n_in;
  if (out_size != 380000 || ws_size < WS_END){
    k_code<<<1, 64, 0, stream>>>((float*)d_out, 14000.f);
    return;
  }
  char* ws = (char*)d_ws;
  int*   flags  = (int*)(ws + WS_FLAGS);
  int*   counts = (int*)(ws + WS_COUNTS);
  int*   offs   = (int*)(ws + WS_OFFSETS);
  int*   cursor = (int*)(ws + WS_CURSOR);
  int*   perm   = (int*)(ws + WS_PERM);
  int*   pli    = (int*)(ws + WS_PLI);
  float* hf     = (float*)(ws + WS_HF);
  float* xf     = (float*)(ws + WS_XF);
  float* vf     = (float*)(ws + WS_VF);
  float* Wf     = (float*)(ws + WS_WF);
  u16*   wT     = (u16*)(ws + WS_WT);
  u16*   edge   = (u16*)(ws + WS_EDGE);
  float* atts   = (float*)(ws + WS_ATTS);
  float* dirs   = (float*)(ws + WS_DIRS);
  float* logits = (float*)(ws + WS_LOGITS);
  float* prei   = (float*)(ws + WS_PREI);
  float* prej   = (float*)(ws + WS_PREJ);
  float* hsem   = (float*)(ws + WS_HSEM);
  float* comb   = (float*)(ws + WS_COMB);
  int*   aid    = (int*)(ws + WS_AID);

  hipMemsetAsync(counts, 0, (size_t)N_ATOMS * 4, stream);
  hipMemsetAsync(comb, 0, (size_t)N_ATOMS * 3 * 224 * 4, stream);  // region untouched until k_gemm3
  k_detect<<<1, 64, 0, stream>>>((const u32*)d_in[0], (const u32*)d_in[3], flags);
  k_norm<<<(700000 + 255) / 256, 256, 0, stream>>>(d_in[0], d_in[1], d_in[2], d_in[3],
                                                   flags, hf, xf, vf, pli);
  k_convert<<<(WF_TOTAL + 255) / 256, 256, 0, stream>>>(
      d_in[4],  d_in[5],  d_in[6],  d_in[7],  d_in[8],  d_in[9],  d_in[10], d_in[11],
      d_in[12], d_in[13], d_in[14], d_in[15], d_in[16], d_in[17], d_in[18], d_in[19],
      d_in[20], d_in[21], d_in[22], d_in[24], flags, Wf);
  k_transpose<<<(224 * 224 + 255) / 256, 256, 0, stream>>>(d_in[23], flags, wT);
  k_atompre<<<N_ATOMS, 192, 0, stream>>>(hf, Wf, prei, prej);
  k_hist<<<P_PAIRS / 256, 256, 0, stream>>>(pli, counts);
  k_scan<<<1, 256, 0, stream>>>(counts, offs, cursor);
  k_scatter<<<P_PAIRS / 256, 256, 0, stream>>>(pli, cursor, perm, aid);
  k_pair<<<P_PAIRS / 256, 256, 0, stream>>>(xf, pli, perm, Wf, prei, prej, edge, logits, dirs);
  k_att<<<N_ATOMS / 16, 256, 0, stream>>>(offs, logits, edge, atts, hsem);
  k_gemm3<<<P_PAIRS / 128, 256, 0, stream>>>(edge, atts, wT, dirs, aid, comb);
  k_final4<<<N_ATOMS / 4, 256, 0, stream>>>(hf, xf, vf, Wf, offs, hsem, comb, (float*)d_out);
}

// Round 4
// 435.175 us; speedup vs baseline: 1.0018x; 1.0018x over previous
//
#include <hip/hip_runtime.h>

typedef unsigned short u16;
typedef unsigned int u32;
typedef __attribute__((ext_vector_type(8))) short short8;
typedef __attribute__((ext_vector_type(4))) float floatx4;

#define P_PAIRS 160000
#define N_ATOMS 10000

#define OFF_WMLP  0      // stored TRANSPOSED: [50][64], (o,k) at o*64+k
#define OFF_BMLP  3200
#define OFF_WE1   3250
#define OFF_BE1   6930
#define OFF_WE2   6962
#define OFF_BE2   7986
#define OFF_WATT  8018
#define OFF_BATT  8242
#define OFF_WN1   8249
#define OFF_BN1   17465
#define OFF_WN2   17497
#define OFF_BN2   18521
#define OFF_WP1   18553
#define OFF_BP1   25721
#define OFF_WP2   25753
#define OFF_BP2   26777
#define OFF_WV1   26809
#define OFF_BV1   27833
#define OFF_WV2   27865
#define OFF_WVMIX 27897
#define WF_TOTAL  28121

__device__ __forceinline__ float b2f(u16 u){ return __uint_as_float(((u32)u) << 16); }
__device__ __forceinline__ u16 f2b(float f){
  u32 u = __float_as_uint(f);
  u32 r = (u + 0x7FFFu + ((u >> 16) & 1u)) >> 16;
  return (u16)r;
}
__device__ __forceinline__ float siluf(float v){ return v / (1.f + __expf(-v)); }
__device__ __forceinline__ float ldw(const void* p, int o, int bf){
  return bf ? b2f(((const u16*)p)[o]) : ((const float*)p)[o];
}

__global__ void k_code(float* out, float code){
  if (threadIdx.x == 0 && blockIdx.x == 0) out[0] = code;
}

// ---------------- dtype detection ----------------
__global__ void k_detect(const u32* __restrict__ hw, const u32* __restrict__ plw,
                         int* __restrict__ flags){
  if (threadIdx.x == 0 && blockIdx.x == 0){
    int bf = 0;
    for (int k = 0; k < 64; ++k){
      u32 e = (hw[k] >> 7) & 0xFFu;
      if (e >= 100u && e <= 140u) bf++;
    }
    flags[0] = (bf >= 48) ? 1 : 0;
    int z = 0;
    for (int k = 0; k < 64; ++k) if (plw[2*k+1] == 0u) z++;
    flags[1] = (z >= 60) ? 1 : 0;
  }
}

// ---------------- input normalization ----------------
__global__ void k_norm(const void* __restrict__ h_raw, const void* __restrict__ x_raw,
                       const void* __restrict__ v_raw, const void* __restrict__ pl_raw,
                       const int* __restrict__ flags, float* __restrict__ hf,
                       float* __restrict__ xf, float* __restrict__ vf, int* __restrict__ pli){
  int t = blockIdx.x * 256 + threadIdx.x;
  int bf = flags[0], i64 = flags[1];
  if (t < 320000){
    hf[t] = ldw(h_raw, t, bf);
  } else if (t < 350000){
    int i = t - 320000;
    xf[i] = ldw(x_raw, i, bf);
  } else if (t < 380000){
    int i = t - 350000;
    vf[i] = ldw(v_raw, i, bf);
  } else if (t < 700000){
    int k = t - 380000;
    const int* p32 = (const int*)pl_raw;
    pli[k] = i64 ? p32[2*(size_t)k] : p32[k];
  }
}

// ---------------- weight conversion -> fp32 (WMLP stored transposed) --------
__global__ void k_convert(const void* w_mlp, const void* b_mlp, const void* w_e1, const void* b_e1,
  const void* w_e2, const void* b_e2, const void* w_att, const void* b_att,
  const void* w_n1, const void* b_n1, const void* w_n2, const void* b_n2,
  const void* w_p1, const void* b_p1, const void* w_p2, const void* b_p2,
  const void* w_v1, const void* b_v1, const void* w_v2, const void* w_vmix,
  const int* __restrict__ flags, float* __restrict__ Wf){
  int t = blockIdx.x * 256 + threadIdx.x;
  if (t >= WF_TOTAL) return;
  int bf = flags[0];
  if (t < 3200){
    int k = t / 50, o = t - k * 50;           // src (k,o) row-major [64][50]
    Wf[OFF_WMLP + o * 64 + k] = ldw(w_mlp, t, bf);
    return;
  }
  const void* src; int o;
  if      (t < 3250)  { src = b_mlp;  o = t - 3200; }
  else if (t < 6930)  { src = w_e1;   o = t - 3250; }
  else if (t < 6962)  { src = b_e1;   o = t - 6930; }
  else if (t < 7986)  { src = w_e2;   o = t - 6962; }
  else if (t < 8018)  { src = b_e2;   o = t - 7986; }
  else if (t < 8242)  { src = w_att;  o = t - 8018; }
  else if (t < 8249)  { src = b_att;  o = t - 8242; }
  else if (t < 17465) { src = w_n1;   o = t - 8249; }
  else if (t < 17497) { src = b_n1;   o = t - 17465; }
  else if (t < 18521) { src = w_n2;   o = t - 17497; }
  else if (t < 18553) { src = b_n2;   o = t - 18521; }
  else if (t < 25721) { src = w_p1;   o = t - 18553; }
  else if (t < 25753) { src = b_p1;   o = t - 25721; }
  else if (t < 26777) { src = w_p2;   o = t - 25753; }
  else if (t < 26809) { src = b_p2;   o = t - 26777; }
  else if (t < 27833) { src = w_v1;   o = t - 26809; }
  else if (t < 27865) { src = b_v1;   o = t - 27833; }
  else if (t < 27897) { src = w_v2;   o = t - 27865; }
  else                { src = w_vmix; o = t - 27897; }
  Wf[t] = ldw(src, o, bf);
}

// wT[n][k] = w_xmix[k][n] as bf16 (B^T operand for MFMA)
__global__ void k_transpose(const void* __restrict__ wx, const int* __restrict__ flags,
                            u16* __restrict__ wT){
  int t = blockIdx.x * 256 + threadIdx.x;
  if (t >= 224 * 224) return;
  int n = t / 224, k = t - n * 224;
  wT[t] = f2b(ldw(wx, k * 224 + n, flags[0]));
}

// ---------------- per-atom projections (factorized edge model) --------------
__global__ void k_atompre(const float* __restrict__ h, const float* __restrict__ Wf,
                          float* __restrict__ prei, float* __restrict__ prej){
  int a = blockIdx.x;
  int r = threadIdx.x;
  __shared__ float hs[32];
  if (r < 32) hs[r] = h[(size_t)a * 32 + r];
  __syncthreads();
  if (r < 50){
    const float* wm = Wf + OFF_WMLP + r * 64;
    float acc = Wf[OFF_BMLP + r];
    #pragma unroll
    for (int k = 0; k < 32; ++k) acc += hs[k] * wm[k];
    prei[(size_t)a * 84 + r] = acc;
  } else if (r < 100){
    int kk = r - 50;
    const float* wm = Wf + OFF_WMLP + kk * 64 + 32;
    float acc = 0.f;
    #pragma unroll
    for (int k = 0; k < 32; ++k) acc += hs[k] * wm[k];
    prej[(size_t)a * 84 + kk] = acc;
  } else if (r < 132){
    int o = r - 100;
    float acc = Wf[OFF_BE1 + o];
    #pragma unroll
    for (int k = 0; k < 32; ++k) acc += hs[k] * Wf[OFF_WE1 + k * 32 + o];
    prei[(size_t)a * 84 + 52 + o] = acc;
  } else if (r < 164){
    int o = r - 132;
    float acc = 0.f;
    #pragma unroll
    for (int k = 0; k < 32; ++k) acc += hs[k] * Wf[OFF_WE1 + (32 + k) * 32 + o];
    prej[(size_t)a * 84 + 52 + o] = acc;
  }
}

// ---------------- counting sort ----------------
__global__ void k_hist(const int* __restrict__ pl, int* __restrict__ counts){
  int p = blockIdx.x * 256 + threadIdx.x;
  atomicAdd(&counts[pl[p]], 1);
}

__global__ void k_scan(const int* __restrict__ counts, int* __restrict__ offs, int* __restrict__ cursor){
  __shared__ int part[256];
  int t = threadIdx.x;
  int sum = 0;
  for (int k = 0; k < 40; ++k){
    int idx = t * 40 + k;
    if (idx < N_ATOMS) sum += counts[idx];
  }
  part[t] = sum;
  __syncthreads();
  if (t == 0){
    int run = 0;
    for (int q = 0; q < 256; ++q){ int tmp = part[q]; part[q] = run; run += tmp; }
  }
  __syncthreads();
  int run = part[t];
  for (int k = 0; k < 40; ++k){
    int idx = t * 40 + k;
    if (idx < N_ATOMS){ offs[idx] = run; cursor[idx] = run; run += counts[idx]; }
  }
  if (t == 0) offs[N_ATOMS] = P_PAIRS;
}

__global__ void k_scatter(const int* __restrict__ pl, int* __restrict__ cursor,
                          int* __restrict__ perm, int* __restrict__ aid){
  int p = blockIdx.x * 256 + threadIdx.x;
  int i = pl[p];
  int pos = atomicAdd(&cursor[i], 1);
  perm[pos] = p;
  aid[pos] = i;
}

// ------- per-pair edge model (factorized: per-atom projections gathered) ----
__global__ __launch_bounds__(256, 1) void k_pair(const float* __restrict__ x,
    const int* __restrict__ pl, const int* __restrict__ perm, const float* __restrict__ Wf,
    const float* __restrict__ prei, const float* __restrict__ prej,
    u16* __restrict__ edge, float* __restrict__ logits, float* __restrict__ dirs){
  int tid = threadIdx.x;
  int s = blockIdx.x * 256 + tid;            // sorted slot
  int p = perm[s];
  int i = pl[p], j = pl[P_PAIRS + p];
  float r0 = x[j*3+0] - x[i*3+0];
  float r1 = x[j*3+1] - x[i*3+1];
  float r2 = x[j*3+2] - x[i*3+2];
  float d = sqrtf(r0*r0 + r1*r1 + r2*r2);
  float rinv = 1.f / (d + 1e-5f);
  dirs[s*3+0] = r0*rinv; dirs[s*3+1] = r1*rinv; dirs[s*3+2] = r2*rinv;

  const float4* pi4 = (const float4*)(prei + (size_t)i * 84);
  const float4* pj4 = (const float4*)(prej + (size_t)j * 84);

  // tb[kk] = b_mlp[kk] + h_i@Wtop[kk] + h_j@Wbot[kk]   (filt dots, pre-summed)
  float tb[52];
  #pragma unroll
  for (int q = 0; q < 13; ++q){
    float4 aa = pi4[q], bb = pj4[q];
    tb[q*4+0] = aa.x + bb.x; tb[q*4+1] = aa.y + bb.y;
    tb[q*4+2] = aa.z + bb.z; tb[q*4+3] = aa.w + bb.w;
  }
  // u[o] = b_e1[o] + h_cat @ WE1[0:64] (pre-summed) ...
  float u[32];
  #pragma unroll
  for (int q = 0; q < 8; ++q){
    float4 aa = pi4[13+q], bb = pj4[13+q];
    u[q*4+0] = aa.x + bb.x; u[q*4+1] = aa.y + bb.y;
    u[q*4+2] = aa.z + bb.z; u[q*4+3] = aa.w + bb.w;
  }
  // ... + d * WE1[114]
  {
    const float* wr = Wf + OFF_WE1 + 114 * 32;
    #pragma unroll
    for (int o = 0; o < 32; ++o) u[o] += d * wr[o];
  }
  // fused filt: per kk compute scalar filt from tb, accumulate into u
  for (int kk = 0; kk < 50; ++kk){
    float c = (float)kk * (5.0f / 49.0f);
    float dd = d - c;
    float filt = tb[kk] * __expf(-10.0f * dd * dd);
    const float* we = Wf + OFF_WE1 + (64 + kk) * 32;
    #pragma unroll
    for (int o = 0; o < 32; ++o) u[o] += filt * we[o];
  }
  #pragma unroll
  for (int o = 0; o < 32; ++o) u[o] = siluf(u[o]);
  // edge = u @ w_e2 + b
  float eg[32];
  #pragma unroll
  for (int o = 0; o < 32; ++o) eg[o] = Wf[OFF_BE2 + o];
  #pragma unroll
  for (int k = 0; k < 32; ++k){
    const float* wr = Wf + OFF_WE2 + k * 32;
    #pragma unroll
    for (int o = 0; o < 32; ++o) eg[o] += u[k] * wr[o];
  }
  {
    u32 st[16];
    #pragma unroll
    for (int o = 0; o < 16; ++o)
      st[o] = (u32)f2b(eg[2*o]) | ((u32)f2b(eg[2*o+1]) << 16);
    #pragma unroll
    for (int q = 0; q < 4; ++q){
      uint4 vv; vv.x = st[4*q]; vv.y = st[4*q+1]; vv.z = st[4*q+2]; vv.w = st[4*q+3];
      *(uint4*)(edge + (size_t)s * 32 + q * 8) = vv;
    }
  }
  float lg[7];
  #pragma unroll
  for (int o = 0; o < 7; ++o) lg[o] = Wf[OFF_BATT + o];
  #pragma unroll
  for (int k = 0; k < 32; ++k){
    const float* wr = Wf + OFF_WATT + k * 7;
    #pragma unroll
    for (int o = 0; o < 7; ++o) lg[o] += eg[k] * wr[o];
  }
  #pragma unroll
  for (int o = 0; o < 7; ++o){
    float vv = lg[o];
    float cl = vv > 0.f ? vv : 2.f * expm1f(0.5f * vv);
    logits[s*7+o] = cl;
  }
}

// -------- segment softmax + hsem accumulation (16-lane group per atom) ------
__global__ __launch_bounds__(256) void k_att(const int* __restrict__ offs,
    const float* __restrict__ logits, const u16* __restrict__ edge,
    float* __restrict__ atts, float* __restrict__ hsem){
  int a = blockIdx.x * 16 + (threadIdx.x >> 4);   // N = 625*16
  int lane = threadIdx.x & 15;
  int off = offs[a], end = offs[a+1];
  float m[7];
  #pragma unroll
  for (int hh = 0; hh < 7; ++hh) m[hh] = -1e30f;
  for (int s = off + lane; s < end; s += 16){
    #pragma unroll
    for (int hh = 0; hh < 7; ++hh) m[hh] = fmaxf(m[hh], logits[s*7+hh]);
  }
  #pragma unroll
  for (int hh = 0; hh < 7; ++hh){
    float v = m[hh];
    #pragma unroll
    for (int msk = 8; msk >= 1; msk >>= 1) v = fmaxf(v, __shfl_xor(v, msk));
    m[hh] = v;
  }
  float sm[7] = {0,0,0,0,0,0,0};
  for (int s = off + lane; s < end; s += 16){
    #pragma unroll
    for (int hh = 0; hh < 7; ++hh){
      float e = __expf(logits[s*7+hh] - m[hh]);
      sm[hh] += e;
      atts[s*7+hh] = e;
    }
  }
  #pragma unroll
  for (int hh = 0; hh < 7; ++hh){
    float v = sm[hh];
    #pragma unroll
    for (int msk = 8; msk >= 1; msk >>= 1) v += __shfl_xor(v, msk);
    sm[hh] = 1.f / v;
  }
  for (int s = off + lane; s < end; s += 16){
    #pragma unroll
    for (int hh = 0; hh < 7; ++hh) atts[s*7+hh] *= sm[hh];
  }
  __syncthreads();   // drain atts stores (vmcnt) so the re-reads below are safe
  float acc[14] = {0,0,0,0,0,0,0,0,0,0,0,0,0,0};
  for (int s = off; s < end; ++s){
    u32 ev = *(const u32*)(edge + (size_t)s * 32 + lane * 2);
    float e0 = b2f((u16)(ev & 0xFFFFu));
    float e1 = b2f((u16)(ev >> 16));
    const float* ap = atts + (size_t)s * 7;
    #pragma unroll
    for (int hh = 0; hh < 7; ++hh){
      float at = ap[hh];
      acc[hh]     += e0 * at;
      acc[7 + hh] += e1 * at;
    }
  }
  float* hp = hsem + (size_t)a * 224 + lane * 14;
  #pragma unroll
  for (int jj = 0; jj < 14; ++jj) hp[jj] = acc[jj];
}

// -------- MFMA GEMM: pack-once A, kt loop = stage+MFMA only, in-place tanh --
// LDS: As [128][232]u16 = 59392 (doubles as xth after MFMA)
//      Bs [224][40]u16  = 17920 at 59392 (eL[128][36]u16 9216 + aL 3584 overlay)
//      daL 128*16       =  2048 at 77312        total 79360 -> 2 blocks/CU
#define G_BS   59392
#define G_AL   (59392 + 9216)
#define G_DA   77312
#define G_TOT  79360

__global__ __launch_bounds__(256) void k_gemm3(const u16* __restrict__ edge,
    const float* __restrict__ atts, const u16* __restrict__ BT,
    const float* __restrict__ dirs, const int* __restrict__ aid,
    float* __restrict__ comb){
  __shared__ __attribute__((aligned(16))) char smem[G_TOT];
  u16*   As  = (u16*)smem;                 // stride 232 u16
  u16*   xth = (u16*)smem;                 // in-place after MFMA
  u16*   Bs  = (u16*)(smem + G_BS);        // stride 40 u16
  u16*   eL  = (u16*)(smem + G_BS);        // stride 36 u16 (overlay, dead after pack)
  float* aL  = (float*)(smem + G_AL);      // stride 7 floats
  float4* daL = (float4*)(smem + G_DA);    // {dir0,dir1,dir2,aid-as-bits}
  int tid = threadIdx.x;
  int wave = tid >> 6, lane = tid & 63, l15 = lane & 15, quad = lane >> 4;
  int row0 = blockIdx.x * 128;

  // stage edge rows (padded stride 36) + atts + dirs/aid
  for (int e = tid; e < 1024; e += 256){
    int r = e >> 3, q = e & 7;
    *(uint2*)(eL + r*36 + q*4) = *(const uint2*)(edge + (size_t)(row0 + r)*32 + q*4);
  }
  for (int e = tid; e < 896; e += 256) aL[e] = atts[(size_t)row0*7 + e];
  if (tid < 128){
    int s = row0 + tid;
    float4 t;
    t.x = dirs[s*3+0]; t.y = dirs[s*3+1]; t.z = dirs[s*3+2];
    t.w = __int_as_float(aid[s]);
    daL[tid] = t;
  }
  floatx4 acc[2][14];
  #pragma unroll
  for (int mt = 0; mt < 2; ++mt)
    #pragma unroll
    for (int nt = 0; nt < 14; ++nt)
      acc[mt][nt] = (floatx4){0.f, 0.f, 0.f, 0.f};
  __syncthreads();

  // pack full A-tile once: thread t -> row t>>1, column half (t&1)*112
  {
    int pr = tid >> 1, pp = tid & 1;
    u32* asw = (u32*)As + pr*116 + pp*56;
    const u16* er = eL + pr*36 + pp*16;
    const float* ar = aL + pr*7;
    float av[7];
    #pragma unroll
    for (int hh = 0; hh < 7; ++hh) av[hh] = ar[hh];
    #pragma unroll
    for (int fo = 0; fo < 8; ++fo){
      float e0 = b2f(er[2*fo]);
      float e1 = b2f(er[2*fo+1]);
      u16 w[14];
      #pragma unroll
      for (int hh = 0; hh < 7; ++hh){
        w[hh]   = f2b(e0 * av[hh]);
        w[7+hh] = f2b(e1 * av[hh]);
      }
      #pragma unroll
      for (int k = 0; k < 7; ++k)
        asw[fo*7 + k] = (u32)w[2*k] | ((u32)w[2*k+1] << 16);
    }
  }
  __syncthreads();

  for (int kt = 0; kt < 7; ++kt){
    int kk = kt * 32;
    for (int e = tid; e < 896; e += 256){
      int r = e >> 2, q = e & 3;
      *(uint4*)(Bs + r*40 + q*8) = *(const uint4*)(BT + (size_t)r*224 + kk + q*8);
    }
    __syncthreads();
    short8 a0 = *(const short8*)(As + (wave*32 + l15)*232 + kk + quad*8);
    short8 a1 = *(const short8*)(As + (wave*32 + 16 + l15)*232 + kk + quad*8);
    #pragma unroll
    for (int nt = 0; nt < 14; ++nt){
      short8 b = *(const short8*)(Bs + (nt*16 + l15)*40 + quad*8);
      acc[0][nt] = __builtin_amdgcn_mfma_f32_16x16x32_bf16(a0, b, acc[0][nt], 0, 0, 0);
      acc[1][nt] = __builtin_amdgcn_mfma_f32_16x16x32_bf16(a1, b, acc[1][nt], 0, 0, 0);
    }
    __syncthreads();
  }

  // tanh epilogue, full width, in place over As
  #pragma unroll
  for (int mt = 0; mt < 2; ++mt)
    #pragma unroll
    for (int nt = 0; nt < 14; ++nt)
      #pragma unroll
      for (int reg = 0; reg < 4; ++reg){
        int r = wave*32 + mt*16 + quad*4 + reg;
        int c = nt*16 + l15;
        float vv = acc[mt][nt][reg];
        vv = fminf(fmaxf(vv, -15.f), 15.f);
        float e2 = __expf(2.f * vv);
        xth[r*232 + c] = f2b((e2 - 1.f) / (e2 + 1.f));
      }
  __syncthreads();

  // comb accumulation: run-length compressed atomics, both halves
  if (lane < 56){
    #pragma unroll
    for (int half = 0; half < 2; ++half){
      int cl = half * 112 + lane * 2;      // column in xth == global channel
      float a00=0.f,a01=0.f,a02=0.f,a10=0.f,a11=0.f,a12=0.f;
      int r = wave*32, rend = r + 32;
      int cur = __float_as_int(daL[r].w);
      for (; r < rend; ++r){
        float4 da = daL[r];
        int ar = __float_as_int(da.w);
        if (ar != cur){
          size_t cb = ((size_t)cur*3)*224 + cl;
          atomicAdd(&comb[cb],     a00); atomicAdd(&comb[cb+1],   a10);
          atomicAdd(&comb[cb+224], a01); atomicAdd(&comb[cb+225], a11);
          atomicAdd(&comb[cb+448], a02); atomicAdd(&comb[cb+449], a12);
          a00=a01=a02=a10=a11=a12=0.f;
          cur = ar;
        }
        u32 xv = *(const u32*)(xth + r*232 + cl);
        float x0 = b2f((u16)(xv & 0xFFFFu)), x1 = b2f((u16)(xv >> 16));
        a00 += da.x*x0; a01 += da.y*x0; a02 += da.z*x0;
        a10 += da.x*x1; a11 += da.y*x1; a12 += da.z*x1;
      }
      size_t cb = ((size_t)cur*3)*224 + cl;
      atomicAdd(&comb[cb],     a00); atomicAdd(&comb[cb+1],   a10);
      atomicAdd(&comb[cb+224], a01); atomicAdd(&comb[cb+225], a11);
      atomicAdd(&comb[cb+448], a02); atomicAdd(&comb[cb+449], a12);
    }
  }
}

// ---------------- final: wave per atom, precomputed hsem/comb ----------------
__global__ __launch_bounds__(256) void k_final4(const float* __restrict__ h,
    const float* __restrict__ x, const float* __restrict__ v,
    const float* __restrict__ Wf, const int* __restrict__ offs,
    const float* __restrict__ hsem, const float* __restrict__ comb,
    float* __restrict__ out){
  __shared__ float s_in[4][288];     // [0:32)=h, [32:256)=hsem, [256:288)=sp
  __shared__ float s_nsq[4][224];
  __shared__ float s_u1[4][32], s_g[4][32], s_un[4][32];
  int wv_ = threadIdx.x >> 6, lane = threadIdx.x & 63;
  int a = blockIdx.x * 4 + wv_;                 // N = 2500*4
  int cnt = offs[a+1] - offs[a];
  float inv = 1.f / fmaxf((float)cnt, 1.f);
  float pv0 = 0.f, pv1 = 0.f, pv2 = 0.f;
  if (lane < 56){
    int c4 = lane * 4;
    float4 hs = *(const float4*)(hsem + (size_t)a*224 + c4);
    float4 cX = *(const float4*)(comb + ((size_t)a*3 + 0)*224 + c4);
    float4 cY = *(const float4*)(comb + ((size_t)a*3 + 1)*224 + c4);
    float4 cZ = *(const float4*)(comb + ((size_t)a*3 + 2)*224 + c4);
    float hx[4] = {hs.x, hs.y, hs.z, hs.w};
    float mx[4] = {cX.x*inv, cX.y*inv, cX.z*inv, cX.w*inv};
    float my[4] = {cY.x*inv, cY.y*inv, cY.z*inv, cY.w*inv};
    float mz[4] = {cZ.x*inv, cZ.y*inv, cZ.z*inv, cZ.w*inv};
    #pragma unroll
    for (int j = 0; j < 4; ++j){
      int c = c4 + j;
      s_nsq[wv_][c] = mx[j]*mx[j] + my[j]*my[j] + mz[j]*mz[j];
      s_in[wv_][32 + c] = hx[j];
      float wvx = Wf[OFF_WVMIX + c];
      pv0 += wvx*mx[j]; pv1 += wvx*my[j]; pv2 += wvx*mz[j];
    }
  } else {
    int k4 = (lane - 56) * 4;
    float4 hv = *(const float4*)(h + (size_t)a*32 + k4);
    s_in[wv_][k4+0] = hv.x; s_in[wv_][k4+1] = hv.y;
    s_in[wv_][k4+2] = hv.z; s_in[wv_][k4+3] = hv.w;
  }
  #pragma unroll
  for (int m = 32; m >= 1; m >>= 1){
    pv0 += __shfl_xor(pv0, m); pv1 += __shfl_xor(pv1, m); pv2 += __shfl_xor(pv2, m);
  }
  __syncthreads();
  int o = lane & 31, kh = lane >> 5;
  // p1 (K=224), K-split across wave halves
  {
    float u = 0.f;
    const float* q = &s_nsq[wv_][kh*112];
    const float* w = Wf + OFF_WP1 + (kh*112)*32 + o;
    #pragma unroll 4
    for (int kk = 0; kk < 112; ++kk) u += q[kk] * w[kk*32];
    u += __shfl_xor(u, 32);
    if (lane < 32) s_u1[wv_][o] = siluf(u + Wf[OFF_BP1 + o]);
  }
  // g = silu(h @ Wv1 + b), K=32 split 16/16
  {
    float g = 0.f;
    const float* q = &s_in[wv_][kh*16];
    const float* w = Wf + OFF_WV1 + (kh*16)*32 + o;
    #pragma unroll
    for (int kk = 0; kk < 16; ++kk) g += q[kk] * w[kk*32];
    g += __shfl_xor(g, 32);
    if (lane < 32) s_g[wv_][o] = siluf(g + Wf[OFF_BV1 + o]);
  }
  __syncthreads();
  float zpart = (lane < 32) ? s_g[wv_][lane] * Wf[OFF_WV2 + lane] : 0.f;
  #pragma unroll
  for (int m = 32; m >= 1; m >>= 1) zpart += __shfl_xor(zpart, m);
  float sc = 2.f / (1.f + __expf(-zpart));
  // p2 (K=32) split 16/16 -> s_in[256..288)
  {
    float u = 0.f;
    const float* q = &s_u1[wv_][kh*16];
    const float* w = Wf + OFF_WP2 + (kh*16)*32 + o;
    #pragma unroll
    for (int kk = 0; kk < 16; ++kk) u += q[kk] * w[kk*32];
    u += __shfl_xor(u, 32);
    if (lane < 32) s_in[wv_][256 + o] = siluf(u + Wf[OFF_BP2 + o]);
  }
  __syncthreads();
  // n1 (K=288) split 144/144, uniform via staged s_in
  {
    float u = 0.f;
    const float* q = &s_in[wv_][kh*144];
    const float* w = Wf + OFF_WN1 + (kh*144)*32 + o;
    #pragma unroll 4
    for (int kk = 0; kk < 144; ++kk) u += q[kk] * w[kk*32];
    u += __shfl_xor(u, 32);
    if (lane < 32) s_un[wv_][o] = siluf(u + Wf[OFF_BN1 + o]);
  }
  __syncthreads();
  if (lane < 32){
    float u = Wf[OFF_BN2 + lane];
    #pragma unroll
    for (int k = 0; k < 32; ++k) u += s_un[wv_][k] * Wf[OFF_WN2 + k*32 + lane];
    out[a*32 + lane] = s_in[wv_][lane] + siluf(u);
  }
  if (lane < 3){
    float vup = sc * v[a*3+lane] + ((lane == 0) ? pv0 : (lane == 1) ? pv1 : pv2);
    float xup = x[a*3+lane] + vup;
    out[N_ATOMS*32 + a*3 + lane] = xup;
    out[N_ATOMS*32 + N_ATOMS*3 + a*3 + lane] = vup;
  }
}

// ---------------- workspace layout ----------------
static constexpr size_t al256(size_t x){ return (x + 255) & ~(size_t)255; }
static constexpr size_t WS_FLAGS   = 0;
static constexpr size_t WS_COUNTS  = al256(WS_FLAGS + 8);
static constexpr size_t WS_OFFSETS = al256(WS_COUNTS + (size_t)N_ATOMS * 4);
static constexpr size_t WS_CURSOR  = al256(WS_OFFSETS + (size_t)(N_ATOMS + 1) * 4);
static constexpr size_t WS_PERM    = al256(WS_CURSOR + (size_t)N_ATOMS * 4);
static constexpr size_t WS_PLI     = al256(WS_PERM + (size_t)P_PAIRS * 4);
static constexpr size_t WS_HF      = al256(WS_PLI + (size_t)2 * P_PAIRS * 4);
static constexpr size_t WS_XF      = al256(WS_HF + (size_t)N_ATOMS * 32 * 4);
static constexpr size_t WS_VF      = al256(WS_XF + (size_t)N_ATOMS * 3 * 4);
static constexpr size_t WS_WF      = al256(WS_VF + (size_t)N_ATOMS * 3 * 4);
static constexpr size_t WS_WT      = al256(WS_WF + (size_t)WF_TOTAL * 4);
static constexpr size_t WS_EDGE    = al256(WS_WT + (size_t)224 * 224 * 2);
static constexpr size_t WS_ATTS    = al256(WS_EDGE + (size_t)P_PAIRS * 32 * 2);
static constexpr size_t WS_DIRS    = al256(WS_ATTS + (size_t)P_PAIRS * 7 * 4);
static constexpr size_t WS_LOGITS  = al256(WS_DIRS + (size_t)P_PAIRS * 3 * 4);
// shared region (old xmix space). Lifetimes (launch order) make aliases safe:
//   logits [0, 4.48M)            : written k_pair, read k_att
//   prei/prej [4.48M, 11.2M)     : written k_atompre, read k_pair (then dead)
//   hsem [4.48M, 13.44M)         : written k_att (after k_pair), read k_final4
//   comb [13.44M, 40.32M)        : memset at top, atomicAdd k_gemm3, read k_final4
//   aid  [40.32M, 40.96M)        : written k_scatter, read k_gemm3
static constexpr size_t WS_PREI    = al256(WS_LOGITS + (size_t)P_PAIRS * 7 * 4);
static constexpr size_t WS_PREJ    = al256(WS_PREI + (size_t)N_ATOMS * 84 * 4);
static constexpr size_t WS_HSEM    = WS_LOGITS + 4480000;
static constexpr size_t WS_COMB    = WS_HSEM + (size_t)N_ATOMS * 224 * 4;          // +8.96M
static constexpr size_t WS_AID     = WS_COMB + (size_t)N_ATOMS * 3 * 224 * 4;      // +26.88M
static constexpr size_t WS_END     = WS_AID + (size_t)P_PAIRS * 4;
static_assert(WS_PREJ + (size_t)N_ATOMS * 84 * 4 <= WS_COMB, "pre tables within hsem region only");
static_assert(WS_HSEM % 256 == 0 && WS_COMB % 256 == 0 && WS_AID % 256 == 0, "alignment");

extern "C" void kernel_launch(void* const* d_in, const int* in_sizes, int n_in,
                              void* d_out, int out_size, void* d_ws, size_t ws_size,
                              hipStream_t stream){
  (void)in_sizes; (void)n_in;
  if (out_size != 380000 || ws_size < WS_END){
    k_code<<<1, 64, 0, stream>>>((float*)d_out, 14000.f);
    return;
  }
  char* ws = (char*)d_ws;
  int*   flags  = (int*)(ws + WS_FLAGS);
  int*   counts = (int*)(ws + WS_COUNTS);
  int*   offs   = (int*)(ws + WS_OFFSETS);
  int*   cursor = (int*)(ws + WS_CURSOR);
  int*   perm   = (int*)(ws + WS_PERM);
  int*   pli    = (int*)(ws + WS_PLI);
  float* hf     = (float*)(ws + WS_HF);
  float* xf     = (float*)(ws + WS_XF);
  float* vf     = (float*)(ws + WS_VF);
  float* Wf     = (float*)(ws + WS_WF);
  u16*   wT     = (u16*)(ws + WS_WT);
  u16*   edge   = (u16*)(ws + WS_EDGE);
  float* atts   = (float*)(ws + WS_ATTS);
  float* dirs   = (float*)(ws + WS_DIRS);
  float* logits = (float*)(ws + WS_LOGITS);
  float* prei   = (float*)(ws + WS_PREI);
  float* prej   = (float*)(ws + WS_PREJ);
  float* hsem   = (float*)(ws + WS_HSEM);
  float* comb   = (float*)(ws + WS_COMB);
  int*   aid    = (int*)(ws + WS_AID);

  hipMemsetAsync(counts, 0, (size_t)N_ATOMS * 4, stream);
  hipMemsetAsync(comb, 0, (size_t)N_ATOMS * 3 * 224 * 4, stream);  // region untouched until k_gemm3
  k_detect<<<1, 64, 0, stream>>>((const u32*)d_in[0], (const u32*)d_in[3], flags);
  k_norm<<<(700000 + 255) / 256, 256, 0, stream>>>(d_in[0], d_in[1], d_in[2], d_in[3],
                                                   flags, hf, xf, vf, pli);
  k_convert<<<(WF_TOTAL + 255) / 256, 256, 0, stream>>>(
      d_in[4],  d_in[5],  d_in[6],  d_in[7],  d_in[8],  d_in[9],  d_in[10], d_in[11],
      d_in[12], d_in[13], d_in[14], d_in[15], d_in[16], d_in[17], d_in[18], d_in[19],
      d_in[20], d_in[21], d_in[22], d_in[24], flags, Wf);
  k_transpose<<<(224 * 224 + 255) / 256, 256, 0, stream>>>(d_in[23], flags, wT);
  k_atompre<<<N_ATOMS, 192, 0, stream>>>(hf, Wf, prei, prej);
  k_hist<<<P_PAIRS / 256, 256, 0, stream>>>(pli, counts);
  k_scan<<<1, 256, 0, stream>>>(counts, offs, cursor);
  k_scatter<<<P_PAIRS / 256, 256, 0, stream>>>(pli, cursor, perm, aid);
  k_pair<<<P_PAIRS / 256, 256, 0, stream>>>(xf, pli, perm, Wf, prei, prej, edge, logits, dirs);
  k_att<<<N_ATOMS / 16, 256, 0, stream>>>(offs, logits, edge, atts, hsem);
  k_gemm3<<<P_PAIRS / 128, 256, 0, stream>>>(edge, atts, wT, dirs, aid, comb);
  k_final4<<<N_ATOMS / 4, 256, 0, stream>>>(hf, xf, vf, Wf, offs, hsem, comb, (float*)d_out);
}

// Round 5
// 432.598 us; speedup vs baseline: 1.0078x; 1.0060x over previous
//
#include <hip/hip_runtime.h>

typedef unsigned short u16;
typedef unsigned int u32;
typedef __attribute__((ext_vector_type(8))) short short8;
typedef __attribute__((ext_vector_type(4))) float floatx4;

#define P_PAIRS 160000
#define N_ATOMS 10000

#define OFF_WMLP  0      // stored TRANSPOSED: [50][64], (o,k) at o*64+k
#define OFF_BMLP  3200
#define OFF_WE1   3250
#define OFF_BE1   6930
#define OFF_WE2   6962
#define OFF_BE2   7986
#define OFF_WATT  8018
#define OFF_BATT  8242
#define OFF_WN1   8249
#define OFF_BN1   17465
#define OFF_WN2   17497
#define OFF_BN2   18521
#define OFF_WP1   18553
#define OFF_BP1   25721
#define OFF_WP2   25753
#define OFF_BP2   26777
#define OFF_WV1   26809
#define OFF_BV1   27833
#define OFF_WV2   27865
#define OFF_WVMIX 27897
#define WF_TOTAL  28121

__device__ __forceinline__ float b2f(u16 u){ return __uint_as_float(((u32)u) << 16); }
__device__ __forceinline__ u16 f2b(float f){
  u32 u = __float_as_uint(f);
  u32 r = (u + 0x7FFFu + ((u >> 16) & 1u)) >> 16;
  return (u16)r;
}
__device__ __forceinline__ float siluf(float v){ return v / (1.f + __expf(-v)); }
__device__ __forceinline__ float ldw(const void* p, int o, int bf){
  return bf ? b2f(((const u16*)p)[o]) : ((const float*)p)[o];
}

__global__ void k_code(float* out, float code){
  if (threadIdx.x == 0 && blockIdx.x == 0) out[0] = code;
}

// ---------------- dtype detection ----------------
__global__ void k_detect(const u32* __restrict__ hw, const u32* __restrict__ plw,
                         int* __restrict__ flags){
  if (threadIdx.x == 0 && blockIdx.x == 0){
    int bf = 0;
    for (int k = 0; k < 64; ++k){
      u32 e = (hw[k] >> 7) & 0xFFu;
      if (e >= 100u && e <= 140u) bf++;
    }
    flags[0] = (bf >= 48) ? 1 : 0;
    int z = 0;
    for (int k = 0; k < 64; ++k) if (plw[2*k+1] == 0u) z++;
    flags[1] = (z >= 60) ? 1 : 0;
  }
}

// ---------------- input normalization ----------------
__global__ void k_norm(const void* __restrict__ h_raw, const void* __restrict__ x_raw,
                       const void* __restrict__ v_raw, const void* __restrict__ pl_raw,
                       const int* __restrict__ flags, float* __restrict__ hf,
                       float* __restrict__ xf, float* __restrict__ vf, int* __restrict__ pli){
  int t = blockIdx.x * 256 + threadIdx.x;
  int bf = flags[0], i64 = flags[1];
  if (t < 320000){
    hf[t] = ldw(h_raw, t, bf);
  } else if (t < 350000){
    int i = t - 320000;
    xf[i] = ldw(x_raw, i, bf);
  } else if (t < 380000){
    int i = t - 350000;
    vf[i] = ldw(v_raw, i, bf);
  } else if (t < 700000){
    int k = t - 380000;
    const int* p32 = (const int*)pl_raw;
    pli[k] = i64 ? p32[2*(size_t)k] : p32[k];
  }
}

// ---------------- weight conversion -> fp32 (WMLP stored transposed) --------
__global__ void k_convert(const void* w_mlp, const void* b_mlp, const void* w_e1, const void* b_e1,
  const void* w_e2, const void* b_e2, const void* w_att, const void* b_att,
  const void* w_n1, const void* b_n1, const void* w_n2, const void* b_n2,
  const void* w_p1, const void* b_p1, const void* w_p2, const void* b_p2,
  const void* w_v1, const void* b_v1, const void* w_v2, const void* w_vmix,
  const int* __restrict__ flags, float* __restrict__ Wf){
  int t = blockIdx.x * 256 + threadIdx.x;
  if (t >= WF_TOTAL) return;
  int bf = flags[0];
  if (t < 3200){
    int k = t / 50, o = t - k * 50;           // src (k,o) row-major [64][50]
    Wf[OFF_WMLP + o * 64 + k] = ldw(w_mlp, t, bf);
    return;
  }
  const void* src; int o;
  if      (t < 3250)  { src = b_mlp;  o = t - 3200; }
  else if (t < 6930)  { src = w_e1;   o = t - 3250; }
  else if (t < 6962)  { src = b_e1;   o = t - 6930; }
  else if (t < 7986)  { src = w_e2;   o = t - 6962; }
  else if (t < 8018)  { src = b_e2;   o = t - 7986; }
  else if (t < 8242)  { src = w_att;  o = t - 8018; }
  else if (t < 8249)  { src = b_att;  o = t - 8242; }
  else if (t < 17465) { src = w_n1;   o = t - 8249; }
  else if (t < 17497) { src = b_n1;   o = t - 17465; }
  else if (t < 18521) { src = w_n2;   o = t - 17497; }
  else if (t < 18553) { src = b_n2;   o = t - 18521; }
  else if (t < 25721) { src = w_p1;   o = t - 18553; }
  else if (t < 25753) { src = b_p1;   o = t - 25721; }
  else if (t < 26777) { src = w_p2;   o = t - 25753; }
  else if (t < 26809) { src = b_p2;   o = t - 26777; }
  else if (t < 27833) { src = w_v1;   o = t - 26809; }
  else if (t < 27865) { src = b_v1;   o = t - 27833; }
  else if (t < 27897) { src = w_v2;   o = t - 27865; }
  else                { src = w_vmix; o = t - 27897; }
  Wf[t] = ldw(src, o, bf);
}

// wT[n][k] = w_xmix[k][n] as bf16 (B^T operand for MFMA)
__global__ void k_transpose(const void* __restrict__ wx, const int* __restrict__ flags,
                            u16* __restrict__ wT){
  int t = blockIdx.x * 256 + threadIdx.x;
  if (t >= 224 * 224) return;
  int n = t / 224, k = t - n * 224;
  wT[t] = f2b(ldw(wx, k * 224 + n, flags[0]));
}

// ---------------- per-atom projections (factorized edge model) --------------
__global__ void k_atompre(const float* __restrict__ h, const float* __restrict__ Wf,
                          float* __restrict__ prei, float* __restrict__ prej){
  int a = blockIdx.x;
  int r = threadIdx.x;
  __shared__ float hs[32];
  if (r < 32) hs[r] = h[(size_t)a * 32 + r];
  __syncthreads();
  if (r < 50){
    const float* wm = Wf + OFF_WMLP + r * 64;
    float acc = Wf[OFF_BMLP + r];
    #pragma unroll
    for (int k = 0; k < 32; ++k) acc += hs[k] * wm[k];
    prei[(size_t)a * 84 + r] = acc;
  } else if (r < 100){
    int kk = r - 50;
    const float* wm = Wf + OFF_WMLP + kk * 64 + 32;
    float acc = 0.f;
    #pragma unroll
    for (int k = 0; k < 32; ++k) acc += hs[k] * wm[k];
    prej[(size_t)a * 84 + kk] = acc;
  } else if (r < 132){
    int o = r - 100;
    float acc = Wf[OFF_BE1 + o];
    #pragma unroll
    for (int k = 0; k < 32; ++k) acc += hs[k] * Wf[OFF_WE1 + k * 32 + o];
    prei[(size_t)a * 84 + 52 + o] = acc;
  } else if (r < 164){
    int o = r - 132;
    float acc = 0.f;
    #pragma unroll
    for (int k = 0; k < 32; ++k) acc += hs[k] * Wf[OFF_WE1 + (32 + k) * 32 + o];
    prej[(size_t)a * 84 + 52 + o] = acc;
  }
}

// ---------------- counting sort ----------------
__global__ void k_hist(const int* __restrict__ pl, int* __restrict__ counts){
  int p = blockIdx.x * 256 + threadIdx.x;
  atomicAdd(&counts[pl[p]], 1);
}

__global__ void k_scan(const int* __restrict__ counts, int* __restrict__ offs, int* __restrict__ cursor){
  __shared__ int part[256];
  int t = threadIdx.x;
  int sum = 0;
  for (int k = 0; k < 40; ++k){
    int idx = t * 40 + k;
    if (idx < N_ATOMS) sum += counts[idx];
  }
  part[t] = sum;
  __syncthreads();
  if (t == 0){
    int run = 0;
    for (int q = 0; q < 256; ++q){ int tmp = part[q]; part[q] = run; run += tmp; }
  }
  __syncthreads();
  int run = part[t];
  for (int k = 0; k < 40; ++k){
    int idx = t * 40 + k;
    if (idx < N_ATOMS){ offs[idx] = run; cursor[idx] = run; run += counts[idx]; }
  }
  if (t == 0) offs[N_ATOMS] = P_PAIRS;
}

__global__ void k_scatter(const int* __restrict__ pl, int* __restrict__ cursor,
                          int* __restrict__ perm){
  int p = blockIdx.x * 256 + threadIdx.x;
  int i = pl[p];
  int pos = atomicAdd(&cursor[i], 1);
  perm[pos] = p;
}

// ------- per-pair edge model (factorized: per-atom projections gathered) ----
__global__ __launch_bounds__(256, 1) void k_pair(const float* __restrict__ x,
    const int* __restrict__ pl, const int* __restrict__ perm, const float* __restrict__ Wf,
    const float* __restrict__ prei, const float* __restrict__ prej,
    u16* __restrict__ edge, float* __restrict__ logits, float* __restrict__ dirs){
  int tid = threadIdx.x;
  int s = blockIdx.x * 256 + tid;            // sorted slot
  int p = perm[s];
  int i = pl[p], j = pl[P_PAIRS + p];
  float r0 = x[j*3+0] - x[i*3+0];
  float r1 = x[j*3+1] - x[i*3+1];
  float r2 = x[j*3+2] - x[i*3+2];
  float d = sqrtf(r0*r0 + r1*r1 + r2*r2);
  float rinv = 1.f / (d + 1e-5f);
  dirs[s*3+0] = r0*rinv; dirs[s*3+1] = r1*rinv; dirs[s*3+2] = r2*rinv;

  const float4* pi4 = (const float4*)(prei + (size_t)i * 84);
  const float4* pj4 = (const float4*)(prej + (size_t)j * 84);

  // tb[kk] = b_mlp[kk] + h_i@Wtop[kk] + h_j@Wbot[kk]   (filt dots, pre-summed)
  float tb[52];
  #pragma unroll
  for (int q = 0; q < 13; ++q){
    float4 aa = pi4[q], bb = pj4[q];
    tb[q*4+0] = aa.x + bb.x; tb[q*4+1] = aa.y + bb.y;
    tb[q*4+2] = aa.z + bb.z; tb[q*4+3] = aa.w + bb.w;
  }
  // u[o] = b_e1[o] + h_cat @ WE1[0:64] (pre-summed) ...
  float u[32];
  #pragma unroll
  for (int q = 0; q < 8; ++q){
    float4 aa = pi4[13+q], bb = pj4[13+q];
    u[q*4+0] = aa.x + bb.x; u[q*4+1] = aa.y + bb.y;
    u[q*4+2] = aa.z + bb.z; u[q*4+3] = aa.w + bb.w;
  }
  // ... + d * WE1[114]
  {
    const float* wr = Wf + OFF_WE1 + 114 * 32;
    #pragma unroll
    for (int o = 0; o < 32; ++o) u[o] += d * wr[o];
  }
  // fused filt: per kk compute scalar filt from tb, accumulate into u
  for (int kk = 0; kk < 50; ++kk){
    float c = (float)kk * (5.0f / 49.0f);
    float dd = d - c;
    float filt = tb[kk] * __expf(-10.0f * dd * dd);
    const float* we = Wf + OFF_WE1 + (64 + kk) * 32;
    #pragma unroll
    for (int o = 0; o < 32; ++o) u[o] += filt * we[o];
  }
  #pragma unroll
  for (int o = 0; o < 32; ++o) u[o] = siluf(u[o]);
  // edge = u @ w_e2 + b
  float eg[32];
  #pragma unroll
  for (int o = 0; o < 32; ++o) eg[o] = Wf[OFF_BE2 + o];
  #pragma unroll
  for (int k = 0; k < 32; ++k){
    const float* wr = Wf + OFF_WE2 + k * 32;
    #pragma unroll
    for (int o = 0; o < 32; ++o) eg[o] += u[k] * wr[o];
  }
  {
    u32 st[16];
    #pragma unroll
    for (int o = 0; o < 16; ++o)
      st[o] = (u32)f2b(eg[2*o]) | ((u32)f2b(eg[2*o+1]) << 16);
    #pragma unroll
    for (int q = 0; q < 4; ++q){
      uint4 vv; vv.x = st[4*q]; vv.y = st[4*q+1]; vv.z = st[4*q+2]; vv.w = st[4*q+3];
      *(uint4*)(edge + (size_t)s * 32 + q * 8) = vv;
    }
  }
  float lg[7];
  #pragma unroll
  for (int o = 0; o < 7; ++o) lg[o] = Wf[OFF_BATT + o];
  #pragma unroll
  for (int k = 0; k < 32; ++k){
    const float* wr = Wf + OFF_WATT + k * 7;
    #pragma unroll
    for (int o = 0; o < 7; ++o) lg[o] += eg[k] * wr[o];
  }
  #pragma unroll
  for (int o = 0; o < 7; ++o){
    float vv = lg[o];
    float cl = vv > 0.f ? vv : 2.f * expm1f(0.5f * vv);
    logits[s*7+o] = cl;
  }
}

// -------- segment softmax + hsem accumulation (16-lane group per atom) ------
__global__ __launch_bounds__(256) void k_att(const int* __restrict__ offs,
    const float* __restrict__ logits, const u16* __restrict__ edge,
    float* __restrict__ atts, float* __restrict__ hsem){
  int a = blockIdx.x * 16 + (threadIdx.x >> 4);   // N = 625*16
  int lane = threadIdx.x & 15;
  int off = offs[a], end = offs[a+1];
  float m[7];
  #pragma unroll
  for (int hh = 0; hh < 7; ++hh) m[hh] = -1e30f;
  for (int s = off + lane; s < end; s += 16){
    #pragma unroll
    for (int hh = 0; hh < 7; ++hh) m[hh] = fmaxf(m[hh], logits[s*7+hh]);
  }
  #pragma unroll
  for (int hh = 0; hh < 7; ++hh){
    float v = m[hh];
    #pragma unroll
    for (int msk = 8; msk >= 1; msk >>= 1) v = fmaxf(v, __shfl_xor(v, msk));
    m[hh] = v;
  }
  float sm[7] = {0,0,0,0,0,0,0};
  for (int s = off + lane; s < end; s += 16){
    #pragma unroll
    for (int hh = 0; hh < 7; ++hh){
      float e = __expf(logits[s*7+hh] - m[hh]);
      sm[hh] += e;
      atts[s*7+hh] = e;
    }
  }
  #pragma unroll
  for (int hh = 0; hh < 7; ++hh){
    float v = sm[hh];
    #pragma unroll
    for (int msk = 8; msk >= 1; msk >>= 1) v += __shfl_xor(v, msk);
    sm[hh] = 1.f / v;
  }
  for (int s = off + lane; s < end; s += 16){
    #pragma unroll
    for (int hh = 0; hh < 7; ++hh) atts[s*7+hh] *= sm[hh];
  }
  __syncthreads();   // drain atts stores (vmcnt) so the re-reads below are safe
  float acc[14] = {0,0,0,0,0,0,0,0,0,0,0,0,0,0};
  for (int s = off; s < end; ++s){
    u32 ev = *(const u32*)(edge + (size_t)s * 32 + lane * 2);
    float e0 = b2f((u16)(ev & 0xFFFFu));
    float e1 = b2f((u16)(ev >> 16));
    const float* ap = atts + (size_t)s * 7;
    #pragma unroll
    for (int hh = 0; hh < 7; ++hh){
      float at = ap[hh];
      acc[hh]     += e0 * at;
      acc[7 + hh] += e1 * at;
    }
  }
  float* hp = hsem + (size_t)a * 224 + lane * 14;
  #pragma unroll
  for (int jj = 0; jj < 14; ++jj) hp[jj] = acc[jj];
}

// -------- MFMA GEMM, half-width (112 cols), NO atomics: writes xhalf bf16 ---
// LDS: As [128][232]u16 = 59392 (xth [128][120]u16 = 30720 overlays after MFMA)
//      Bs0 8960 @59392, Bs1 8960 @68352 (eL[128][36]=9216 + aL 3584 overlay)
#define G_BS0  59392
#define G_BS1  68352
#define G_EL   59392
#define G_AL   (59392 + 9216)
#define G_TOT  77312

__global__ __launch_bounds__(256) void k_gemm3(const u16* __restrict__ edge,
    const float* __restrict__ atts, const u16* __restrict__ BT,
    u16* __restrict__ xhalf, int half){
  __shared__ __attribute__((aligned(16))) char smem[G_TOT];
  u16*   As  = (u16*)smem;                 // stride 232 u16
  u16*   xth = (u16*)smem;                 // stride 120 u16, overlays As after MFMA
  u16*   eL  = (u16*)(smem + G_EL);        // stride 36 u16 (overlay, dead after pack)
  float* aL  = (float*)(smem + G_AL);      // stride 7 floats (overlay)
  u16*   BsA[2] = {(u16*)(smem + G_BS0), (u16*)(smem + G_BS1)};
  int tid = threadIdx.x;
  int wave = tid >> 6, lane = tid & 63, l15 = lane & 15, quad = lane >> 4;
  int row0 = blockIdx.x * 128;
  int nbase = half * 112;

  // stage edge rows (padded stride 36) + atts
  for (int e = tid; e < 1024; e += 256){
    int r = e >> 3, q = e & 7;
    *(uint2*)(eL + r*36 + q*4) = *(const uint2*)(edge + (size_t)(row0 + r)*32 + q*4);
  }
  for (int e = tid; e < 896; e += 256) aL[e] = atts[(size_t)row0*7 + e];
  floatx4 acc[2][7];
  #pragma unroll
  for (int mt = 0; mt < 2; ++mt)
    #pragma unroll
    for (int nt = 0; nt < 7; ++nt)
      acc[mt][nt] = (floatx4){0.f, 0.f, 0.f, 0.f};
  __syncthreads();

  // pack full A-tile once: thread t -> row t>>1, column half (t&1)*112
  {
    int pr = tid >> 1, pp = tid & 1;
    u32* asw = (u32*)As + pr*116 + pp*56;
    const u16* er = eL + pr*36 + pp*16;
    const float* ar = aL + pr*7;
    float av[7];
    #pragma unroll
    for (int hh = 0; hh < 7; ++hh) av[hh] = ar[hh];
    #pragma unroll
    for (int fo = 0; fo < 8; ++fo){
      float e0 = b2f(er[2*fo]);
      float e1 = b2f(er[2*fo+1]);
      u16 w[14];
      #pragma unroll
      for (int hh = 0; hh < 7; ++hh){
        w[hh]   = f2b(e0 * av[hh]);
        w[7+hh] = f2b(e1 * av[hh]);
      }
      #pragma unroll
      for (int k = 0; k < 7; ++k)
        asw[fo*7 + k] = (u32)w[2*k] | ((u32)w[2*k+1] << 16);
    }
  }
  __syncthreads();          // As ready; eL/aL dead -> Bs buffers usable

  // prologue: stage Bs[0] for kt=0
  for (int e = tid; e < 448; e += 256){
    int r = e >> 2, q = e & 3;
    *(uint4*)(BsA[0] + r*40 + q*8) = *(const uint4*)(BT + (size_t)(nbase + r)*224 + q*8);
  }
  int cur = 0;
  for (int kt = 0; kt < 7; ++kt){
    __syncthreads();        // Bs[cur] visible; prior MFMA reads of Bs[cur^1] done
    if (kt < 6){
      int kk = (kt + 1) * 32;
      u16* bn = BsA[cur ^ 1];
      for (int e = tid; e < 448; e += 256){
        int r = e >> 2, q = e & 3;
        *(uint4*)(bn + r*40 + q*8) = *(const uint4*)(BT + (size_t)(nbase + r)*224 + kk + q*8);
      }
    }
    int kk = kt * 32;
    short8 a0 = *(const short8*)(As + (wave*32 + l15)*232 + kk + quad*8);
    short8 a1 = *(const short8*)(As + (wave*32 + 16 + l15)*232 + kk + quad*8);
    const u16* bs = BsA[cur];
    #pragma unroll
    for (int nt = 0; nt < 7; ++nt){
      short8 b = *(const short8*)(bs + (nt*16 + l15)*40 + quad*8);
      acc[0][nt] = __builtin_amdgcn_mfma_f32_16x16x32_bf16(a0, b, acc[0][nt], 0, 0, 0);
      acc[1][nt] = __builtin_amdgcn_mfma_f32_16x16x32_bf16(a1, b, acc[1][nt], 0, 0, 0);
    }
    cur ^= 1;
  }
  __syncthreads();          // all MFMA As reads done before xth overlays As

  // tanh epilogue -> xth (stride 120), wave-local rows
  #pragma unroll
  for (int mt = 0; mt < 2; ++mt)
    #pragma unroll
    for (int nt = 0; nt < 7; ++nt)
      #pragma unroll
      for (int reg = 0; reg < 4; ++reg){
        int r = wave*32 + mt*16 + quad*4 + reg;
        int c = nt*16 + l15;
        float vv = acc[mt][nt][reg];
        vv = fminf(fmaxf(vv, -15.f), 15.f);
        float e2 = __expf(2.f * vv);
        xth[r*120 + c] = f2b((e2 - 1.f) / (e2 + 1.f));
      }
  // coalesced copy-out (wave-local rows: thread t -> row t>>1)
  {
    int r = tid >> 1, part = tid & 1;
    const uint4* src = (const uint4*)(xth + r*120 + part*56);
    uint4* dst = (uint4*)(xhalf + (size_t)(row0 + r)*112 + part*56);
    #pragma unroll
    for (int q = 0; q < 7; ++q) dst[q] = src[q];
  }
}

// -------- atom-centric comb reduction: xhalf -> nsq half + pv partial -------
// 16 lanes per atom; lane owns channels c_local = lane + 16k, k=0..6. No atomics.
__global__ __launch_bounds__(256) void k_comb(const int* __restrict__ offs,
    const u16* __restrict__ xhalf, const float* __restrict__ dirs,
    const float* __restrict__ Wf, int half,
    float* __restrict__ nsq, float* __restrict__ pvh){
  int a = blockIdx.x * 16 + (threadIdx.x >> 4);   // N = 625*16
  int lane = threadIdx.x & 15;
  int off = offs[a], end = offs[a+1];
  float c0[7] = {0,0,0,0,0,0,0}, c1[7] = {0,0,0,0,0,0,0}, c2[7] = {0,0,0,0,0,0,0};
  for (int s = off; s < end; ++s){
    float d0 = dirs[s*3+0], d1 = dirs[s*3+1], d2 = dirs[s*3+2];
    const u16* xr = xhalf + (size_t)s * 112 + lane;
    #pragma unroll
    for (int k = 0; k < 7; ++k){
      float xm = b2f(xr[k*16]);
      c0[k] += d0 * xm; c1[k] += d1 * xm; c2[k] += d2 * xm;
    }
  }
  float inv = 1.f / fmaxf((float)(end - off), 1.f);
  float pv0 = 0.f, pv1 = 0.f, pv2 = 0.f;
  #pragma unroll
  for (int k = 0; k < 7; ++k){
    float m0 = c0[k]*inv, m1 = c1[k]*inv, m2 = c2[k]*inv;
    int c = half*112 + k*16 + lane;
    nsq[(size_t)a*224 + c] = m0*m0 + m1*m1 + m2*m2;
    float wv = Wf[OFF_WVMIX + c];
    pv0 += wv*m0; pv1 += wv*m1; pv2 += wv*m2;
  }
  #pragma unroll
  for (int m = 8; m >= 1; m >>= 1){
    pv0 += __shfl_xor(pv0, m); pv1 += __shfl_xor(pv1, m); pv2 += __shfl_xor(pv2, m);
  }
  if (lane == 0){
    float* pp = pvh + (size_t)half*30000 + (size_t)a*3;
    pp[0] = pv0; pp[1] = pv1; pp[2] = pv2;
  }
}

// ---------------- final: wave per atom, precomputed hsem/nsq/pv -------------
__global__ __launch_bounds__(256) void k_final4(const float* __restrict__ h,
    const float* __restrict__ x, const float* __restrict__ v,
    const float* __restrict__ Wf, const float* __restrict__ hsem,
    const float* __restrict__ nsq, const float* __restrict__ pvh,
    float* __restrict__ out){
  __shared__ float s_in[4][288];     // [0:32)=h, [32:256)=hsem, [256:288)=sp
  __shared__ float s_nsq[4][224];
  __shared__ float s_u1[4][32], s_g[4][32], s_un[4][32];
  int wv_ = threadIdx.x >> 6, lane = threadIdx.x & 63;
  int a = blockIdx.x * 4 + wv_;                 // N = 2500*4
  if (lane < 56){
    int c4 = lane * 4;
    float4 hs = *(const float4*)(hsem + (size_t)a*224 + c4);
    float4 nq = *(const float4*)(nsq + (size_t)a*224 + c4);
    s_in[wv_][32 + c4+0] = hs.x; s_in[wv_][32 + c4+1] = hs.y;
    s_in[wv_][32 + c4+2] = hs.z; s_in[wv_][32 + c4+3] = hs.w;
    s_nsq[wv_][c4+0] = nq.x; s_nsq[wv_][c4+1] = nq.y;
    s_nsq[wv_][c4+2] = nq.z; s_nsq[wv_][c4+3] = nq.w;
  } else {
    int k4 = (lane - 56) * 4;
    float4 hv = *(const float4*)(h + (size_t)a*32 + k4);
    s_in[wv_][k4+0] = hv.x; s_in[wv_][k4+1] = hv.y;
    s_in[wv_][k4+2] = hv.z; s_in[wv_][k4+3] = hv.w;
  }
  __syncthreads();
  int o = lane & 31, kh = lane >> 5;
  // p1 (K=224), K-split across wave halves
  {
    float u = 0.f;
    const float* q = &s_nsq[wv_][kh*112];
    const float* w = Wf + OFF_WP1 + (kh*112)*32 + o;
    #pragma unroll 4
    for (int kk = 0; kk < 112; ++kk) u += q[kk] * w[kk*32];
    u += __shfl_xor(u, 32);
    if (lane < 32) s_u1[wv_][o] = siluf(u + Wf[OFF_BP1 + o]);
  }
  // g = silu(h @ Wv1 + b), K=32 split 16/16
  {
    float g = 0.f;
    const float* q = &s_in[wv_][kh*16];
    const float* w = Wf + OFF_WV1 + (kh*16)*32 + o;
    #pragma unroll
    for (int kk = 0; kk < 16; ++kk) g += q[kk] * w[kk*32];
    g += __shfl_xor(g, 32);
    if (lane < 32) s_g[wv_][o] = siluf(g + Wf[OFF_BV1 + o]);
  }
  __syncthreads();
  float zpart = (lane < 32) ? s_g[wv_][lane] * Wf[OFF_WV2 + lane] : 0.f;
  #pragma unroll
  for (int m = 32; m >= 1; m >>= 1) zpart += __shfl_xor(zpart, m);
  float sc = 2.f / (1.f + __expf(-zpart));
  // p2 (K=32) split 16/16 -> s_in[256..288)
  {
    float u = 0.f;
    const float* q = &s_u1[wv_][kh*16];
    const float* w = Wf + OFF_WP2 + (kh*16)*32 + o;
    #pragma unroll
    for (int kk = 0; kk < 16; ++kk) u += q[kk] * w[kk*32];
    u += __shfl_xor(u, 32);
    if (lane < 32) s_in[wv_][256 + o] = siluf(u + Wf[OFF_BP2 + o]);
  }
  __syncthreads();
  // n1 (K=288) split 144/144, uniform via staged s_in
  {
    float u = 0.f;
    const float* q = &s_in[wv_][kh*144];
    const float* w = Wf + OFF_WN1 + (kh*144)*32 + o;
    #pragma unroll 4
    for (int kk = 0; kk < 144; ++kk) u += q[kk] * w[kk*32];
    u += __shfl_xor(u, 32);
    if (lane < 32) s_un[wv_][o] = siluf(u + Wf[OFF_BN1 + o]);
  }
  __syncthreads();
  if (lane < 32){
    float u = Wf[OFF_BN2 + lane];
    #pragma unroll
    for (int k = 0; k < 32; ++k) u += s_un[wv_][k] * Wf[OFF_WN2 + k*32 + lane];
    out[a*32 + lane] = s_in[wv_][lane] + siluf(u);
  }
  if (lane < 3){
    float pv = pvh[(size_t)a*3 + lane] + pvh[30000 + (size_t)a*3 + lane];
    float vup = sc * v[a*3+lane] + pv;
    float xup = x[a*3+lane] + vup;
    out[N_ATOMS*32 + a*3 + lane] = xup;
    out[N_ATOMS*32 + N_ATOMS*3 + a*3 + lane] = vup;
  }
}

// ---------------- workspace layout ----------------
static constexpr size_t al256(size_t x){ return (x + 255) & ~(size_t)255; }
static constexpr size_t WS_FLAGS   = 0;
static constexpr size_t WS_COUNTS  = al256(WS_FLAGS + 8);
static constexpr size_t WS_OFFSETS = al256(WS_COUNTS + (size_t)N_ATOMS * 4);
static constexpr size_t WS_CURSOR  = al256(WS_OFFSETS + (size_t)(N_ATOMS + 1) * 4);
static constexpr size_t WS_PERM    = al256(WS_CURSOR + (size_t)N_ATOMS * 4);
static constexpr size_t WS_PLI     = al256(WS_PERM + (size_t)P_PAIRS * 4);
static constexpr size_t WS_HF      = al256(WS_PLI + (size_t)2 * P_PAIRS * 4);
static constexpr size_t WS_XF      = al256(WS_HF + (size_t)N_ATOMS * 32 * 4);
static constexpr size_t WS_VF      = al256(WS_XF + (size_t)N_ATOMS * 3 * 4);
static constexpr size_t WS_WF      = al256(WS_VF + (size_t)N_ATOMS * 3 * 4);
static constexpr size_t WS_WT      = al256(WS_WF + (size_t)WF_TOTAL * 4);
static constexpr size_t WS_EDGE    = al256(WS_WT + (size_t)224 * 224 * 2);
static constexpr size_t WS_ATTS    = al256(WS_EDGE + (size_t)P_PAIRS * 32 * 2);
static constexpr size_t WS_DIRS    = al256(WS_ATTS + (size_t)P_PAIRS * 7 * 4);
static constexpr size_t WS_LOGITS  = al256(WS_DIRS + (size_t)P_PAIRS * 3 * 4);
// shared region R = [WS_LOGITS, WS_LOGITS+71.68M) (round-1-proven footprint).
// Lifetimes (launch order) make overlaps safe:
//   logits [0, 4.48M)         : k_pair -> k_att
//   prei/prej [4.48M, 11.2M)  : k_atompre -> k_pair (then dead)
//   hsem [4.48M, 13.44M)      : k_att writes (prei/prej dead), k_final4 reads
//   xhalf [13.44M, 49.28M)    : k_gemm3(h) writes, k_comb(h) reads; reused h=0,1
//   nsq [49.28M, 58.24M)      : k_comb writes, k_final4 reads
//   pvh [58.24M, 58.48M)      : k_comb writes, k_final4 reads
static constexpr size_t WS_PREI    = al256(WS_LOGITS + (size_t)P_PAIRS * 7 * 4);
static constexpr size_t WS_PREJ    = al256(WS_PREI + (size_t)N_ATOMS * 84 * 4);
static constexpr size_t WS_HSEM    = WS_LOGITS + 4480000;
static constexpr size_t WS_XH      = WS_HSEM + (size_t)N_ATOMS * 224 * 4;           // +8.96M
static constexpr size_t WS_NSQ     = WS_XH + (size_t)P_PAIRS * 112 * 2;             // +35.84M
static constexpr size_t WS_PVH     = WS_NSQ + (size_t)N_ATOMS * 224 * 4;            // +8.96M
static constexpr size_t WS_END     = WS_PVH + (size_t)2 * 30000 * 4;
static_assert(WS_PREJ + (size_t)N_ATOMS * 84 * 4 <= WS_XH, "pre tables before xhalf");
static_assert(WS_END <= WS_LOGITS + (size_t)P_PAIRS * 224 * 2, "within round-1-proven footprint");
static_assert(WS_HSEM % 256 == 0 && WS_XH % 256 == 0 && WS_NSQ % 256 == 0 && WS_PVH % 256 == 0, "alignment");

extern "C" void kernel_launch(void* const* d_in, const int* in_sizes, int n_in,
                              void* d_out, int out_size, void* d_ws, size_t ws_size,
                              hipStream_t stream){
  (void)in_sizes; (void)n_in;
  if (out_size != 380000 || ws_size < WS_END){
    k_code<<<1, 64, 0, stream>>>((float*)d_out, 14000.f);
    return;
  }
  char* ws = (char*)d_ws;
  int*   flags  = (int*)(ws + WS_FLAGS);
  int*   counts = (int*)(ws + WS_COUNTS);
  int*   offs   = (int*)(ws + WS_OFFSETS);
  int*   cursor = (int*)(ws + WS_CURSOR);
  int*   perm   = (int*)(ws + WS_PERM);
  int*   pli    = (int*)(ws + WS_PLI);
  float* hf     = (float*)(ws + WS_HF);
  float* xf     = (float*)(ws + WS_XF);
  float* vf     = (float*)(ws + WS_VF);
  float* Wf     = (float*)(ws + WS_WF);
  u16*   wT     = (u16*)(ws + WS_WT);
  u16*   edge   = (u16*)(ws + WS_EDGE);
  float* atts   = (float*)(ws + WS_ATTS);
  float* dirs   = (float*)(ws + WS_DIRS);
  float* logits = (float*)(ws + WS_LOGITS);
  float* prei   = (float*)(ws + WS_PREI);
  float* prej   = (float*)(ws + WS_PREJ);
  float* hsem   = (float*)(ws + WS_HSEM);
  u16*   xhalf  = (u16*)(ws + WS_XH);
  float* nsq    = (float*)(ws + WS_NSQ);
  float* pvh    = (float*)(ws + WS_PVH);

  hipMemsetAsync(counts, 0, (size_t)N_ATOMS * 4, stream);
  k_detect<<<1, 64, 0, stream>>>((const u32*)d_in[0], (const u32*)d_in[3], flags);
  k_norm<<<(700000 + 255) / 256, 256, 0, stream>>>(d_in[0], d_in[1], d_in[2], d_in[3],
                                                   flags, hf, xf, vf, pli);
  k_convert<<<(WF_TOTAL + 255) / 256, 256, 0, stream>>>(
      d_in[4],  d_in[5],  d_in[6],  d_in[7],  d_in[8],  d_in[9],  d_in[10], d_in[11],
      d_in[12], d_in[13], d_in[14], d_in[15], d_in[16], d_in[17], d_in[18], d_in[19],
      d_in[20], d_in[21], d_in[22], d_in[24], flags, Wf);
  k_transpose<<<(224 * 224 + 255) / 256, 256, 0, stream>>>(d_in[23], flags, wT);
  k_atompre<<<N_ATOMS, 192, 0, stream>>>(hf, Wf, prei, prej);
  k_hist<<<P_PAIRS / 256, 256, 0, stream>>>(pli, counts);
  k_scan<<<1, 256, 0, stream>>>(counts, offs, cursor);
  k_scatter<<<P_PAIRS / 256, 256, 0, stream>>>(pli, cursor, perm);
  k_pair<<<P_PAIRS / 256, 256, 0, stream>>>(xf, pli, perm, Wf, prei, prej, edge, logits, dirs);
  k_att<<<N_ATOMS / 16, 256, 0, stream>>>(offs, logits, edge, atts, hsem);
  k_gemm3<<<P_PAIRS / 128, 256, 0, stream>>>(edge, atts, wT, xhalf, 0);
  k_comb<<<N_ATOMS / 16, 256, 0, stream>>>(offs, xhalf, dirs, Wf, 0, nsq, pvh);
  k_gemm3<<<P_PAIRS / 128, 256, 0, stream>>>(edge, atts, wT, xhalf, 1);
  k_comb<<<N_ATOMS / 16, 256, 0, stream>>>(offs, xhalf, dirs, Wf, 1, nsq, pvh);
  k_final4<<<N_ATOMS / 4, 256, 0, stream>>>(hf, xf, vf, Wf, hsem, nsq, pvh, (float*)d_out);
}

// Round 6
// 429.348 us; speedup vs baseline: 1.0154x; 1.0076x over previous
//
#include <hip/hip_runtime.h>

typedef unsigned short u16;
typedef unsigned int u32;
typedef __attribute__((ext_vector_type(8))) short short8;
typedef __attribute__((ext_vector_type(4))) float floatx4;

#define P_PAIRS 160000
#define N_ATOMS 10000

#define OFF_WMLP  0      // stored TRANSPOSED: [50][64], (o,k) at o*64+k
#define OFF_BMLP  3200
#define OFF_WE1   3250
#define OFF_BE1   6930
#define OFF_WE2   6962
#define OFF_BE2   7986
#define OFF_WATT  8018
#define OFF_BATT  8242
#define OFF_WN1   8249
#define OFF_BN1   17465
#define OFF_WN2   17497
#define OFF_BN2   18521
#define OFF_WP1   18553
#define OFF_BP1   25721
#define OFF_WP2   25753
#define OFF_BP2   26777
#define OFF_WV1   26809
#define OFF_BV1   27833
#define OFF_WV2   27865
#define OFF_WVMIX 27897
#define WF_TOTAL  28121

__device__ __forceinline__ float b2f(u16 u){ return __uint_as_float(((u32)u) << 16); }
__device__ __forceinline__ u16 f2b(float f){
  u32 u = __float_as_uint(f);
  u32 r = (u + 0x7FFFu + ((u >> 16) & 1u)) >> 16;
  return (u16)r;
}
__device__ __forceinline__ void unpack2(u32 p, float& lo, float& hi){
  lo = __uint_as_float(p << 16);
  hi = __uint_as_float(p & 0xFFFF0000u);
}
__device__ __forceinline__ float siluf(float v){ return v / (1.f + __expf(-v)); }
__device__ __forceinline__ float ldw(const void* p, int o, int bf){
  return bf ? b2f(((const u16*)p)[o]) : ((const float*)p)[o];
}

__global__ void k_code(float* out, float code){
  if (threadIdx.x == 0 && blockIdx.x == 0) out[0] = code;
}

// ---------------- dtype detection ----------------
__global__ void k_detect(const u32* __restrict__ hw, const u32* __restrict__ plw,
                         int* __restrict__ flags){
  if (threadIdx.x == 0 && blockIdx.x == 0){
    int bf = 0;
    for (int k = 0; k < 64; ++k){
      u32 e = (hw[k] >> 7) & 0xFFu;
      if (e >= 100u && e <= 140u) bf++;
    }
    flags[0] = (bf >= 48) ? 1 : 0;
    int z = 0;
    for (int k = 0; k < 64; ++k) if (plw[2*k+1] == 0u) z++;
    flags[1] = (z >= 60) ? 1 : 0;
  }
}

// ---------------- input normalization ----------------
__global__ void k_norm(const void* __restrict__ h_raw, const void* __restrict__ x_raw,
                       const void* __restrict__ v_raw, const void* __restrict__ pl_raw,
                       const int* __restrict__ flags, float* __restrict__ hf,
                       float* __restrict__ xf, float* __restrict__ vf, int* __restrict__ pli){
  int t = blockIdx.x * 256 + threadIdx.x;
  int bf = flags[0], i64 = flags[1];
  if (t < 320000){
    hf[t] = ldw(h_raw, t, bf);
  } else if (t < 350000){
    int i = t - 320000;
    xf[i] = ldw(x_raw, i, bf);
  } else if (t < 380000){
    int i = t - 350000;
    vf[i] = ldw(v_raw, i, bf);
  } else if (t < 700000){
    int k = t - 380000;
    const int* p32 = (const int*)pl_raw;
    pli[k] = i64 ? p32[2*(size_t)k] : p32[k];
  }
}

// ---------------- weight conversion -> fp32 (WMLP stored transposed) --------
__global__ void k_convert(const void* w_mlp, const void* b_mlp, const void* w_e1, const void* b_e1,
  const void* w_e2, const void* b_e2, const void* w_att, const void* b_att,
  const void* w_n1, const void* b_n1, const void* w_n2, const void* b_n2,
  const void* w_p1, const void* b_p1, const void* w_p2, const void* b_p2,
  const void* w_v1, const void* b_v1, const void* w_v2, const void* w_vmix,
  const int* __restrict__ flags, float* __restrict__ Wf){
  int t = blockIdx.x * 256 + threadIdx.x;
  if (t >= WF_TOTAL) return;
  int bf = flags[0];
  if (t < 3200){
    int k = t / 50, o = t - k * 50;           // src (k,o) row-major [64][50]
    Wf[OFF_WMLP + o * 64 + k] = ldw(w_mlp, t, bf);
    return;
  }
  const void* src; int o;
  if      (t < 3250)  { src = b_mlp;  o = t - 3200; }
  else if (t < 6930)  { src = w_e1;   o = t - 3250; }
  else if (t < 6962)  { src = b_e1;   o = t - 6930; }
  else if (t < 7986)  { src = w_e2;   o = t - 6962; }
  else if (t < 8018)  { src = b_e2;   o = t - 7986; }
  else if (t < 8242)  { src = w_att;  o = t - 8018; }
  else if (t < 8249)  { src = b_att;  o = t - 8242; }
  else if (t < 17465) { src = w_n1;   o = t - 8249; }
  else if (t < 17497) { src = b_n1;   o = t - 17465; }
  else if (t < 18521) { src = w_n2;   o = t - 17497; }
  else if (t < 18553) { src = b_n2;   o = t - 18521; }
  else if (t < 25721) { src = w_p1;   o = t - 18553; }
  else if (t < 25753) { src = b_p1;   o = t - 25721; }
  else if (t < 26777) { src = w_p2;   o = t - 25753; }
  else if (t < 26809) { src = b_p2;   o = t - 26777; }
  else if (t < 27833) { src = w_v1;   o = t - 26809; }
  else if (t < 27865) { src = b_v1;   o = t - 27833; }
  else if (t < 27897) { src = w_v2;   o = t - 27865; }
  else                { src = w_vmix; o = t - 27897; }
  Wf[t] = ldw(src, o, bf);
}

// wT[n][k] = w_xmix[k][n] as bf16 (B^T operand for MFMA)
__global__ void k_transpose(const void* __restrict__ wx, const int* __restrict__ flags,
                            u16* __restrict__ wT){
  int t = blockIdx.x * 256 + threadIdx.x;
  if (t >= 224 * 224) return;
  int n = t / 224, k = t - n * 224;
  wT[t] = f2b(ldw(wx, k * 224 + n, flags[0]));
}

// ---------------- per-atom projections, bf16 records (stride 88 u16) --------
// record layout: [0:32) u-part, [32:84) tb-part, [84:88) pad
__global__ void k_atompre(const float* __restrict__ h, const float* __restrict__ Wf,
                          u16* __restrict__ prei, u16* __restrict__ prej){
  int a = blockIdx.x;
  int r = threadIdx.x;
  __shared__ float hs[32];
  if (r < 32) hs[r] = h[(size_t)a * 32 + r];
  __syncthreads();
  if (r < 50){
    const float* wm = Wf + OFF_WMLP + r * 64;
    float acc = Wf[OFF_BMLP + r];
    #pragma unroll
    for (int k = 0; k < 32; ++k) acc += hs[k] * wm[k];
    prei[(size_t)a * 88 + 32 + r] = f2b(acc);
  } else if (r < 100){
    int kk = r - 50;
    const float* wm = Wf + OFF_WMLP + kk * 64 + 32;
    float acc = 0.f;
    #pragma unroll
    for (int k = 0; k < 32; ++k) acc += hs[k] * wm[k];
    prej[(size_t)a * 88 + 32 + kk] = f2b(acc);
  } else if (r < 132){
    int o = r - 100;
    float acc = Wf[OFF_BE1 + o];
    #pragma unroll
    for (int k = 0; k < 32; ++k) acc += hs[k] * Wf[OFF_WE1 + k * 32 + o];
    prei[(size_t)a * 88 + o] = f2b(acc);
  } else if (r < 164){
    int o = r - 132;
    float acc = 0.f;
    #pragma unroll
    for (int k = 0; k < 32; ++k) acc += hs[k] * Wf[OFF_WE1 + (32 + k) * 32 + o];
    prej[(size_t)a * 88 + o] = f2b(acc);
  }
}

// ---------------- counting sort ----------------
__global__ void k_hist(const int* __restrict__ pl, int* __restrict__ counts){
  int p = blockIdx.x * 256 + threadIdx.x;
  atomicAdd(&counts[pl[p]], 1);
}

__global__ void k_scan(const int* __restrict__ counts, int* __restrict__ offs, int* __restrict__ cursor){
  __shared__ int part[256];
  int t = threadIdx.x;
  int sum = 0;
  for (int k = 0; k < 40; ++k){
    int idx = t * 40 + k;
    if (idx < N_ATOMS) sum += counts[idx];
  }
  part[t] = sum;
  __syncthreads();
  if (t == 0){
    int run = 0;
    for (int q = 0; q < 256; ++q){ int tmp = part[q]; part[q] = run; run += tmp; }
  }
  __syncthreads();
  int run = part[t];
  for (int k = 0; k < 40; ++k){
    int idx = t * 40 + k;
    if (idx < N_ATOMS){ offs[idx] = run; cursor[idx] = run; run += counts[idx]; }
  }
  if (t == 0) offs[N_ATOMS] = P_PAIRS;
}

// writes sorted i/j directly: k_pair needs no perm/pl indirection
__global__ void k_scatter(const int* __restrict__ pl, int* __restrict__ cursor,
                          int* __restrict__ isrt, int* __restrict__ jsrt){
  int p = blockIdx.x * 256 + threadIdx.x;
  int i = pl[p];
  int pos = atomicAdd(&cursor[i], 1);
  isrt[pos] = i;
  jsrt[pos] = pl[P_PAIRS + p];
}

// ------- per-pair edge model (bf16 tables, 64-thread blocks) ----------------
__global__ __launch_bounds__(64) void k_pair(const float* __restrict__ x,
    const float* __restrict__ Wf, const u16* __restrict__ prei, const u16* __restrict__ prej,
    const int* __restrict__ isrt, const int* __restrict__ jsrt,
    u16* __restrict__ edge, float* __restrict__ logits, float* __restrict__ dirs){
  int s = blockIdx.x * 64 + threadIdx.x;     // sorted slot
  int i = isrt[s], j = jsrt[s];
  float r0 = x[j*3+0] - x[i*3+0];
  float r1 = x[j*3+1] - x[i*3+1];
  float r2 = x[j*3+2] - x[i*3+2];
  float d = sqrtf(r0*r0 + r1*r1 + r2*r2);
  float rinv = 1.f / (d + 1e-5f);
  dirs[s*3+0] = r0*rinv; dirs[s*3+1] = r1*rinv; dirs[s*3+2] = r2*rinv;

  const uint4* pi4 = (const uint4*)(prei + (size_t)i * 88);
  const uint4* pj4 = (const uint4*)(prej + (size_t)j * 88);

  // u-part: record [0:32)
  float u[32];
  #pragma unroll
  for (int q = 0; q < 4; ++q){
    uint4 a4 = pi4[q], b4 = pj4[q];
    u32 pa[4] = {a4.x, a4.y, a4.z, a4.w};
    u32 pb[4] = {b4.x, b4.y, b4.z, b4.w};
    #pragma unroll
    for (int w = 0; w < 4; ++w){
      float al, ah, bl, bh;
      unpack2(pa[w], al, ah); unpack2(pb[w], bl, bh);
      u[q*8 + w*2]     = al + bl;
      u[q*8 + w*2 + 1] = ah + bh;
    }
  }
  // tb-part: record [32:84) (+4 pad entries read, unused)
  float tb[56];
  #pragma unroll
  for (int q = 0; q < 7; ++q){
    uint4 a4 = pi4[4+q], b4 = pj4[4+q];
    u32 pa[4] = {a4.x, a4.y, a4.z, a4.w};
    u32 pb[4] = {b4.x, b4.y, b4.z, b4.w};
    #pragma unroll
    for (int w = 0; w < 4; ++w){
      float al, ah, bl, bh;
      unpack2(pa[w], al, ah); unpack2(pb[w], bl, bh);
      tb[q*8 + w*2]     = al + bl;
      tb[q*8 + w*2 + 1] = ah + bh;
    }
  }
  // ... + d * WE1[114]
  {
    const float* wr = Wf + OFF_WE1 + 114 * 32;
    #pragma unroll
    for (int o = 0; o < 32; ++o) u[o] += d * wr[o];
  }
  // fused filt: per kk compute scalar filt from tb, accumulate into u
  for (int kk = 0; kk < 50; ++kk){
    float c = (float)kk * (5.0f / 49.0f);
    float dd = d - c;
    float filt = tb[kk] * __expf(-10.0f * dd * dd);
    const float* we = Wf + OFF_WE1 + (64 + kk) * 32;
    #pragma unroll
    for (int o = 0; o < 32; ++o) u[o] += filt * we[o];
  }
  #pragma unroll
  for (int o = 0; o < 32; ++o) u[o] = siluf(u[o]);
  // edge = u @ w_e2 + b
  float eg[32];
  #pragma unroll
  for (int o = 0; o < 32; ++o) eg[o] = Wf[OFF_BE2 + o];
  #pragma unroll
  for (int k = 0; k < 32; ++k){
    const float* wr = Wf + OFF_WE2 + k * 32;
    #pragma unroll
    for (int o = 0; o < 32; ++o) eg[o] += u[k] * wr[o];
  }
  {
    u32 st[16];
    #pragma unroll
    for (int o = 0; o < 16; ++o)
      st[o] = (u32)f2b(eg[2*o]) | ((u32)f2b(eg[2*o+1]) << 16);
    #pragma unroll
    for (int q = 0; q < 4; ++q){
      uint4 vv; vv.x = st[4*q]; vv.y = st[4*q+1]; vv.z = st[4*q+2]; vv.w = st[4*q+3];
      *(uint4*)(edge + (size_t)s * 32 + q * 8) = vv;
    }
  }
  float lg[7];
  #pragma unroll
  for (int o = 0; o < 7; ++o) lg[o] = Wf[OFF_BATT + o];
  #pragma unroll
  for (int k = 0; k < 32; ++k){
    const float* wr = Wf + OFF_WATT + k * 7;
    #pragma unroll
    for (int o = 0; o < 7; ++o) lg[o] += eg[k] * wr[o];
  }
  #pragma unroll
  for (int o = 0; o < 7; ++o){
    float vv = lg[o];
    float cl = vv > 0.f ? vv : 2.f * expm1f(0.5f * vv);
    logits[s*7+o] = cl;
  }
}

// -------- segment softmax + hsem accumulation (16-lane group per atom) ------
__global__ __launch_bounds__(256) void k_att(const int* __restrict__ offs,
    const float* __restrict__ logits, const u16* __restrict__ edge,
    float* __restrict__ atts, float* __restrict__ hsem){
  int a = blockIdx.x * 16 + (threadIdx.x >> 4);   // N = 625*16
  int lane = threadIdx.x & 15;
  int off = offs[a], end = offs[a+1];
  float m[7];
  #pragma unroll
  for (int hh = 0; hh < 7; ++hh) m[hh] = -1e30f;
  for (int s = off + lane; s < end; s += 16){
    #pragma unroll
    for (int hh = 0; hh < 7; ++hh) m[hh] = fmaxf(m[hh], logits[s*7+hh]);
  }
  #pragma unroll
  for (int hh = 0; hh < 7; ++hh){
    float v = m[hh];
    #pragma unroll
    for (int msk = 8; msk >= 1; msk >>= 1) v = fmaxf(v, __shfl_xor(v, msk));
    m[hh] = v;
  }
  float sm[7] = {0,0,0,0,0,0,0};
  for (int s = off + lane; s < end; s += 16){
    #pragma unroll
    for (int hh = 0; hh < 7; ++hh){
      float e = __expf(logits[s*7+hh] - m[hh]);
      sm[hh] += e;
      atts[s*7+hh] = e;
    }
  }
  #pragma unroll
  for (int hh = 0; hh < 7; ++hh){
    float v = sm[hh];
    #pragma unroll
    for (int msk = 8; msk >= 1; msk >>= 1) v += __shfl_xor(v, msk);
    sm[hh] = 1.f / v;
  }
  for (int s = off + lane; s < end; s += 16){
    #pragma unroll
    for (int hh = 0; hh < 7; ++hh) atts[s*7+hh] *= sm[hh];
  }
  __syncthreads();   // drain atts stores (vmcnt) so the re-reads below are safe
  float acc[14] = {0,0,0,0,0,0,0,0,0,0,0,0,0,0};
  for (int s = off; s < end; ++s){
    u32 ev = *(const u32*)(edge + (size_t)s * 32 + lane * 2);
    float e0 = b2f((u16)(ev & 0xFFFFu));
    float e1 = b2f((u16)(ev >> 16));
    const float* ap = atts + (size_t)s * 7;
    #pragma unroll
    for (int hh = 0; hh < 7; ++hh){
      float at = ap[hh];
      acc[hh]     += e0 * at;
      acc[7 + hh] += e1 * at;
    }
  }
  float* hp = hsem + (size_t)a * 224 + lane * 14;
  #pragma unroll
  for (int jj = 0; jj < 14; ++jj) hp[jj] = acc[jj];
}

// -------- MFMA GEMM, half-width (112 cols), NO atomics: writes xhalf bf16 ---
// LDS: As [128][232]u16 = 59392 (xth [128][120]u16 = 30720 overlays after MFMA)
//      Bs0 8960 @59392, Bs1 8960 @68352 (eL[128][36]=9216 + aL 3584 overlay)
#define G_BS0  59392
#define G_BS1  68352
#define G_EL   59392
#define G_AL   (59392 + 9216)
#define G_TOT  77312

__global__ __launch_bounds__(256) void k_gemm3(const u16* __restrict__ edge,
    const float* __restrict__ atts, const u16* __restrict__ BT,
    u16* __restrict__ xhalf, int half){
  __shared__ __attribute__((aligned(16))) char smem[G_TOT];
  u16*   As  = (u16*)smem;                 // stride 232 u16
  u16*   xth = (u16*)smem;                 // stride 120 u16, overlays As after MFMA
  u16*   eL  = (u16*)(smem + G_EL);        // stride 36 u16 (overlay, dead after pack)
  float* aL  = (float*)(smem + G_AL);      // stride 7 floats (overlay)
  u16*   BsA[2] = {(u16*)(smem + G_BS0), (u16*)(smem + G_BS1)};
  int tid = threadIdx.x;
  int wave = tid >> 6, lane = tid & 63, l15 = lane & 15, quad = lane >> 4;
  int row0 = blockIdx.x * 128;
  int nbase = half * 112;

  // stage edge rows (padded stride 36) + atts
  for (int e = tid; e < 1024; e += 256){
    int r = e >> 3, q = e & 7;
    *(uint2*)(eL + r*36 + q*4) = *(const uint2*)(edge + (size_t)(row0 + r)*32 + q*4);
  }
  for (int e = tid; e < 896; e += 256) aL[e] = atts[(size_t)row0*7 + e];
  floatx4 acc[2][7];
  #pragma unroll
  for (int mt = 0; mt < 2; ++mt)
    #pragma unroll
    for (int nt = 0; nt < 7; ++nt)
      acc[mt][nt] = (floatx4){0.f, 0.f, 0.f, 0.f};
  __syncthreads();

  // pack full A-tile once: thread t -> row t>>1, column half (t&1)*112
  {
    int pr = tid >> 1, pp = tid & 1;
    u32* asw = (u32*)As + pr*116 + pp*56;
    const u16* er = eL + pr*36 + pp*16;
    const float* ar = aL + pr*7;
    float av[7];
    #pragma unroll
    for (int hh = 0; hh < 7; ++hh) av[hh] = ar[hh];
    #pragma unroll
    for (int fo = 0; fo < 8; ++fo){
      float e0 = b2f(er[2*fo]);
      float e1 = b2f(er[2*fo+1]);
      u16 w[14];
      #pragma unroll
      for (int hh = 0; hh < 7; ++hh){
        w[hh]   = f2b(e0 * av[hh]);
        w[7+hh] = f2b(e1 * av[hh]);
      }
      #pragma unroll
      for (int k = 0; k < 7; ++k)
        asw[fo*7 + k] = (u32)w[2*k] | ((u32)w[2*k+1] << 16);
    }
  }
  __syncthreads();          // As ready; eL/aL dead -> Bs buffers usable

  // prologue: stage Bs[0] for kt=0
  for (int e = tid; e < 448; e += 256){
    int r = e >> 2, q = e & 3;
    *(uint4*)(BsA[0] + r*40 + q*8) = *(const uint4*)(BT + (size_t)(nbase + r)*224 + q*8);
  }
  int cur = 0;
  for (int kt = 0; kt < 7; ++kt){
    __syncthreads();        // Bs[cur] visible; prior MFMA reads of Bs[cur^1] done
    if (kt < 6){
      int kk = (kt + 1) * 32;
      u16* bn = BsA[cur ^ 1];
      for (int e = tid; e < 448; e += 256){
        int r = e >> 2, q = e & 3;
        *(uint4*)(bn + r*40 + q*8) = *(const uint4*)(BT + (size_t)(nbase + r)*224 + kk + q*8);
      }
    }
    int kk = kt * 32;
    short8 a0 = *(const short8*)(As + (wave*32 + l15)*232 + kk + quad*8);
    short8 a1 = *(const short8*)(As + (wave*32 + 16 + l15)*232 + kk + quad*8);
    const u16* bs = BsA[cur];
    #pragma unroll
    for (int nt = 0; nt < 7; ++nt){
      short8 b = *(const short8*)(bs + (nt*16 + l15)*40 + quad*8);
      acc[0][nt] = __builtin_amdgcn_mfma_f32_16x16x32_bf16(a0, b, acc[0][nt], 0, 0, 0);
      acc[1][nt] = __builtin_amdgcn_mfma_f32_16x16x32_bf16(a1, b, acc[1][nt], 0, 0, 0);
    }
    cur ^= 1;
  }
  __syncthreads();          // all MFMA As reads done before xth overlays As

  // tanh epilogue -> xth (stride 120), wave-local rows
  #pragma unroll
  for (int mt = 0; mt < 2; ++mt)
    #pragma unroll
    for (int nt = 0; nt < 7; ++nt)
      #pragma unroll
      for (int reg = 0; reg < 4; ++reg){
        int r = wave*32 + mt*16 + quad*4 + reg;
        int c = nt*16 + l15;
        float vv = acc[mt][nt][reg];
        vv = fminf(fmaxf(vv, -15.f), 15.f);
        float e2 = __expf(2.f * vv);
        xth[r*120 + c] = f2b((e2 - 1.f) / (e2 + 1.f));
      }
  // coalesced copy-out (wave-local rows: thread t -> row t>>1)
  {
    int r = tid >> 1, part = tid & 1;
    const uint4* src = (const uint4*)(xth + r*120 + part*56);
    uint4* dst = (uint4*)(xhalf + (size_t)(row0 + r)*112 + part*56);
    #pragma unroll
    for (int q = 0; q < 7; ++q) dst[q] = src[q];
  }
}

// -------- atom-centric comb reduction: xhalf -> nsq half + pv partial -------
// 16 lanes per atom; lane owns channels c_local = lane + 16k, k=0..6. No atomics.
__global__ __launch_bounds__(256) void k_comb(const int* __restrict__ offs,
    const u16* __restrict__ xhalf, const float* __restrict__ dirs,
    const float* __restrict__ Wf, int half,
    float* __restrict__ nsq, float* __restrict__ pvh){
  int a = blockIdx.x * 16 + (threadIdx.x >> 4);   // N = 625*16
  int lane = threadIdx.x & 15;
  int off = offs[a], end = offs[a+1];
  float c0[7] = {0,0,0,0,0,0,0}, c1[7] = {0,0,0,0,0,0,0}, c2[7] = {0,0,0,0,0,0,0};
  for (int s = off; s < end; ++s){
    float d0 = dirs[s*3+0], d1 = dirs[s*3+1], d2 = dirs[s*3+2];
    const u16* xr = xhalf + (size_t)s * 112 + lane;
    #pragma unroll
    for (int k = 0; k < 7; ++k){
      float xm = b2f(xr[k*16]);
      c0[k] += d0 * xm; c1[k] += d1 * xm; c2[k] += d2 * xm;
    }
  }
  float inv = 1.f / fmaxf((float)(end - off), 1.f);
  float pv0 = 0.f, pv1 = 0.f, pv2 = 0.f;
  #pragma unroll
  for (int k = 0; k < 7; ++k){
    float m0 = c0[k]*inv, m1 = c1[k]*inv, m2 = c2[k]*inv;
    int c = half*112 + k*16 + lane;
    nsq[(size_t)a*224 + c] = m0*m0 + m1*m1 + m2*m2;
    float wv = Wf[OFF_WVMIX + c];
    pv0 += wv*m0; pv1 += wv*m1; pv2 += wv*m2;
  }
  #pragma unroll
  for (int m = 8; m >= 1; m >>= 1){
    pv0 += __shfl_xor(pv0, m); pv1 += __shfl_xor(pv1, m); pv2 += __shfl_xor(pv2, m);
  }
  if (lane == 0){
    float* pp = pvh + (size_t)half*30000 + (size_t)a*3;
    pp[0] = pv0; pp[1] = pv1; pp[2] = pv2;
  }
}

// ---------------- final: wave per atom, precomputed hsem/nsq/pv -------------
__global__ __launch_bounds__(256) void k_final4(const float* __restrict__ h,
    const float* __restrict__ x, const float* __restrict__ v,
    const float* __restrict__ Wf, const float* __restrict__ hsem,
    const float* __restrict__ nsq, const float* __restrict__ pvh,
    float* __restrict__ out){
  __shared__ float s_in[4][288];     // [0:32)=h, [32:256)=hsem, [256:288)=sp
  __shared__ float s_nsq[4][224];
  __shared__ float s_u1[4][32], s_g[4][32], s_un[4][32];
  int wv_ = threadIdx.x >> 6, lane = threadIdx.x & 63;
  int a = blockIdx.x * 4 + wv_;                 // N = 2500*4
  if (lane < 56){
    int c4 = lane * 4;
    float4 hs = *(const float4*)(hsem + (size_t)a*224 + c4);
    float4 nq = *(const float4*)(nsq + (size_t)a*224 + c4);
    s_in[wv_][32 + c4+0] = hs.x; s_in[wv_][32 + c4+1] = hs.y;
    s_in[wv_][32 + c4+2] = hs.z; s_in[wv_][32 + c4+3] = hs.w;
    s_nsq[wv_][c4+0] = nq.x; s_nsq[wv_][c4+1] = nq.y;
    s_nsq[wv_][c4+2] = nq.z; s_nsq[wv_][c4+3] = nq.w;
  } else {
    int k4 = (lane - 56) * 4;
    float4 hv = *(const float4*)(h + (size_t)a*32 + k4);
    s_in[wv_][k4+0] = hv.x; s_in[wv_][k4+1] = hv.y;
    s_in[wv_][k4+2] = hv.z; s_in[wv_][k4+3] = hv.w;
  }
  __syncthreads();
  int o = lane & 31, kh = lane >> 5;
  // p1 (K=224), K-split across wave halves
  {
    float u = 0.f;
    const float* q = &s_nsq[wv_][kh*112];
    const float* w = Wf + OFF_WP1 + (kh*112)*32 + o;
    #pragma unroll 4
    for (int kk = 0; kk < 112; ++kk) u += q[kk] * w[kk*32];
    u += __shfl_xor(u, 32);
    if (lane < 32) s_u1[wv_][o] = siluf(u + Wf[OFF_BP1 + o]);
  }
  // g = silu(h @ Wv1 + b), K=32 split 16/16
  {
    float g = 0.f;
    const float* q = &s_in[wv_][kh*16];
    const float* w = Wf + OFF_WV1 + (kh*16)*32 + o;
    #pragma unroll
    for (int kk = 0; kk < 16; ++kk) g += q[kk] * w[kk*32];
    g += __shfl_xor(g, 32);
    if (lane < 32) s_g[wv_][o] = siluf(g + Wf[OFF_BV1 + o]);
  }
  __syncthreads();
  float zpart = (lane < 32) ? s_g[wv_][lane] * Wf[OFF_WV2 + lane] : 0.f;
  #pragma unroll
  for (int m = 32; m >= 1; m >>= 1) zpart += __shfl_xor(zpart, m);
  float sc = 2.f / (1.f + __expf(-zpart));
  // p2 (K=32) split 16/16 -> s_in[256..288)
  {
    float u = 0.f;
    const float* q = &s_u1[wv_][kh*16];
    const float* w = Wf + OFF_WP2 + (kh*16)*32 + o;
    #pragma unroll
    for (int kk = 0; kk < 16; ++kk) u += q[kk] * w[kk*32];
    u += __shfl_xor(u, 32);
    if (lane < 32) s_in[wv_][256 + o] = siluf(u + Wf[OFF_BP2 + o]);
  }
  __syncthreads();
  // n1 (K=288) split 144/144, uniform via staged s_in
  {
    float u = 0.f;
    const float* q = &s_in[wv_][kh*144];
    const float* w = Wf + OFF_WN1 + (kh*144)*32 + o;
    #pragma unroll 4
    for (int kk = 0; kk < 144; ++kk) u += q[kk] * w[kk*32];
    u += __shfl_xor(u, 32);
    if (lane < 32) s_un[wv_][o] = siluf(u + Wf[OFF_BN1 + o]);
  }
  __syncthreads();
  if (lane < 32){
    float u = Wf[OFF_BN2 + lane];
    #pragma unroll
    for (int k = 0; k < 32; ++k) u += s_un[wv_][k] * Wf[OFF_WN2 + k*32 + lane];
    out[a*32 + lane] = s_in[wv_][lane] + siluf(u);
  }
  if (lane < 3){
    float pv = pvh[(size_t)a*3 + lane] + pvh[30000 + (size_t)a*3 + lane];
    float vup = sc * v[a*3+lane] + pv;
    float xup = x[a*3+lane] + vup;
    out[N_ATOMS*32 + a*3 + lane] = xup;
    out[N_ATOMS*32 + N_ATOMS*3 + a*3 + lane] = vup;
  }
}

// ---------------- workspace layout ----------------
static constexpr size_t al256(size_t x){ return (x + 255) & ~(size_t)255; }
static constexpr size_t WS_FLAGS   = 0;
static constexpr size_t WS_COUNTS  = al256(WS_FLAGS + 8);
static constexpr size_t WS_OFFSETS = al256(WS_COUNTS + (size_t)N_ATOMS * 4);
static constexpr size_t WS_CURSOR  = al256(WS_OFFSETS + (size_t)(N_ATOMS + 1) * 4);
static constexpr size_t WS_PERM    = al256(WS_CURSOR + (size_t)N_ATOMS * 4);   // isrt
static constexpr size_t WS_PLI     = al256(WS_PERM + (size_t)P_PAIRS * 4);
static constexpr size_t WS_HF      = al256(WS_PLI + (size_t)2 * P_PAIRS * 4);
static constexpr size_t WS_XF      = al256(WS_HF + (size_t)N_ATOMS * 32 * 4);
static constexpr size_t WS_VF      = al256(WS_XF + (size_t)N_ATOMS * 3 * 4);
static constexpr size_t WS_WF      = al256(WS_VF + (size_t)N_ATOMS * 3 * 4);
static constexpr size_t WS_WT      = al256(WS_WF + (size_t)WF_TOTAL * 4);
static constexpr size_t WS_EDGE    = al256(WS_WT + (size_t)224 * 224 * 2);
static constexpr size_t WS_ATTS    = al256(WS_EDGE + (size_t)P_PAIRS * 32 * 2);
static constexpr size_t WS_DIRS    = al256(WS_ATTS + (size_t)P_PAIRS * 7 * 4);
static constexpr size_t WS_LOGITS  = al256(WS_DIRS + (size_t)P_PAIRS * 3 * 4);
// shared region R = [WS_LOGITS, WS_LOGITS+71.68M) (round-1-proven footprint).
// Lifetimes (launch order) make overlaps safe:
//   logits [0, 4.48M)         : k_pair -> k_att
//   prei/prej [4.48M, 8.1M)   : k_atompre -> k_pair (then dead), bf16 stride-88
//   hsem [4.48M, 13.44M)      : k_att writes (prei/prej dead), k_final4 reads
//   xhalf [13.44M, 49.28M)    : k_gemm3(h) writes, k_comb(h) reads; reused h=0,1
//   nsq [49.28M, 58.24M)      : k_comb writes, k_final4 reads
//   pvh [58.24M, 58.48M)      : k_comb writes, k_final4 reads
//   jsrt [58.48M, 59.12M)     : k_scatter writes, k_pair reads (dead after)
static constexpr size_t WS_PREI    = al256(WS_LOGITS + (size_t)P_PAIRS * 7 * 4);
static constexpr size_t WS_PREJ    = al256(WS_PREI + (size_t)N_ATOMS * 88 * 2);
static constexpr size_t WS_HSEM    = WS_LOGITS + 4480000;
static constexpr size_t WS_XH      = WS_HSEM + (size_t)N_ATOMS * 224 * 4;           // +8.96M
static constexpr size_t WS_NSQ     = WS_XH + (size_t)P_PAIRS * 112 * 2;             // +35.84M
static constexpr size_t WS_PVH     = WS_NSQ + (size_t)N_ATOMS * 224 * 4;            // +8.96M
static constexpr size_t WS_JSRT    = al256(WS_PVH + (size_t)2 * 30000 * 4);
static constexpr size_t WS_END     = WS_JSRT + (size_t)P_PAIRS * 4;
static_assert(WS_PREJ + (size_t)N_ATOMS * 88 * 2 <= WS_XH, "pre tables before xhalf");
static_assert(WS_END <= WS_LOGITS + (size_t)P_PAIRS * 224 * 2, "within round-1-proven footprint");
static_assert(WS_HSEM % 256 == 0 && WS_XH % 256 == 0 && WS_NSQ % 256 == 0 && WS_PVH % 256 == 0, "alignment");

extern "C" void kernel_launch(void* const* d_in, const int* in_sizes, int n_in,
                              void* d_out, int out_size, void* d_ws, size_t ws_size,
                              hipStream_t stream){
  (void)in_sizes; (void)n_in;
  if (out_size != 380000 || ws_size < WS_END){
    k_code<<<1, 64, 0, stream>>>((float*)d_out, 14000.f);
    return;
  }
  char* ws = (char*)d_ws;
  int*   flags  = (int*)(ws + WS_FLAGS);
  int*   counts = (int*)(ws + WS_COUNTS);
  int*   offs   = (int*)(ws + WS_OFFSETS);
  int*   cursor = (int*)(ws + WS_CURSOR);
  int*   isrt   = (int*)(ws + WS_PERM);
  int*   pli    = (int*)(ws + WS_PLI);
  float* hf     = (float*)(ws + WS_HF);
  float* xf     = (float*)(ws + WS_XF);
  float* vf     = (float*)(ws + WS_VF);
  float* Wf     = (float*)(ws + WS_WF);
  u16*   wT     = (u16*)(ws + WS_WT);
  u16*   edge   = (u16*)(ws + WS_EDGE);
  float* atts   = (float*)(ws + WS_ATTS);
  float* dirs   = (float*)(ws + WS_DIRS);
  float* logits = (float*)(ws + WS_LOGITS);
  u16*   prei   = (u16*)(ws + WS_PREI);
  u16*   prej   = (u16*)(ws + WS_PREJ);
  float* hsem   = (float*)(ws + WS_HSEM);
  u16*   xhalf  = (u16*)(ws + WS_XH);
  float* nsq    = (float*)(ws + WS_NSQ);
  float* pvh    = (float*)(ws + WS_PVH);
  int*   jsrt   = (int*)(ws + WS_JSRT);

  hipMemsetAsync(counts, 0, (size_t)N_ATOMS * 4, stream);
  k_detect<<<1, 64, 0, stream>>>((const u32*)d_in[0], (const u32*)d_in[3], flags);
  k_norm<<<(700000 + 255) / 256, 256, 0, stream>>>(d_in[0], d_in[1], d_in[2], d_in[3],
                                                   flags, hf, xf, vf, pli);
  k_convert<<<(WF_TOTAL + 255) / 256, 256, 0, stream>>>(
      d_in[4],  d_in[5],  d_in[6],  d_in[7],  d_in[8],  d_in[9],  d_in[10], d_in[11],
      d_in[12], d_in[13], d_in[14], d_in[15], d_in[16], d_in[17], d_in[18], d_in[19],
      d_in[20], d_in[21], d_in[22], d_in[24], flags, Wf);
  k_transpose<<<(224 * 224 + 255) / 256, 256, 0, stream>>>(d_in[23], flags, wT);
  k_atompre<<<N_ATOMS, 192, 0, stream>>>(hf, Wf, prei, prej);
  k_hist<<<P_PAIRS / 256, 256, 0, stream>>>(pli, counts);
  k_scan<<<1, 256, 0, stream>>>(counts, offs, cursor);
  k_scatter<<<P_PAIRS / 256, 256, 0, stream>>>(pli, cursor, isrt, jsrt);
  k_pair<<<P_PAIRS / 64, 64, 0, stream>>>(xf, Wf, prei, prej, isrt, jsrt, edge, logits, dirs);
  k_att<<<N_ATOMS / 16, 256, 0, stream>>>(offs, logits, edge, atts, hsem);
  k_gemm3<<<P_PAIRS / 128, 256, 0, stream>>>(edge, atts, wT, xhalf, 0);
  k_comb<<<N_ATOMS / 16, 256, 0, stream>>>(offs, xhalf, dirs, Wf, 0, nsq, pvh);
  k_gemm3<<<P_PAIRS / 128, 256, 0, stream>>>(edge, atts, wT, xhalf, 1);
  k_comb<<<N_ATOMS / 16, 256, 0, stream>>>(offs, xhalf, dirs, Wf, 1, nsq, pvh);
  k_final4<<<N_ATOMS / 4, 256, 0, stream>>>(hf, xf, vf, Wf, hsem, nsq, pvh, (float*)d_out);
}

// Round 7
// 388.996 us; speedup vs baseline: 1.1208x; 1.1037x over previous
//
#include <hip/hip_runtime.h>

typedef unsigned short u16;
typedef unsigned int u32;
typedef __attribute__((ext_vector_type(8))) short short8;
typedef __attribute__((ext_vector_type(4))) float floatx4;

#define P_PAIRS 160000
#define N_ATOMS 10000

#define OFF_WMLP  0      // stored TRANSPOSED: [50][64], (o,k) at o*64+k
#define OFF_BMLP  3200
#define OFF_WE1   3250
#define OFF_BE1   6930
#define OFF_WE2   6962
#define OFF_BE2   7986
#define OFF_WATT  8018
#define OFF_BATT  8242
#define OFF_WN1   8249
#define OFF_BN1   17465
#define OFF_WN2   17497
#define OFF_BN2   18521
#define OFF_WP1   18553
#define OFF_BP1   25721
#define OFF_WP2   25753
#define OFF_BP2   26777
#define OFF_WV1   26809
#define OFF_BV1   27833
#define OFF_WV2   27865
#define OFF_WVMIX 27897
#define WF_TOTAL  28121

__device__ __forceinline__ float b2f(u16 u){ return __uint_as_float(((u32)u) << 16); }
__device__ __forceinline__ u16 f2b(float f){
  u32 u = __float_as_uint(f);
  u32 r = (u + 0x7FFFu + ((u >> 16) & 1u)) >> 16;
  return (u16)r;
}
__device__ __forceinline__ void unpack2(u32 p, float& lo, float& hi){
  lo = __uint_as_float(p << 16);
  hi = __uint_as_float(p & 0xFFFF0000u);
}
__device__ __forceinline__ float siluf(float v){ return v / (1.f + __expf(-v)); }
__device__ __forceinline__ float ldw(const void* p, int o, int bf){
  return bf ? b2f(((const u16*)p)[o]) : ((const float*)p)[o];
}

__global__ void k_code(float* out, float code){
  if (threadIdx.x == 0 && blockIdx.x == 0) out[0] = code;
}

// per-block dtype detection (wave 0 ballot), replaces k_detect dispatch
__device__ __forceinline__ void detect_flags(const u32* hw, const u32* plw, int* s_fl){
  int tid = threadIdx.x;
  if (tid < 64){
    u32 e = (hw[tid] >> 7) & 0xFFu;
    unsigned long long m1 = __ballot(e >= 100u && e <= 140u);
    unsigned long long m2 = __ballot(plw[2*tid+1] == 0u);
    if (tid == 0){
      s_fl[0] = (__popcll(m1) >= 48) ? 1 : 0;
      s_fl[1] = (__popcll(m2) >= 60) ? 1 : 0;
    }
  }
  __syncthreads();
}

// ------------- fused preprocessing: norm + convert + transpose + bpk + hist -
#define NBP_NORM 2735
#define NBP_CONV (NBP_NORM + 110)
#define NBP_TRAN (NBP_CONV + 196)
#define NBP_PB   (NBP_TRAN + 14)
#define NBP_HIST (NBP_PB + 625)

__global__ void k_prep(const void* __restrict__ h_raw, const void* __restrict__ x_raw,
    const void* __restrict__ v_raw, const void* __restrict__ pl_raw,
    const void* w_mlp, const void* b_mlp, const void* w_e1, const void* b_e1,
    const void* w_e2, const void* b_e2, const void* w_att, const void* b_att,
    const void* w_n1, const void* b_n1, const void* w_n2, const void* b_n2,
    const void* w_p1, const void* b_p1, const void* w_p2, const void* b_p2,
    const void* w_v1, const void* b_v1, const void* w_v2, const void* w_vmix,
    const void* wx,
    float* __restrict__ hf, float* __restrict__ xf, float* __restrict__ vf,
    int* __restrict__ pli, float* __restrict__ Wf, u16* __restrict__ wT,
    u16* __restrict__ bpk, int* __restrict__ counts){
  __shared__ int s_fl[2];
  detect_flags((const u32*)h_raw, (const u32*)pl_raw, s_fl);
  int bf = s_fl[0], i64 = s_fl[1];
  int bid = blockIdx.x, tid = threadIdx.x;
  if (bid < NBP_NORM){
    int t = bid * 256 + tid;
    if (t < 320000){
      hf[t] = ldw(h_raw, t, bf);
    } else if (t < 350000){
      int i = t - 320000; xf[i] = ldw(x_raw, i, bf);
    } else if (t < 380000){
      int i = t - 350000; vf[i] = ldw(v_raw, i, bf);
    } else if (t < 700000){
      int k = t - 380000;
      const int* p32 = (const int*)pl_raw;
      pli[k] = i64 ? p32[2*(size_t)k] : p32[k];
    }
  } else if (bid < NBP_CONV){
    int t = (bid - NBP_NORM) * 256 + tid;
    if (t >= WF_TOTAL) return;
    if (t < 3200){
      int k = t / 50, o = t - k * 50;
      Wf[OFF_WMLP + o * 64 + k] = ldw(w_mlp, t, bf);
      return;
    }
    const void* src; int o;
    if      (t < 3250)  { src = b_mlp;  o = t - 3200; }
    else if (t < 6930)  { src = w_e1;   o = t - 3250; }
    else if (t < 6962)  { src = b_e1;   o = t - 6930; }
    else if (t < 7986)  { src = w_e2;   o = t - 6962; }
    else if (t < 8018)  { src = b_e2;   o = t - 7986; }
    else if (t < 8242)  { src = w_att;  o = t - 8018; }
    else if (t < 8249)  { src = b_att;  o = t - 8242; }
    else if (t < 17465) { src = w_n1;   o = t - 8249; }
    else if (t < 17497) { src = b_n1;   o = t - 17465; }
    else if (t < 18521) { src = w_n2;   o = t - 17497; }
    else if (t < 18553) { src = b_n2;   o = t - 18521; }
    else if (t < 25721) { src = w_p1;   o = t - 18553; }
    else if (t < 25753) { src = b_p1;   o = t - 25721; }
    else if (t < 26777) { src = w_p2;   o = t - 25753; }
    else if (t < 26809) { src = b_p2;   o = t - 26777; }
    else if (t < 27833) { src = w_v1;   o = t - 26809; }
    else if (t < 27865) { src = b_v1;   o = t - 27833; }
    else if (t < 27897) { src = w_v2;   o = t - 27865; }
    else                { src = w_vmix; o = t - 27897; }
    Wf[t] = ldw(src, o, bf);
  } else if (bid < NBP_TRAN){
    int t = (bid - NBP_CONV) * 256 + tid;
    if (t >= 224 * 224) return;
    int n = t / 224, k = t - n * 224;
    wT[t] = f2b(ldw(wx, k * 224 + n, bf));
  } else if (bid < NBP_PB){
    // bpk: B1T [32][64] | B2T [32][32] | B3T [16][32]  (bf16, from RAW weights)
    int t = (bid - NBP_TRAN) * 256 + tid;
    if (t >= 3584) return;
    float v = 0.f;
    if (t < 2048){
      int n = t >> 6, k = t & 63;
      if (k < 50)       v = ldw(w_e1, (64 + k) * 32 + n, bf);
      else if (k == 50) v = ldw(w_e1, 114 * 32 + n, bf);
    } else if (t < 3072){
      int e = t - 2048; int n = e >> 5, k = e & 31;
      v = ldw(w_e2, k * 32 + n, bf);
    } else {
      int e = t - 3072; int n = e >> 5, k = e & 31;
      if (n < 7) v = ldw(w_att, k * 7 + n, bf);
    }
    bpk[t] = f2b(v);
  } else {
    int p = (bid - NBP_PB) * 256 + tid;     // hist from raw pairlist
    const int* p32 = (const int*)pl_raw;
    int i = i64 ? p32[2*(size_t)p] : p32[p];
    atomicAdd(&counts[i], 1);
  }
}

// ---------- fused: per-atom projections (10000 blocks) + scan (1 block) -----
__global__ void k_atomscan(const float* __restrict__ hf, const float* __restrict__ Wf,
    u16* __restrict__ prei, u16* __restrict__ prej,
    const int* __restrict__ counts, int* __restrict__ offs, int* __restrict__ cursor){
  __shared__ float hs[32];
  __shared__ int part[256];
  if (blockIdx.x < N_ATOMS){
    int a = blockIdx.x, r = threadIdx.x;
    if (r < 32) hs[r] = hf[(size_t)a * 32 + r];
    __syncthreads();
    if (r < 50){
      const float* wm = Wf + OFF_WMLP + r * 64;
      float acc = Wf[OFF_BMLP + r];
      #pragma unroll
      for (int k = 0; k < 32; ++k) acc += hs[k] * wm[k];
      prei[(size_t)a * 88 + 32 + r] = f2b(acc);
    } else if (r < 100){
      int kk = r - 50;
      const float* wm = Wf + OFF_WMLP + kk * 64 + 32;
      float acc = 0.f;
      #pragma unroll
      for (int k = 0; k < 32; ++k) acc += hs[k] * wm[k];
      prej[(size_t)a * 88 + 32 + kk] = f2b(acc);
    } else if (r < 132){
      int o = r - 100;
      float acc = Wf[OFF_BE1 + o];
      #pragma unroll
      for (int k = 0; k < 32; ++k) acc += hs[k] * Wf[OFF_WE1 + k * 32 + o];
      prei[(size_t)a * 88 + o] = f2b(acc);
    } else if (r < 164){
      int o = r - 132;
      float acc = 0.f;
      #pragma unroll
      for (int k = 0; k < 32; ++k) acc += hs[k] * Wf[OFF_WE1 + (32 + k) * 32 + o];
      prej[(size_t)a * 88 + o] = f2b(acc);
    }
  } else {
    int t = threadIdx.x;
    int sum = 0;
    for (int k = 0; k < 40; ++k){
      int idx = t * 40 + k;
      if (idx < N_ATOMS) sum += counts[idx];
    }
    part[t] = sum;
    __syncthreads();
    if (t == 0){
      int run = 0;
      for (int q = 0; q < 256; ++q){ int tmp = part[q]; part[q] = run; run += tmp; }
    }
    __syncthreads();
    int run = part[t];
    for (int k = 0; k < 40; ++k){
      int idx = t * 40 + k;
      if (idx < N_ATOMS){ offs[idx] = run; cursor[idx] = run; run += counts[idx]; }
    }
    if (t == 0) offs[N_ATOMS] = P_PAIRS;
  }
}

__global__ void k_scatter(const int* __restrict__ pl, int* __restrict__ cursor,
                          int* __restrict__ isrt, int* __restrict__ jsrt){
  int p = blockIdx.x * 256 + threadIdx.x;
  int i = pl[p];
  int pos = atomicAdd(&cursor[i], 1);
  isrt[pos] = i;
  jsrt[pos] = pl[P_PAIRS + p];
}

// ------- per-pair edge model via MFMA: 128 pairs/block, 4 waves -------------
// LDS: UB f32[128][32] | TB u16[128][56] | DD f32[128] | A1 u16[128][72]
//      B1 u16[32][72] | A2 u16[128][40] (silu-u, then eg) | B2 u16[32][40] | B3 u16[16][40]
#define PM_UB   0
#define PM_TB   16384
#define PM_DD   30720
#define PM_A1   31232
#define PM_B1   49664
#define PM_A2   54272
#define PM_B2   64512
#define PM_B3   67072
#define PM_TOT  68352

__global__ __launch_bounds__(256) void k_pairm(const float* __restrict__ x,
    const float* __restrict__ Wf, const u16* __restrict__ prei, const u16* __restrict__ prej,
    const int* __restrict__ isrt, const int* __restrict__ jsrt, const u16* __restrict__ bpk,
    u16* __restrict__ edge, float* __restrict__ logits, float* __restrict__ dirs){
  __shared__ __attribute__((aligned(16))) char smem[PM_TOT];
  float* UB = (float*)(smem + PM_UB);
  u16*   TB = (u16*)(smem + PM_TB);
  float* DD = (float*)(smem + PM_DD);
  u16*   A1 = (u16*)(smem + PM_A1);
  u16*   B1 = (u16*)(smem + PM_B1);
  u16*   A2 = (u16*)(smem + PM_A2);
  u16*   B2 = (u16*)(smem + PM_B2);
  u16*   B3 = (u16*)(smem + PM_B3);
  int tid = threadIdx.x;
  int wave = tid >> 6, lane = tid & 63, l15 = lane & 15, quad = lane >> 4;
  int row0 = blockIdx.x * 128;

  if (tid < 128){
    int s = row0 + tid;
    int i = isrt[s], j = jsrt[s];
    float r0 = x[j*3+0] - x[i*3+0];
    float r1 = x[j*3+1] - x[i*3+1];
    float r2 = x[j*3+2] - x[i*3+2];
    float d = sqrtf(r0*r0 + r1*r1 + r2*r2);
    float rinv = 1.f / (d + 1e-5f);
    dirs[s*3+0] = r0*rinv; dirs[s*3+1] = r1*rinv; dirs[s*3+2] = r2*rinv;
    DD[tid] = d;
    const uint4* pi4 = (const uint4*)(prei + (size_t)i * 88);
    const uint4* pj4 = (const uint4*)(prej + (size_t)j * 88);
    float* ub = UB + tid * 32;
    #pragma unroll
    for (int q = 0; q < 4; ++q){
      uint4 a4 = pi4[q], b4 = pj4[q];
      u32 pa[4] = {a4.x, a4.y, a4.z, a4.w};
      u32 pb[4] = {b4.x, b4.y, b4.z, b4.w};
      #pragma unroll
      for (int w2 = 0; w2 < 4; ++w2){
        float al, ah, bl, bh;
        unpack2(pa[w2], al, ah); unpack2(pb[w2], bl, bh);
        ub[q*8 + w2*2]     = al + bl;
        ub[q*8 + w2*2 + 1] = ah + bh;
      }
    }
    u32* tb = (u32*)TB + tid * 28;
    #pragma unroll
    for (int q = 0; q < 7; ++q){
      uint4 a4 = pi4[4+q], b4 = pj4[4+q];
      u32 pa[4] = {a4.x, a4.y, a4.z, a4.w};
      u32 pb[4] = {b4.x, b4.y, b4.z, b4.w};
      #pragma unroll
      for (int w2 = 0; w2 < 4; ++w2){
        float al, ah, bl, bh;
        unpack2(pa[w2], al, ah); unpack2(pb[w2], bl, bh);
        tb[q*4 + w2] = (u32)f2b(al + bl) | ((u32)f2b(ah + bh) << 16);
      }
    }
  } else {
    int t2 = tid - 128;
    const u32* src = (const u32*)bpk;
    for (int e = t2; e < 1024; e += 128){         // B1T [32][64] -> stride 36 u32
      int n = e >> 5, kp = e & 31;
      ((u32*)B1)[n*36 + kp] = src[e];
    }
    for (int e = t2; e < 512; e += 128){          // B2T [32][32] -> stride 20 u32
      int n = e >> 4, kp = e & 15;
      ((u32*)B2)[n*20 + kp] = src[1024 + e];
    }
    for (int e = t2; e < 256; e += 128){          // B3T [16][32] -> stride 20 u32
      int n = e >> 4, kp = e & 15;
      ((u32*)B3)[n*20 + kp] = src[1536 + e];
    }
  }
  __syncthreads();
  // A1 [128][72-stride]: cols 0..49 filt, col 50 = d, 51..63 = 0
  for (int e = tid; e < 4096; e += 256){
    int r = e >> 5, kp = e & 31;
    int k0 = kp * 2, k1 = k0 + 1;
    float d = DD[r];
    float v0 = 0.f, v1 = 0.f;
    if (k0 < 50){
      float t0 = b2f(TB[r*56 + k0]);
      float c0 = (float)k0 * (5.f/49.f), dd0 = d - c0;
      v0 = t0 * __expf(-10.f * dd0 * dd0);
    } else if (k0 == 50) v0 = d;
    if (k1 < 50){
      float t1 = b2f(TB[r*56 + k1]);
      float c1 = (float)k1 * (5.f/49.f), dd1 = d - c1;
      v1 = t1 * __expf(-10.f * dd1 * dd1);
    }
    ((u32*)A1)[r*36 + kp] = (u32)f2b(v0) | ((u32)f2b(v1) << 16);
  }
  __syncthreads();
  // u = A1 @ B1 + UB  (M=128 N=32 K=64)
  floatx4 au[2][2];
  #pragma unroll
  for (int mt = 0; mt < 2; ++mt)
    #pragma unroll
    for (int nt = 0; nt < 2; ++nt) au[mt][nt] = (floatx4){0.f,0.f,0.f,0.f};
  #pragma unroll
  for (int ks = 0; ks < 2; ++ks){
    int kk = ks * 32;
    short8 a0 = *(const short8*)(A1 + (wave*32 + l15)*72 + kk + quad*8);
    short8 a1 = *(const short8*)(A1 + (wave*32 + 16 + l15)*72 + kk + quad*8);
    #pragma unroll
    for (int nt = 0; nt < 2; ++nt){
      short8 b = *(const short8*)(B1 + (nt*16 + l15)*72 + kk + quad*8);
      au[0][nt] = __builtin_amdgcn_mfma_f32_16x16x32_bf16(a0, b, au[0][nt], 0, 0, 0);
      au[1][nt] = __builtin_amdgcn_mfma_f32_16x16x32_bf16(a1, b, au[1][nt], 0, 0, 0);
    }
  }
  #pragma unroll
  for (int mt = 0; mt < 2; ++mt)
    #pragma unroll
    for (int nt = 0; nt < 2; ++nt)
      #pragma unroll
      for (int reg = 0; reg < 4; ++reg){
        int r = wave*32 + mt*16 + quad*4 + reg;
        int c = nt*16 + l15;
        float uval = au[mt][nt][reg] + UB[r*32 + c];
        A2[r*40 + c] = f2b(siluf(uval));
      }
  __syncthreads();
  // eg = A2 @ B2 (M=128 N=32 K=32)
  floatx4 ae[2][2];
  #pragma unroll
  for (int mt = 0; mt < 2; ++mt)
    #pragma unroll
    for (int nt = 0; nt < 2; ++nt) ae[mt][nt] = (floatx4){0.f,0.f,0.f,0.f};
  {
    short8 a0 = *(const short8*)(A2 + (wave*32 + l15)*40 + quad*8);
    short8 a1 = *(const short8*)(A2 + (wave*32 + 16 + l15)*40 + quad*8);
    #pragma unroll
    for (int nt = 0; nt < 2; ++nt){
      short8 b = *(const short8*)(B2 + (nt*16 + l15)*40 + quad*8);
      ae[0][nt] = __builtin_amdgcn_mfma_f32_16x16x32_bf16(a0, b, ae[0][nt], 0, 0, 0);
      ae[1][nt] = __builtin_amdgcn_mfma_f32_16x16x32_bf16(a1, b, ae[1][nt], 0, 0, 0);
    }
  }
  __syncthreads();    // all A2 (silu-u) reads done before overwrite with eg
  #pragma unroll
  for (int mt = 0; mt < 2; ++mt)
    #pragma unroll
    for (int nt = 0; nt < 2; ++nt)
      #pragma unroll
      for (int reg = 0; reg < 4; ++reg){
        int r = wave*32 + mt*16 + quad*4 + reg;
        int c = nt*16 + l15;
        float ev = ae[mt][nt][reg] + Wf[OFF_BE2 + c];
        A2[r*40 + c] = f2b(ev);
      }
  __syncthreads();
  // edge copy-out (coalesced)
  {
    int r = tid >> 1, p = tid & 1;
    const uint4* srcp = (const uint4*)(A2 + r*40 + p*16);
    uint4* dstp = (uint4*)(edge + (size_t)(row0 + r)*32 + p*16);
    dstp[0] = srcp[0]; dstp[1] = srcp[1];
  }
  // logits = celu(A2 @ B3 + batt)  (N=16, 7 used)
  floatx4 al_[2];
  al_[0] = (floatx4){0.f,0.f,0.f,0.f};
  al_[1] = (floatx4){0.f,0.f,0.f,0.f};
  {
    short8 a0 = *(const short8*)(A2 + (wave*32 + l15)*40 + quad*8);
    short8 a1 = *(const short8*)(A2 + (wave*32 + 16 + l15)*40 + quad*8);
    short8 b = *(const short8*)(B3 + l15*40 + quad*8);
    al_[0] = __builtin_amdgcn_mfma_f32_16x16x32_bf16(a0, b, al_[0], 0, 0, 0);
    al_[1] = __builtin_amdgcn_mfma_f32_16x16x32_bf16(a1, b, al_[1], 0, 0, 0);
  }
  if (l15 < 7){
    float ba = Wf[OFF_BATT + l15];
    #pragma unroll
    for (int mt = 0; mt < 2; ++mt)
      #pragma unroll
      for (int reg = 0; reg < 4; ++reg){
        int r = wave*32 + mt*16 + quad*4 + reg;
        float vv = al_[mt][reg] + ba;
        float cl = vv > 0.f ? vv : 2.f * expm1f(0.5f * vv);
        logits[(size_t)(row0 + r)*7 + l15] = cl;
      }
  }
}

// -------- segment softmax + hsem accumulation (16-lane group per atom) ------
__global__ __launch_bounds__(256) void k_att(const int* __restrict__ offs,
    const float* __restrict__ logits, const u16* __restrict__ edge,
    float* __restrict__ atts, float* __restrict__ hsem){
  int a = blockIdx.x * 16 + (threadIdx.x >> 4);   // N = 625*16
  int lane = threadIdx.x & 15;
  int off = offs[a], end = offs[a+1];
  float m[7];
  #pragma unroll
  for (int hh = 0; hh < 7; ++hh) m[hh] = -1e30f;
  for (int s = off + lane; s < end; s += 16){
    #pragma unroll
    for (int hh = 0; hh < 7; ++hh) m[hh] = fmaxf(m[hh], logits[s*7+hh]);
  }
  #pragma unroll
  for (int hh = 0; hh < 7; ++hh){
    float v = m[hh];
    #pragma unroll
    for (int msk = 8; msk >= 1; msk >>= 1) v = fmaxf(v, __shfl_xor(v, msk));
    m[hh] = v;
  }
  float sm[7] = {0,0,0,0,0,0,0};
  for (int s = off + lane; s < end; s += 16){
    #pragma unroll
    for (int hh = 0; hh < 7; ++hh){
      float e = __expf(logits[s*7+hh] - m[hh]);
      sm[hh] += e;
      atts[s*7+hh] = e;
    }
  }
  #pragma unroll
  for (int hh = 0; hh < 7; ++hh){
    float v = sm[hh];
    #pragma unroll
    for (int msk = 8; msk >= 1; msk >>= 1) v += __shfl_xor(v, msk);
    sm[hh] = 1.f / v;
  }
  for (int s = off + lane; s < end; s += 16){
    #pragma unroll
    for (int hh = 0; hh < 7; ++hh) atts[s*7+hh] *= sm[hh];
  }
  __syncthreads();
  float acc[14] = {0,0,0,0,0,0,0,0,0,0,0,0,0,0};
  for (int s = off; s < end; ++s){
    u32 ev = *(const u32*)(edge + (size_t)s * 32 + lane * 2);
    float e0 = b2f((u16)(ev & 0xFFFFu));
    float e1 = b2f((u16)(ev >> 16));
    const float* ap = atts + (size_t)s * 7;
    #pragma unroll
    for (int hh = 0; hh < 7; ++hh){
      float at = ap[hh];
      acc[hh]     += e0 * at;
      acc[7 + hh] += e1 * at;
    }
  }
  float* hp = hsem + (size_t)a * 224 + lane * 14;
  #pragma unroll
  for (int jj = 0; jj < 14; ++jj) hp[jj] = acc[jj];
}

// -------- MFMA GEMM, half-width (112 cols), NO atomics: writes xhalf bf16 ---
#define G_BS0  59392
#define G_BS1  68352
#define G_EL   59392
#define G_AL   (59392 + 9216)
#define G_TOT  77312

__global__ __launch_bounds__(256) void k_gemm3(const u16* __restrict__ edge,
    const float* __restrict__ atts, const u16* __restrict__ BT,
    u16* __restrict__ xhalf, int half){
  __shared__ __attribute__((aligned(16))) char smem[G_TOT];
  u16*   As  = (u16*)smem;
  u16*   xth = (u16*)smem;
  u16*   eL  = (u16*)(smem + G_EL);
  float* aL  = (float*)(smem + G_AL);
  u16*   BsA[2] = {(u16*)(smem + G_BS0), (u16*)(smem + G_BS1)};
  int tid = threadIdx.x;
  int wave = tid >> 6, lane = tid & 63, l15 = lane & 15, quad = lane >> 4;
  int row0 = blockIdx.x * 128;
  int nbase = half * 112;

  for (int e = tid; e < 1024; e += 256){
    int r = e >> 3, q = e & 7;
    *(uint2*)(eL + r*36 + q*4) = *(const uint2*)(edge + (size_t)(row0 + r)*32 + q*4);
  }
  for (int e = tid; e < 896; e += 256) aL[e] = atts[(size_t)row0*7 + e];
  floatx4 acc[2][7];
  #pragma unroll
  for (int mt = 0; mt < 2; ++mt)
    #pragma unroll
    for (int nt = 0; nt < 7; ++nt)
      acc[mt][nt] = (floatx4){0.f, 0.f, 0.f, 0.f};
  __syncthreads();

  {
    int pr = tid >> 1, pp = tid & 1;
    u32* asw = (u32*)As + pr*116 + pp*56;
    const u16* er = eL + pr*36 + pp*16;
    const float* ar = aL + pr*7;
    float av[7];
    #pragma unroll
    for (int hh = 0; hh < 7; ++hh) av[hh] = ar[hh];
    #pragma unroll
    for (int fo = 0; fo < 8; ++fo){
      float e0 = b2f(er[2*fo]);
      float e1 = b2f(er[2*fo+1]);
      u16 w[14];
      #pragma unroll
      for (int hh = 0; hh < 7; ++hh){
        w[hh]   = f2b(e0 * av[hh]);
        w[7+hh] = f2b(e1 * av[hh]);
      }
      #pragma unroll
      for (int k = 0; k < 7; ++k)
        asw[fo*7 + k] = (u32)w[2*k] | ((u32)w[2*k+1] << 16);
    }
  }
  __syncthreads();

  for (int e = tid; e < 448; e += 256){
    int r = e >> 2, q = e & 3;
    *(uint4*)(BsA[0] + r*40 + q*8) = *(const uint4*)(BT + (size_t)(nbase + r)*224 + q*8);
  }
  int cur = 0;
  for (int kt = 0; kt < 7; ++kt){
    __syncthreads();
    if (kt < 6){
      int kk = (kt + 1) * 32;
      u16* bn = BsA[cur ^ 1];
      for (int e = tid; e < 448; e += 256){
        int r = e >> 2, q = e & 3;
        *(uint4*)(bn + r*40 + q*8) = *(const uint4*)(BT + (size_t)(nbase + r)*224 + kk + q*8);
      }
    }
    int kk = kt * 32;
    short8 a0 = *(const short8*)(As + (wave*32 + l15)*232 + kk + quad*8);
    short8 a1 = *(const short8*)(As + (wave*32 + 16 + l15)*232 + kk + quad*8);
    const u16* bs = BsA[cur];
    #pragma unroll
    for (int nt = 0; nt < 7; ++nt){
      short8 b = *(const short8*)(bs + (nt*16 + l15)*40 + quad*8);
      acc[0][nt] = __builtin_amdgcn_mfma_f32_16x16x32_bf16(a0, b, acc[0][nt], 0, 0, 0);
      acc[1][nt] = __builtin_amdgcn_mfma_f32_16x16x32_bf16(a1, b, acc[1][nt], 0, 0, 0);
    }
    cur ^= 1;
  }
  __syncthreads();

  #pragma unroll
  for (int mt = 0; mt < 2; ++mt)
    #pragma unroll
    for (int nt = 0; nt < 7; ++nt)
      #pragma unroll
      for (int reg = 0; reg < 4; ++reg){
        int r = wave*32 + mt*16 + quad*4 + reg;
        int c = nt*16 + l15;
        float vv = acc[mt][nt][reg];
        vv = fminf(fmaxf(vv, -15.f), 15.f);
        float e2 = __expf(2.f * vv);
        xth[r*120 + c] = f2b((e2 - 1.f) / (e2 + 1.f));
      }
  __syncthreads();
  {
    int r = tid >> 1, part = tid & 1;
    const uint4* src = (const uint4*)(xth + r*120 + part*56);
    uint4* dst = (uint4*)(xhalf + (size_t)(row0 + r)*112 + part*56);
    #pragma unroll
    for (int q = 0; q < 7; ++q) dst[q] = src[q];
  }
}

// -------- atom-centric comb reduction: xhalf -> nsq half + pv partial -------
__global__ __launch_bounds__(256) void k_comb(const int* __restrict__ offs,
    const u16* __restrict__ xhalf, const float* __restrict__ dirs,
    const float* __restrict__ Wf, int half,
    float* __restrict__ nsq, float* __restrict__ pvh){
  int a = blockIdx.x * 16 + (threadIdx.x >> 4);
  int lane = threadIdx.x & 15;
  int off = offs[a], end = offs[a+1];
  float c0[7] = {0,0,0,0,0,0,0}, c1[7] = {0,0,0,0,0,0,0}, c2[7] = {0,0,0,0,0,0,0};
  for (int s = off; s < end; ++s){
    float d0 = dirs[s*3+0], d1 = dirs[s*3+1], d2 = dirs[s*3+2];
    const u16* xr = xhalf + (size_t)s * 112 + lane;
    #pragma unroll
    for (int k = 0; k < 7; ++k){
      float xm = b2f(xr[k*16]);
      c0[k] += d0 * xm; c1[k] += d1 * xm; c2[k] += d2 * xm;
    }
  }
  float inv = 1.f / fmaxf((float)(end - off), 1.f);
  float pv0 = 0.f, pv1 = 0.f, pv2 = 0.f;
  #pragma unroll
  for (int k = 0; k < 7; ++k){
    float m0 = c0[k]*inv, m1 = c1[k]*inv, m2 = c2[k]*inv;
    int c = half*112 + k*16 + lane;
    nsq[(size_t)a*224 + c] = m0*m0 + m1*m1 + m2*m2;
    float wv = Wf[OFF_WVMIX + c];
    pv0 += wv*m0; pv1 += wv*m1; pv2 += wv*m2;
  }
  #pragma unroll
  for (int m = 8; m >= 1; m >>= 1){
    pv0 += __shfl_xor(pv0, m); pv1 += __shfl_xor(pv1, m); pv2 += __shfl_xor(pv2, m);
  }
  if (lane == 0){
    float* pp = pvh + (size_t)half*30000 + (size_t)a*3;
    pp[0] = pv0; pp[1] = pv1; pp[2] = pv2;
  }
}

// ---------------- final: wave per atom, precomputed hsem/nsq/pv -------------
__global__ __launch_bounds__(256) void k_final4(const float* __restrict__ h,
    const float* __restrict__ x, const float* __restrict__ v,
    const float* __restrict__ Wf, const float* __restrict__ hsem,
    const float* __restrict__ nsq, const float* __restrict__ pvh,
    float* __restrict__ out){
  __shared__ float s_in[4][288];
  __shared__ float s_nsq[4][224];
  __shared__ float s_u1[4][32], s_g[4][32], s_un[4][32];
  int wv_ = threadIdx.x >> 6, lane = threadIdx.x & 63;
  int a = blockIdx.x * 4 + wv_;
  if (lane < 56){
    int c4 = lane * 4;
    float4 hs = *(const float4*)(hsem + (size_t)a*224 + c4);
    float4 nq = *(const float4*)(nsq + (size_t)a*224 + c4);
    s_in[wv_][32 + c4+0] = hs.x; s_in[wv_][32 + c4+1] = hs.y;
    s_in[wv_][32 + c4+2] = hs.z; s_in[wv_][32 + c4+3] = hs.w;
    s_nsq[wv_][c4+0] = nq.x; s_nsq[wv_][c4+1] = nq.y;
    s_nsq[wv_][c4+2] = nq.z; s_nsq[wv_][c4+3] = nq.w;
  } else {
    int k4 = (lane - 56) * 4;
    float4 hv = *(const float4*)(h + (size_t)a*32 + k4);
    s_in[wv_][k4+0] = hv.x; s_in[wv_][k4+1] = hv.y;
    s_in[wv_][k4+2] = hv.z; s_in[wv_][k4+3] = hv.w;
  }
  __syncthreads();
  int o = lane & 31, kh = lane >> 5;
  {
    float u = 0.f;
    const float* q = &s_nsq[wv_][kh*112];
    const float* w = Wf + OFF_WP1 + (kh*112)*32 + o;
    #pragma unroll 4
    for (int kk = 0; kk < 112; ++kk) u += q[kk] * w[kk*32];
    u += __shfl_xor(u, 32);
    if (lane < 32) s_u1[wv_][o] = siluf(u + Wf[OFF_BP1 + o]);
  }
  {
    float g = 0.f;
    const float* q = &s_in[wv_][kh*16];
    const float* w = Wf + OFF_WV1 + (kh*16)*32 + o;
    #pragma unroll
    for (int kk = 0; kk < 16; ++kk) g += q[kk] * w[kk*32];
    g += __shfl_xor(g, 32);
    if (lane < 32) s_g[wv_][o] = siluf(g + Wf[OFF_BV1 + o]);
  }
  __syncthreads();
  float zpart = (lane < 32) ? s_g[wv_][lane] * Wf[OFF_WV2 + lane] : 0.f;
  #pragma unroll
  for (int m = 32; m >= 1; m >>= 1) zpart += __shfl_xor(zpart, m);
  float sc = 2.f / (1.f + __expf(-zpart));
  {
    float u = 0.f;
    const float* q = &s_u1[wv_][kh*16];
    const float* w = Wf + OFF_WP2 + (kh*16)*32 + o;
    #pragma unroll
    for (int kk = 0; kk < 16; ++kk) u += q[kk] * w[kk*32];
    u += __shfl_xor(u, 32);
    if (lane < 32) s_in[wv_][256 + o] = siluf(u + Wf[OFF_BP2 + o]);
  }
  __syncthreads();
  {
    float u = 0.f;
    const float* q = &s_in[wv_][kh*144];
    const float* w = Wf + OFF_WN1 + (kh*144)*32 + o;
    #pragma unroll 4
    for (int kk = 0; kk < 144; ++kk) u += q[kk] * w[kk*32];
    u += __shfl_xor(u, 32);
    if (lane < 32) s_un[wv_][o] = siluf(u + Wf[OFF_BN1 + o]);
  }
  __syncthreads();
  if (lane < 32){
    float u = Wf[OFF_BN2 + lane];
    #pragma unroll
    for (int k = 0; k < 32; ++k) u += s_un[wv_][k] * Wf[OFF_WN2 + k*32 + lane];
    out[a*32 + lane] = s_in[wv_][lane] + siluf(u);
  }
  if (lane < 3){
    float pv = pvh[(size_t)a*3 + lane] + pvh[30000 + (size_t)a*3 + lane];
    float vup = sc * v[a*3+lane] + pv;
    float xup = x[a*3+lane] + vup;
    out[N_ATOMS*32 + a*3 + lane] = xup;
    out[N_ATOMS*32 + N_ATOMS*3 + a*3 + lane] = vup;
  }
}

// ---------------- workspace layout ----------------
static constexpr size_t al256(size_t x){ return (x + 255) & ~(size_t)255; }
static constexpr size_t WS_FLAGS   = 0;
static constexpr size_t WS_COUNTS  = al256(WS_FLAGS + 8);
static constexpr size_t WS_OFFSETS = al256(WS_COUNTS + (size_t)N_ATOMS * 4);
static constexpr size_t WS_CURSOR  = al256(WS_OFFSETS + (size_t)(N_ATOMS + 1) * 4);
static constexpr size_t WS_PERM    = al256(WS_CURSOR + (size_t)N_ATOMS * 4);   // isrt
static constexpr size_t WS_PLI     = al256(WS_PERM + (size_t)P_PAIRS * 4);
static constexpr size_t WS_HF      = al256(WS_PLI + (size_t)2 * P_PAIRS * 4);
static constexpr size_t WS_XF      = al256(WS_HF + (size_t)N_ATOMS * 32 * 4);
static constexpr size_t WS_VF      = al256(WS_XF + (size_t)N_ATOMS * 3 * 4);
static constexpr size_t WS_WF      = al256(WS_VF + (size_t)N_ATOMS * 3 * 4);
static constexpr size_t WS_WT      = al256(WS_WF + (size_t)WF_TOTAL * 4);
static constexpr size_t WS_EDGE    = al256(WS_WT + (size_t)224 * 224 * 2);
static constexpr size_t WS_ATTS    = al256(WS_EDGE + (size_t)P_PAIRS * 32 * 2);
static constexpr size_t WS_DIRS    = al256(WS_ATTS + (size_t)P_PAIRS * 7 * 4);
static constexpr size_t WS_LOGITS  = al256(WS_DIRS + (size_t)P_PAIRS * 3 * 4);
static constexpr size_t WS_PREI    = al256(WS_LOGITS + (size_t)P_PAIRS * 7 * 4);
static constexpr size_t WS_PREJ    = al256(WS_PREI + (size_t)N_ATOMS * 88 * 2);
static constexpr size_t WS_HSEM    = WS_LOGITS + 4480000;
static constexpr size_t WS_XH      = WS_HSEM + (size_t)N_ATOMS * 224 * 4;
static constexpr size_t WS_NSQ     = WS_XH + (size_t)P_PAIRS * 112 * 2;
static constexpr size_t WS_PVH     = WS_NSQ + (size_t)N_ATOMS * 224 * 4;
static constexpr size_t WS_JSRT    = al256(WS_PVH + (size_t)2 * 30000 * 4);
static constexpr size_t WS_BPK     = al256(WS_JSRT + (size_t)P_PAIRS * 4);
static constexpr size_t WS_END     = WS_BPK + 3584 * 2;
static_assert(WS_PREJ + (size_t)N_ATOMS * 88 * 2 <= WS_XH, "pre tables before xhalf");
static_assert(WS_END <= WS_LOGITS + (size_t)P_PAIRS * 224 * 2, "within round-1-proven footprint");
static_assert(WS_HSEM % 256 == 0 && WS_XH % 256 == 0 && WS_NSQ % 256 == 0 && WS_PVH % 256 == 0, "alignment");

extern "C" void kernel_launch(void* const* d_in, const int* in_sizes, int n_in,
                              void* d_out, int out_size, void* d_ws, size_t ws_size,
                              hipStream_t stream){
  (void)in_sizes; (void)n_in;
  if (out_size != 380000 || ws_size < WS_END){
    k_code<<<1, 64, 0, stream>>>((float*)d_out, 14000.f);
    return;
  }
  char* ws = (char*)d_ws;
  int*   counts = (int*)(ws + WS_COUNTS);
  int*   offs   = (int*)(ws + WS_OFFSETS);
  int*   cursor = (int*)(ws + WS_CURSOR);
  int*   isrt   = (int*)(ws + WS_PERM);
  int*   pli    = (int*)(ws + WS_PLI);
  float* hf     = (float*)(ws + WS_HF);
  float* xf     = (float*)(ws + WS_XF);
  float* vf     = (float*)(ws + WS_VF);
  float* Wf     = (float*)(ws + WS_WF);
  u16*   wT     = (u16*)(ws + WS_WT);
  u16*   edge   = (u16*)(ws + WS_EDGE);
  float* atts   = (float*)(ws + WS_ATTS);
  float* dirs   = (float*)(ws + WS_DIRS);
  float* logits = (float*)(ws + WS_LOGITS);
  u16*   prei   = (u16*)(ws + WS_PREI);
  u16*   prej   = (u16*)(ws + WS_PREJ);
  float* hsem   = (float*)(ws + WS_HSEM);
  u16*   xhalf  = (u16*)(ws + WS_XH);
  float* nsq    = (float*)(ws + WS_NSQ);
  float* pvh    = (float*)(ws + WS_PVH);
  int*   jsrt   = (int*)(ws + WS_JSRT);
  u16*   bpk    = (u16*)(ws + WS_BPK);

  hipMemsetAsync(counts, 0, (size_t)N_ATOMS * 4, stream);
  k_prep<<<NBP_HIST, 256, 0, stream>>>(d_in[0], d_in[1], d_in[2], d_in[3],
      d_in[4],  d_in[5],  d_in[6],  d_in[7],  d_in[8],  d_in[9],  d_in[10], d_in[11],
      d_in[12], d_in[13], d_in[14], d_in[15], d_in[16], d_in[17], d_in[18], d_in[19],
      d_in[20], d_in[21], d_in[22], d_in[24], d_in[23],
      hf, xf, vf, pli, Wf, wT, bpk, counts);
  k_atomscan<<<N_ATOMS + 1, 256, 0, stream>>>(hf, Wf, prei, prej, counts, offs, cursor);
  k_scatter<<<P_PAIRS / 256, 256, 0, stream>>>(pli, cursor, isrt, jsrt);
  k_pairm<<<P_PAIRS / 128, 256, 0, stream>>>(xf, Wf, prei, prej, isrt, jsrt, bpk, edge, logits, dirs);
  k_att<<<N_ATOMS / 16, 256, 0, stream>>>(offs, logits, edge, atts, hsem);
  k_gemm3<<<P_PAIRS / 128, 256, 0, stream>>>(edge, atts, wT, xhalf, 0);
  k_comb<<<N_ATOMS / 16, 256, 0, stream>>>(offs, xhalf, dirs, Wf, 0, nsq, pvh);
  k_gemm3<<<P_PAIRS / 128, 256, 0, stream>>>(edge, atts, wT, xhalf, 1);
  k_comb<<<N_ATOMS / 16, 256, 0, stream>>>(offs, xhalf, dirs, Wf, 1, nsq, pvh);
  k_final4<<<N_ATOMS / 4, 256, 0, stream>>>(hf, xf, vf, Wf, hsem, nsq, pvh, (float*)d_out);
}

// Round 8
// 378.045 us; speedup vs baseline: 1.1532x; 1.0290x over previous
//
#include <hip/hip_runtime.h>

typedef unsigned short u16;
typedef unsigned int u32;
typedef __attribute__((ext_vector_type(8))) short short8;
typedef __attribute__((ext_vector_type(4))) float floatx4;

#define P_PAIRS 160000
#define N_ATOMS 10000

#define OFF_WMLP  0      // stored TRANSPOSED: [50][64], (o,k) at o*64+k
#define OFF_BMLP  3200
#define OFF_WE1   3250
#define OFF_BE1   6930
#define OFF_WE2   6962
#define OFF_BE2   7986
#define OFF_WATT  8018
#define OFF_BATT  8242
#define OFF_WN1   8249
#define OFF_BN1   17465
#define OFF_WN2   17497
#define OFF_BN2   18521
#define OFF_WP1   18553
#define OFF_BP1   25721
#define OFF_WP2   25753
#define OFF_BP2   26777
#define OFF_WV1   26809
#define OFF_BV1   27833
#define OFF_WV2   27865
#define OFF_WVMIX 27897
#define WF_TOTAL  28121

__device__ __forceinline__ float b2f(u16 u){ return __uint_as_float(((u32)u) << 16); }
__device__ __forceinline__ u16 f2b(float f){
  u32 u = __float_as_uint(f);
  u32 r = (u + 0x7FFFu + ((u >> 16) & 1u)) >> 16;
  return (u16)r;
}
__device__ __forceinline__ void unpack2(u32 p, float& lo, float& hi){
  lo = __uint_as_float(p << 16);
  hi = __uint_as_float(p & 0xFFFF0000u);
}
__device__ __forceinline__ float siluf(float v){ return v / (1.f + __expf(-v)); }
__device__ __forceinline__ float ldw(const void* p, int o, int bf){
  return bf ? b2f(((const u16*)p)[o]) : ((const float*)p)[o];
}

__global__ void k_code(float* out, float code){
  if (threadIdx.x == 0 && blockIdx.x == 0) out[0] = code;
}

// per-block dtype detection (wave 0 ballot), replaces k_detect dispatch
__device__ __forceinline__ void detect_flags(const u32* hw, const u32* plw, int* s_fl){
  int tid = threadIdx.x;
  if (tid < 64){
    u32 e = (hw[tid] >> 7) & 0xFFu;
    unsigned long long m1 = __ballot(e >= 100u && e <= 140u);
    unsigned long long m2 = __ballot(plw[2*tid+1] == 0u);
    if (tid == 0){
      s_fl[0] = (__popcll(m1) >= 48) ? 1 : 0;
      s_fl[1] = (__popcll(m2) >= 60) ? 1 : 0;
    }
  }
  __syncthreads();
}

// ------------- fused preprocessing: norm + convert + transpose + bpk + hist -
#define NBP_NORM 2735
#define NBP_CONV (NBP_NORM + 110)
#define NBP_TRAN (NBP_CONV + 196)
#define NBP_PB   (NBP_TRAN + 14)
#define NBP_HIST (NBP_PB + 625)

__global__ void k_prep(const void* __restrict__ h_raw, const void* __restrict__ x_raw,
    const void* __restrict__ v_raw, const void* __restrict__ pl_raw,
    const void* w_mlp, const void* b_mlp, const void* w_e1, const void* b_e1,
    const void* w_e2, const void* b_e2, const void* w_att, const void* b_att,
    const void* w_n1, const void* b_n1, const void* w_n2, const void* b_n2,
    const void* w_p1, const void* b_p1, const void* w_p2, const void* b_p2,
    const void* w_v1, const void* b_v1, const void* w_v2, const void* w_vmix,
    const void* wx,
    float* __restrict__ hf, float* __restrict__ xf, float* __restrict__ vf,
    int* __restrict__ pli, float* __restrict__ Wf, u16* __restrict__ wT,
    u16* __restrict__ bpk, int* __restrict__ counts){
  __shared__ int s_fl[2];
  detect_flags((const u32*)h_raw, (const u32*)pl_raw, s_fl);
  int bf = s_fl[0], i64 = s_fl[1];
  int bid = blockIdx.x, tid = threadIdx.x;
  if (bid < NBP_NORM){
    int t = bid * 256 + tid;
    if (t < 320000){
      hf[t] = ldw(h_raw, t, bf);
    } else if (t < 350000){
      int i = t - 320000; xf[i] = ldw(x_raw, i, bf);
    } else if (t < 380000){
      int i = t - 350000; vf[i] = ldw(v_raw, i, bf);
    } else if (t < 700000){
      int k = t - 380000;
      const int* p32 = (const int*)pl_raw;
      pli[k] = i64 ? p32[2*(size_t)k] : p32[k];
    }
  } else if (bid < NBP_CONV){
    int t = (bid - NBP_NORM) * 256 + tid;
    if (t >= WF_TOTAL) return;
    if (t < 3200){
      int k = t / 50, o = t - k * 50;
      Wf[OFF_WMLP + o * 64 + k] = ldw(w_mlp, t, bf);
      return;
    }
    const void* src; int o;
    if      (t < 3250)  { src = b_mlp;  o = t - 3200; }
    else if (t < 6930)  { src = w_e1;   o = t - 3250; }
    else if (t < 6962)  { src = b_e1;   o = t - 6930; }
    else if (t < 7986)  { src = w_e2;   o = t - 6962; }
    else if (t < 8018)  { src = b_e2;   o = t - 7986; }
    else if (t < 8242)  { src = w_att;  o = t - 8018; }
    else if (t < 8249)  { src = b_att;  o = t - 8242; }
    else if (t < 17465) { src = w_n1;   o = t - 8249; }
    else if (t < 17497) { src = b_n1;   o = t - 17465; }
    else if (t < 18521) { src = w_n2;   o = t - 17497; }
    else if (t < 18553) { src = b_n2;   o = t - 18521; }
    else if (t < 25721) { src = w_p1;   o = t - 18553; }
    else if (t < 25753) { src = b_p1;   o = t - 25721; }
    else if (t < 26777) { src = w_p2;   o = t - 25753; }
    else if (t < 26809) { src = b_p2;   o = t - 26777; }
    else if (t < 27833) { src = w_v1;   o = t - 26809; }
    else if (t < 27865) { src = b_v1;   o = t - 27833; }
    else if (t < 27897) { src = w_v2;   o = t - 27865; }
    else                { src = w_vmix; o = t - 27897; }
    Wf[t] = ldw(src, o, bf);
  } else if (bid < NBP_TRAN){
    int t = (bid - NBP_CONV) * 256 + tid;
    if (t >= 224 * 224) return;
    int n = t / 224, k = t - n * 224;
    wT[t] = f2b(ldw(wx, k * 224 + n, bf));
  } else if (bid < NBP_PB){
    // bpk: B1T [32][64] | B2T [32][32] | B3T [16][32]  (bf16, from RAW weights)
    int t = (bid - NBP_TRAN) * 256 + tid;
    if (t >= 3584) return;
    float v = 0.f;
    if (t < 2048){
      int n = t >> 6, k = t & 63;
      if (k < 50)       v = ldw(w_e1, (64 + k) * 32 + n, bf);
      else if (k == 50) v = ldw(w_e1, 114 * 32 + n, bf);
    } else if (t < 3072){
      int e = t - 2048; int n = e >> 5, k = e & 31;
      v = ldw(w_e2, k * 32 + n, bf);
    } else {
      int e = t - 3072; int n = e >> 5, k = e & 31;
      if (n < 7) v = ldw(w_att, k * 7 + n, bf);
    }
    bpk[t] = f2b(v);
  } else {
    int p = (bid - NBP_PB) * 256 + tid;     // hist from raw pairlist
    const int* p32 = (const int*)pl_raw;
    int i = i64 ? p32[2*(size_t)p] : p32[p];
    atomicAdd(&counts[i], 1);
  }
}

// ---------- fused: per-atom projections (625 fat blocks) + scan (1 block) ---
// 16 atoms/block; hs padded [16][33] to avoid same-bank across atoms.
__global__ void k_atomscan(const float* __restrict__ hf, const float* __restrict__ Wf,
    u16* __restrict__ prei, u16* __restrict__ prej,
    const int* __restrict__ counts, int* __restrict__ offs, int* __restrict__ cursor){
  __shared__ float hs[16][33];
  __shared__ int part[256];
  int tid = threadIdx.x;
  if (blockIdx.x < 625){
    int a0 = blockIdx.x * 16;
    for (int e = tid; e < 512; e += 256){
      int a = e >> 5, k = e & 31;
      hs[a][k] = hf[(size_t)(a0 + a) * 32 + k];
    }
    __syncthreads();
    // prei tb (50/atom): b_mlp + h @ Wmlp_top
    for (int e = tid; e < 800; e += 256){
      int a = e / 50, r = e - a * 50;
      const float* wm = Wf + OFF_WMLP + r * 64;
      float acc = Wf[OFF_BMLP + r];
      #pragma unroll
      for (int k = 0; k < 32; ++k) acc += hs[a][k] * wm[k];
      prei[(size_t)(a0 + a) * 88 + 32 + r] = f2b(acc);
    }
    // prej tb (50/atom): h @ Wmlp_bot
    for (int e = tid; e < 800; e += 256){
      int a = e / 50, r = e - a * 50;
      const float* wm = Wf + OFF_WMLP + r * 64 + 32;
      float acc = 0.f;
      #pragma unroll
      for (int k = 0; k < 32; ++k) acc += hs[a][k] * wm[k];
      prej[(size_t)(a0 + a) * 88 + 32 + r] = f2b(acc);
    }
    // prei u (32/atom): b_e1 + h @ WE1[0:32]
    for (int e = tid; e < 512; e += 256){
      int a = e >> 5, o = e & 31;
      float acc = Wf[OFF_BE1 + o];
      #pragma unroll
      for (int k = 0; k < 32; ++k) acc += hs[a][k] * Wf[OFF_WE1 + k * 32 + o];
      prei[(size_t)(a0 + a) * 88 + o] = f2b(acc);
    }
    // prej u (32/atom): h @ WE1[32:64]
    for (int e = tid; e < 512; e += 256){
      int a = e >> 5, o = e & 31;
      float acc = 0.f;
      #pragma unroll
      for (int k = 0; k < 32; ++k) acc += hs[a][k] * Wf[OFF_WE1 + (32 + k) * 32 + o];
      prej[(size_t)(a0 + a) * 88 + o] = f2b(acc);
    }
  } else {
    int sum = 0;
    for (int k = 0; k < 40; ++k){
      int idx = tid * 40 + k;
      if (idx < N_ATOMS) sum += counts[idx];
    }
    part[tid] = sum;
    __syncthreads();
    if (tid == 0){
      int run = 0;
      for (int q = 0; q < 256; ++q){ int tmp = part[q]; part[q] = run; run += tmp; }
    }
    __syncthreads();
    int run = part[tid];
    for (int k = 0; k < 40; ++k){
      int idx = tid * 40 + k;
      if (idx < N_ATOMS){ offs[idx] = run; cursor[idx] = run; run += counts[idx]; }
    }
    if (tid == 0) offs[N_ATOMS] = P_PAIRS;
  }
}

__global__ void k_scatter(const int* __restrict__ pl, int* __restrict__ cursor,
                          int* __restrict__ isrt, int* __restrict__ jsrt){
  int p = blockIdx.x * 256 + threadIdx.x;
  int i = pl[p];
  int pos = atomicAdd(&cursor[i], 1);
  isrt[pos] = i;
  jsrt[pos] = pl[P_PAIRS + p];
}

// ------- per-pair edge model via MFMA: 128 pairs/block, 4 waves -------------
// LDS: UB f32[128][32] | TB u16[128][56] | DD f32[128] | A1 u16[128][72]
//      B1 u16[32][72] | A2 u16[128][40] (silu-u, then eg) | B2 u16[32][40] | B3 u16[16][40]
#define PM_UB   0
#define PM_TB   16384
#define PM_DD   30720
#define PM_A1   31232
#define PM_B1   49664
#define PM_A2   54272
#define PM_B2   64512
#define PM_B3   67072
#define PM_TOT  68352

__global__ __launch_bounds__(256) void k_pairm(const float* __restrict__ x,
    const float* __restrict__ Wf, const u16* __restrict__ prei, const u16* __restrict__ prej,
    const int* __restrict__ isrt, const int* __restrict__ jsrt, const u16* __restrict__ bpk,
    u16* __restrict__ edge, float* __restrict__ logits, float* __restrict__ dirs){
  __shared__ __attribute__((aligned(16))) char smem[PM_TOT];
  float* UB = (float*)(smem + PM_UB);
  u16*   TB = (u16*)(smem + PM_TB);
  float* DD = (float*)(smem + PM_DD);
  u16*   A1 = (u16*)(smem + PM_A1);
  u16*   B1 = (u16*)(smem + PM_B1);
  u16*   A2 = (u16*)(smem + PM_A2);
  u16*   B2 = (u16*)(smem + PM_B2);
  u16*   B3 = (u16*)(smem + PM_B3);
  int tid = threadIdx.x;
  int wave = tid >> 6, lane = tid & 63, l15 = lane & 15, quad = lane >> 4;
  int row0 = blockIdx.x * 128;

  if (tid < 128){
    int s = row0 + tid;
    int i = isrt[s], j = jsrt[s];
    float r0 = x[j*3+0] - x[i*3+0];
    float r1 = x[j*3+1] - x[i*3+1];
    float r2 = x[j*3+2] - x[i*3+2];
    float d = sqrtf(r0*r0 + r1*r1 + r2*r2);
    float rinv = 1.f / (d + 1e-5f);
    dirs[s*3+0] = r0*rinv; dirs[s*3+1] = r1*rinv; dirs[s*3+2] = r2*rinv;
    DD[tid] = d;
    const uint4* pi4 = (const uint4*)(prei + (size_t)i * 88);
    const uint4* pj4 = (const uint4*)(prej + (size_t)j * 88);
    float* ub = UB + tid * 32;
    #pragma unroll
    for (int q = 0; q < 4; ++q){
      uint4 a4 = pi4[q], b4 = pj4[q];
      u32 pa[4] = {a4.x, a4.y, a4.z, a4.w};
      u32 pb[4] = {b4.x, b4.y, b4.z, b4.w};
      #pragma unroll
      for (int w2 = 0; w2 < 4; ++w2){
        float al, ah, bl, bh;
        unpack2(pa[w2], al, ah); unpack2(pb[w2], bl, bh);
        ub[q*8 + w2*2]     = al + bl;
        ub[q*8 + w2*2 + 1] = ah + bh;
      }
    }
    u32* tb = (u32*)TB + tid * 28;
    #pragma unroll
    for (int q = 0; q < 7; ++q){
      uint4 a4 = pi4[4+q], b4 = pj4[4+q];
      u32 pa[4] = {a4.x, a4.y, a4.z, a4.w};
      u32 pb[4] = {b4.x, b4.y, b4.z, b4.w};
      #pragma unroll
      for (int w2 = 0; w2 < 4; ++w2){
        float al, ah, bl, bh;
        unpack2(pa[w2], al, ah); unpack2(pb[w2], bl, bh);
        tb[q*4 + w2] = (u32)f2b(al + bl) | ((u32)f2b(ah + bh) << 16);
      }
    }
  } else {
    int t2 = tid - 128;
    const u32* src = (const u32*)bpk;
    for (int e = t2; e < 1024; e += 128){         // B1T [32][64] -> stride 36 u32
      int n = e >> 5, kp = e & 31;
      ((u32*)B1)[n*36 + kp] = src[e];
    }
    for (int e = t2; e < 512; e += 128){          // B2T [32][32] -> stride 20 u32
      int n = e >> 4, kp = e & 15;
      ((u32*)B2)[n*20 + kp] = src[1024 + e];
    }
    for (int e = t2; e < 256; e += 128){          // B3T [16][32] -> stride 20 u32
      int n = e >> 4, kp = e & 15;
      ((u32*)B3)[n*20 + kp] = src[1536 + e];
    }
  }
  __syncthreads();
  // A1 [128][72-stride]: cols 0..49 filt, col 50 = d, 51..63 = 0
  for (int e = tid; e < 4096; e += 256){
    int r = e >> 5, kp = e & 31;
    int k0 = kp * 2, k1 = k0 + 1;
    float d = DD[r];
    float v0 = 0.f, v1 = 0.f;
    if (k0 < 50){
      float t0 = b2f(TB[r*56 + k0]);
      float c0 = (float)k0 * (5.f/49.f), dd0 = d - c0;
      v0 = t0 * __expf(-10.f * dd0 * dd0);
    } else if (k0 == 50) v0 = d;
    if (k1 < 50){
      float t1 = b2f(TB[r*56 + k1]);
      float c1 = (float)k1 * (5.f/49.f), dd1 = d - c1;
      v1 = t1 * __expf(-10.f * dd1 * dd1);
    }
    ((u32*)A1)[r*36 + kp] = (u32)f2b(v0) | ((u32)f2b(v1) << 16);
  }
  __syncthreads();
  // u = A1 @ B1 + UB  (M=128 N=32 K=64)
  floatx4 au[2][2];
  #pragma unroll
  for (int mt = 0; mt < 2; ++mt)
    #pragma unroll
    for (int nt = 0; nt < 2; ++nt) au[mt][nt] = (floatx4){0.f,0.f,0.f,0.f};
  #pragma unroll
  for (int ks = 0; ks < 2; ++ks){
    int kk = ks * 32;
    short8 a0 = *(const short8*)(A1 + (wave*32 + l15)*72 + kk + quad*8);
    short8 a1 = *(const short8*)(A1 + (wave*32 + 16 + l15)*72 + kk + quad*8);
    #pragma unroll
    for (int nt = 0; nt < 2; ++nt){
      short8 b = *(const short8*)(B1 + (nt*16 + l15)*72 + kk + quad*8);
      au[0][nt] = __builtin_amdgcn_mfma_f32_16x16x32_bf16(a0, b, au[0][nt], 0, 0, 0);
      au[1][nt] = __builtin_amdgcn_mfma_f32_16x16x32_bf16(a1, b, au[1][nt], 0, 0, 0);
    }
  }
  #pragma unroll
  for (int mt = 0; mt < 2; ++mt)
    #pragma unroll
    for (int nt = 0; nt < 2; ++nt)
      #pragma unroll
      for (int reg = 0; reg < 4; ++reg){
        int r = wave*32 + mt*16 + quad*4 + reg;
        int c = nt*16 + l15;
        float uval = au[mt][nt][reg] + UB[r*32 + c];
        A2[r*40 + c] = f2b(siluf(uval));
      }
  __syncthreads();
  // eg = A2 @ B2 (M=128 N=32 K=32)
  floatx4 ae[2][2];
  #pragma unroll
  for (int mt = 0; mt < 2; ++mt)
    #pragma unroll
    for (int nt = 0; nt < 2; ++nt) ae[mt][nt] = (floatx4){0.f,0.f,0.f,0.f};
  {
    short8 a0 = *(const short8*)(A2 + (wave*32 + l15)*40 + quad*8);
    short8 a1 = *(const short8*)(A2 + (wave*32 + 16 + l15)*40 + quad*8);
    #pragma unroll
    for (int nt = 0; nt < 2; ++nt){
      short8 b = *(const short8*)(B2 + (nt*16 + l15)*40 + quad*8);
      ae[0][nt] = __builtin_amdgcn_mfma_f32_16x16x32_bf16(a0, b, ae[0][nt], 0, 0, 0);
      ae[1][nt] = __builtin_amdgcn_mfma_f32_16x16x32_bf16(a1, b, ae[1][nt], 0, 0, 0);
    }
  }
  __syncthreads();    // all A2 (silu-u) reads done before overwrite with eg
  #pragma unroll
  for (int mt = 0; mt < 2; ++mt)
    #pragma unroll
    for (int nt = 0; nt < 2; ++nt)
      #pragma unroll
      for (int reg = 0; reg < 4; ++reg){
        int r = wave*32 + mt*16 + quad*4 + reg;
        int c = nt*16 + l15;
        float ev = ae[mt][nt][reg] + Wf[OFF_BE2 + c];
        A2[r*40 + c] = f2b(ev);
      }
  __syncthreads();
  // edge copy-out (coalesced)
  {
    int r = tid >> 1, p = tid & 1;
    const uint4* srcp = (const uint4*)(A2 + r*40 + p*16);
    uint4* dstp = (uint4*)(edge + (size_t)(row0 + r)*32 + p*16);
    dstp[0] = srcp[0]; dstp[1] = srcp[1];
  }
  // logits = celu(A2 @ B3 + batt)  (N=16, 7 used)
  floatx4 al_[2];
  al_[0] = (floatx4){0.f,0.f,0.f,0.f};
  al_[1] = (floatx4){0.f,0.f,0.f,0.f};
  {
    short8 a0 = *(const short8*)(A2 + (wave*32 + l15)*40 + quad*8);
    short8 a1 = *(const short8*)(A2 + (wave*32 + 16 + l15)*40 + quad*8);
    short8 b = *(const short8*)(B3 + l15*40 + quad*8);
    al_[0] = __builtin_amdgcn_mfma_f32_16x16x32_bf16(a0, b, al_[0], 0, 0, 0);
    al_[1] = __builtin_amdgcn_mfma_f32_16x16x32_bf16(a1, b, al_[1], 0, 0, 0);
  }
  if (l15 < 7){
    float ba = Wf[OFF_BATT + l15];
    #pragma unroll
    for (int mt = 0; mt < 2; ++mt)
      #pragma unroll
      for (int reg = 0; reg < 4; ++reg){
        int r = wave*32 + mt*16 + quad*4 + reg;
        float vv = al_[mt][reg] + ba;
        float cl = vv > 0.f ? vv : 2.f * expm1f(0.5f * vv);
        logits[(size_t)(row0 + r)*7 + l15] = cl;
      }
  }
}

// -------- segment softmax + hsem accumulation (16-lane group per atom) ------
__global__ __launch_bounds__(256) void k_att(const int* __restrict__ offs,
    const float* __restrict__ logits, const u16* __restrict__ edge,
    float* __restrict__ atts, float* __restrict__ hsem){
  int a = blockIdx.x * 16 + (threadIdx.x >> 4);   // N = 625*16
  int lane = threadIdx.x & 15;
  int off = offs[a], end = offs[a+1];
  float m[7];
  #pragma unroll
  for (int hh = 0; hh < 7; ++hh) m[hh] = -1e30f;
  for (int s = off + lane; s < end; s += 16){
    #pragma unroll
    for (int hh = 0; hh < 7; ++hh) m[hh] = fmaxf(m[hh], logits[s*7+hh]);
  }
  #pragma unroll
  for (int hh = 0; hh < 7; ++hh){
    float v = m[hh];
    #pragma unroll
    for (int msk = 8; msk >= 1; msk >>= 1) v = fmaxf(v, __shfl_xor(v, msk));
    m[hh] = v;
  }
  float sm[7] = {0,0,0,0,0,0,0};
  for (int s = off + lane; s < end; s += 16){
    #pragma unroll
    for (int hh = 0; hh < 7; ++hh){
      float e = __expf(logits[s*7+hh] - m[hh]);
      sm[hh] += e;
      atts[s*7+hh] = e;
    }
  }
  #pragma unroll
  for (int hh = 0; hh < 7; ++hh){
    float v = sm[hh];
    #pragma unroll
    for (int msk = 8; msk >= 1; msk >>= 1) v += __shfl_xor(v, msk);
    sm[hh] = 1.f / v;
  }
  for (int s = off + lane; s < end; s += 16){
    #pragma unroll
    for (int hh = 0; hh < 7; ++hh) atts[s*7+hh] *= sm[hh];
  }
  __syncthreads();
  float acc[14] = {0,0,0,0,0,0,0,0,0,0,0,0,0,0};
  for (int s = off; s < end; ++s){
    u32 ev = *(const u32*)(edge + (size_t)s * 32 + lane * 2);
    float e0 = b2f((u16)(ev & 0xFFFFu));
    float e1 = b2f((u16)(ev >> 16));
    const float* ap = atts + (size_t)s * 7;
    #pragma unroll
    for (int hh = 0; hh < 7; ++hh){
      float at = ap[hh];
      acc[hh]     += e0 * at;
      acc[7 + hh] += e1 * at;
    }
  }
  float* hp = hsem + (size_t)a * 224 + lane * 14;
  #pragma unroll
  for (int jj = 0; jj < 14; ++jj) hp[jj] = acc[jj];
}

// -------- MFMA GEMM, half-width (112 cols), NO atomics: writes xhalf bf16 ---
#define G_BS0  59392
#define G_BS1  68352
#define G_EL   59392
#define G_AL   (59392 + 9216)
#define G_TOT  77312

__global__ __launch_bounds__(256) void k_gemm3(const u16* __restrict__ edge,
    const float* __restrict__ atts, const u16* __restrict__ BT,
    u16* __restrict__ xhalf, int half){
  __shared__ __attribute__((aligned(16))) char smem[G_TOT];
  u16*   As  = (u16*)smem;
  u16*   xth = (u16*)smem;
  u16*   eL  = (u16*)(smem + G_EL);
  float* aL  = (float*)(smem + G_AL);
  u16*   BsA[2] = {(u16*)(smem + G_BS0), (u16*)(smem + G_BS1)};
  int tid = threadIdx.x;
  int wave = tid >> 6, lane = tid & 63, l15 = lane & 15, quad = lane >> 4;
  int row0 = blockIdx.x * 128;
  int nbase = half * 112;

  for (int e = tid; e < 1024; e += 256){
    int r = e >> 3, q = e & 7;
    *(uint2*)(eL + r*36 + q*4) = *(const uint2*)(edge + (size_t)(row0 + r)*32 + q*4);
  }
  for (int e = tid; e < 896; e += 256) aL[e] = atts[(size_t)row0*7 + e];
  floatx4 acc[2][7];
  #pragma unroll
  for (int mt = 0; mt < 2; ++mt)
    #pragma unroll
    for (int nt = 0; nt < 7; ++nt)
      acc[mt][nt] = (floatx4){0.f, 0.f, 0.f, 0.f};
  __syncthreads();

  {
    int pr = tid >> 1, pp = tid & 1;
    u32* asw = (u32*)As + pr*116 + pp*56;
    const u16* er = eL + pr*36 + pp*16;
    const float* ar = aL + pr*7;
    float av[7];
    #pragma unroll
    for (int hh = 0; hh < 7; ++hh) av[hh] = ar[hh];
    #pragma unroll
    for (int fo = 0; fo < 8; ++fo){
      float e0 = b2f(er[2*fo]);
      float e1 = b2f(er[2*fo+1]);
      u16 w[14];
      #pragma unroll
      for (int hh = 0; hh < 7; ++hh){
        w[hh]   = f2b(e0 * av[hh]);
        w[7+hh] = f2b(e1 * av[hh]);
      }
      #pragma unroll
      for (int k = 0; k < 7; ++k)
        asw[fo*7 + k] = (u32)w[2*k] | ((u32)w[2*k+1] << 16);
    }
  }
  __syncthreads();

  for (int e = tid; e < 448; e += 256){
    int r = e >> 2, q = e & 3;
    *(uint4*)(BsA[0] + r*40 + q*8) = *(const uint4*)(BT + (size_t)(nbase + r)*224 + q*8);
  }
  int cur = 0;
  for (int kt = 0; kt < 7; ++kt){
    __syncthreads();
    if (kt < 6){
      int kk = (kt + 1) * 32;
      u16* bn = BsA[cur ^ 1];
      for (int e = tid; e < 448; e += 256){
        int r = e >> 2, q = e & 3;
        *(uint4*)(bn + r*40 + q*8) = *(const uint4*)(BT + (size_t)(nbase + r)*224 + kk + q*8);
      }
    }
    int kk = kt * 32;
    short8 a0 = *(const short8*)(As + (wave*32 + l15)*232 + kk + quad*8);
    short8 a1 = *(const short8*)(As + (wave*32 + 16 + l15)*232 + kk + quad*8);
    const u16* bs = BsA[cur];
    #pragma unroll
    for (int nt = 0; nt < 7; ++nt){
      short8 b = *(const short8*)(bs + (nt*16 + l15)*40 + quad*8);
      acc[0][nt] = __builtin_amdgcn_mfma_f32_16x16x32_bf16(a0, b, acc[0][nt], 0, 0, 0);
      acc[1][nt] = __builtin_amdgcn_mfma_f32_16x16x32_bf16(a1, b, acc[1][nt], 0, 0, 0);
    }
    cur ^= 1;
  }
  __syncthreads();

  #pragma unroll
  for (int mt = 0; mt < 2; ++mt)
    #pragma unroll
    for (int nt = 0; nt < 7; ++nt)
      #pragma unroll
      for (int reg = 0; reg < 4; ++reg){
        int r = wave*32 + mt*16 + quad*4 + reg;
        int c = nt*16 + l15;
        float vv = acc[mt][nt][reg];
        vv = fminf(fmaxf(vv, -15.f), 15.f);
        float e2 = __expf(2.f * vv);
        xth[r*120 + c] = f2b((e2 - 1.f) / (e2 + 1.f));
      }
  __syncthreads();
  {
    int r = tid >> 1, part = tid & 1;
    const uint4* src = (const uint4*)(xth + r*120 + part*56);
    uint4* dst = (uint4*)(xhalf + (size_t)(row0 + r)*112 + part*56);
    #pragma unroll
    for (int q = 0; q < 7; ++q) dst[q] = src[q];
  }
}

// -------- atom-centric comb reduction: xhalf -> nsq half + pv partial -------
__global__ __launch_bounds__(256) void k_comb(const int* __restrict__ offs,
    const u16* __restrict__ xhalf, const float* __restrict__ dirs,
    const float* __restrict__ Wf, int half,
    float* __restrict__ nsq, float* __restrict__ pvh){
  int a = blockIdx.x * 16 + (threadIdx.x >> 4);
  int lane = threadIdx.x & 15;
  int off = offs[a], end = offs[a+1];
  float c0[7] = {0,0,0,0,0,0,0}, c1[7] = {0,0,0,0,0,0,0}, c2[7] = {0,0,0,0,0,0,0};
  for (int s = off; s < end; ++s){
    float d0 = dirs[s*3+0], d1 = dirs[s*3+1], d2 = dirs[s*3+2];
    const u16* xr = xhalf + (size_t)s * 112 + lane;
    #pragma unroll
    for (int k = 0; k < 7; ++k){
      float xm = b2f(xr[k*16]);
      c0[k] += d0 * xm; c1[k] += d1 * xm; c2[k] += d2 * xm;
    }
  }
  float inv = 1.f / fmaxf((float)(end - off), 1.f);
  float pv0 = 0.f, pv1 = 0.f, pv2 = 0.f;
  #pragma unroll
  for (int k = 0; k < 7; ++k){
    float m0 = c0[k]*inv, m1 = c1[k]*inv, m2 = c2[k]*inv;
    int c = half*112 + k*16 + lane;
    nsq[(size_t)a*224 + c] = m0*m0 + m1*m1 + m2*m2;
    float wv = Wf[OFF_WVMIX + c];
    pv0 += wv*m0; pv1 += wv*m1; pv2 += wv*m2;
  }
  #pragma unroll
  for (int m = 8; m >= 1; m >>= 1){
    pv0 += __shfl_xor(pv0, m); pv1 += __shfl_xor(pv1, m); pv2 += __shfl_xor(pv2, m);
  }
  if (lane == 0){
    float* pp = pvh + (size_t)half*30000 + (size_t)a*3;
    pp[0] = pv0; pp[1] = pv1; pp[2] = pv2;
  }
}

// ---------------- final: wave per atom, precomputed hsem/nsq/pv -------------
__global__ __launch_bounds__(256) void k_final4(const float* __restrict__ h,
    const float* __restrict__ x, const float* __restrict__ v,
    const float* __restrict__ Wf, const float* __restrict__ hsem,
    const float* __restrict__ nsq, const float* __restrict__ pvh,
    float* __restrict__ out){
  __shared__ float s_in[4][288];
  __shared__ float s_nsq[4][224];
  __shared__ float s_u1[4][32], s_g[4][32], s_un[4][32];
  int wv_ = threadIdx.x >> 6, lane = threadIdx.x & 63;
  int a = blockIdx.x * 4 + wv_;
  if (lane < 56){
    int c4 = lane * 4;
    float4 hs = *(const float4*)(hsem + (size_t)a*224 + c4);
    float4 nq = *(const float4*)(nsq + (size_t)a*224 + c4);
    s_in[wv_][32 + c4+0] = hs.x; s_in[wv_][32 + c4+1] = hs.y;
    s_in[wv_][32 + c4+2] = hs.z; s_in[wv_][32 + c4+3] = hs.w;
    s_nsq[wv_][c4+0] = nq.x; s_nsq[wv_][c4+1] = nq.y;
    s_nsq[wv_][c4+2] = nq.z; s_nsq[wv_][c4+3] = nq.w;
  } else {
    int k4 = (lane - 56) * 4;
    float4 hv = *(const float4*)(h + (size_t)a*32 + k4);
    s_in[wv_][k4+0] = hv.x; s_in[wv_][k4+1] = hv.y;
    s_in[wv_][k4+2] = hv.z; s_in[wv_][k4+3] = hv.w;
  }
  __syncthreads();
  int o = lane & 31, kh = lane >> 5;
  {
    float u = 0.f;
    const float* q = &s_nsq[wv_][kh*112];
    const float* w = Wf + OFF_WP1 + (kh*112)*32 + o;
    #pragma unroll 4
    for (int kk = 0; kk < 112; ++kk) u += q[kk] * w[kk*32];
    u += __shfl_xor(u, 32);
    if (lane < 32) s_u1[wv_][o] = siluf(u + Wf[OFF_BP1 + o]);
  }
  {
    float g = 0.f;
    const float* q = &s_in[wv_][kh*16];
    const float* w = Wf + OFF_WV1 + (kh*16)*32 + o;
    #pragma unroll
    for (int kk = 0; kk < 16; ++kk) g += q[kk] * w[kk*32];
    g += __shfl_xor(g, 32);
    if (lane < 32) s_g[wv_][o] = siluf(g + Wf[OFF_BV1 + o]);
  }
  __syncthreads();
  float zpart = (lane < 32) ? s_g[wv_][lane] * Wf[OFF_WV2 + lane] : 0.f;
  #pragma unroll
  for (int m = 32; m >= 1; m >>= 1) zpart += __shfl_xor(zpart, m);
  float sc = 2.f / (1.f + __expf(-zpart));
  {
    float u = 0.f;
    const float* q = &s_u1[wv_][kh*16];
    const float* w = Wf + OFF_WP2 + (kh*16)*32 + o;
    #pragma unroll
    for (int kk = 0; kk < 16; ++kk) u += q[kk] * w[kk*32];
    u += __shfl_xor(u, 32);
    if (lane < 32) s_in[wv_][256 + o] = siluf(u + Wf[OFF_BP2 + o]);
  }
  __syncthreads();
  {
    float u = 0.f;
    const float* q = &s_in[wv_][kh*144];
    const float* w = Wf + OFF_WN1 + (kh*144)*32 + o;
    #pragma unroll 4
    for (int kk = 0; kk < 144; ++kk) u += q[kk] * w[kk*32];
    u += __shfl_xor(u, 32);
    if (lane < 32) s_un[wv_][o] = siluf(u + Wf[OFF_BN1 + o]);
  }
  __syncthreads();
  if (lane < 32){
    float u = Wf[OFF_BN2 + lane];
    #pragma unroll
    for (int k = 0; k < 32; ++k) u += s_un[wv_][k] * Wf[OFF_WN2 + k*32 + lane];
    out[a*32 + lane] = s_in[wv_][lane] + siluf(u);
  }
  if (lane < 3){
    float pv = pvh[(size_t)a*3 + lane] + pvh[30000 + (size_t)a*3 + lane];
    float vup = sc * v[a*3+lane] + pv;
    float xup = x[a*3+lane] + vup;
    out[N_ATOMS*32 + a*3 + lane] = xup;
    out[N_ATOMS*32 + N_ATOMS*3 + a*3 + lane] = vup;
  }
}

// ---------------- workspace layout ----------------
static constexpr size_t al256(size_t x){ return (x + 255) & ~(size_t)255; }
static constexpr size_t WS_FLAGS   = 0;
static constexpr size_t WS_COUNTS  = al256(WS_FLAGS + 8);
static constexpr size_t WS_OFFSETS = al256(WS_COUNTS + (size_t)N_ATOMS * 4);
static constexpr size_t WS_CURSOR  = al256(WS_OFFSETS + (size_t)(N_ATOMS + 1) * 4);
static constexpr size_t WS_PERM    = al256(WS_CURSOR + (size_t)N_ATOMS * 4);   // isrt
static constexpr size_t WS_PLI     = al256(WS_PERM + (size_t)P_PAIRS * 4);
static constexpr size_t WS_HF      = al256(WS_PLI + (size_t)2 * P_PAIRS * 4);
static constexpr size_t WS_XF      = al256(WS_HF + (size_t)N_ATOMS * 32 * 4);
static constexpr size_t WS_VF      = al256(WS_XF + (size_t)N_ATOMS * 3 * 4);
static constexpr size_t WS_WF      = al256(WS_VF + (size_t)N_ATOMS * 3 * 4);
static constexpr size_t WS_WT      = al256(WS_WF + (size_t)WF_TOTAL * 4);
static constexpr size_t WS_EDGE    = al256(WS_WT + (size_t)224 * 224 * 2);
static constexpr size_t WS_ATTS    = al256(WS_EDGE + (size_t)P_PAIRS * 32 * 2);
static constexpr size_t WS_DIRS    = al256(WS_ATTS + (size_t)P_PAIRS * 7 * 4);
static constexpr size_t WS_LOGITS  = al256(WS_DIRS + (size_t)P_PAIRS * 3 * 4);
static constexpr size_t WS_PREI    = al256(WS_LOGITS + (size_t)P_PAIRS * 7 * 4);
static constexpr size_t WS_PREJ    = al256(WS_PREI + (size_t)N_ATOMS * 88 * 2);
static constexpr size_t WS_HSEM    = WS_LOGITS + 4480000;
static constexpr size_t WS_XH      = WS_HSEM + (size_t)N_ATOMS * 224 * 4;
static constexpr size_t WS_NSQ     = WS_XH + (size_t)P_PAIRS * 112 * 2;
static constexpr size_t WS_PVH     = WS_NSQ + (size_t)N_ATOMS * 224 * 4;
static constexpr size_t WS_JSRT    = al256(WS_PVH + (size_t)2 * 30000 * 4);
static constexpr size_t WS_BPK     = al256(WS_JSRT + (size_t)P_PAIRS * 4);
static constexpr size_t WS_END     = WS_BPK + 3584 * 2;
static_assert(WS_PREJ + (size_t)N_ATOMS * 88 * 2 <= WS_XH, "pre tables before xhalf");
static_assert(WS_END <= WS_LOGITS + (size_t)P_PAIRS * 224 * 2, "within round-1-proven footprint");
static_assert(WS_HSEM % 256 == 0 && WS_XH % 256 == 0 && WS_NSQ % 256 == 0 && WS_PVH % 256 == 0, "alignment");

extern "C" void kernel_launch(void* const* d_in, const int* in_sizes, int n_in,
                              void* d_out, int out_size, void* d_ws, size_t ws_size,
                              hipStream_t stream){
  (void)in_sizes; (void)n_in;
  if (out_size != 380000 || ws_size < WS_END){
    k_code<<<1, 64, 0, stream>>>((float*)d_out, 14000.f);
    return;
  }
  char* ws = (char*)d_ws;
  int*   counts = (int*)(ws + WS_COUNTS);
  int*   offs   = (int*)(ws + WS_OFFSETS);
  int*   cursor = (int*)(ws + WS_CURSOR);
  int*   isrt   = (int*)(ws + WS_PERM);
  int*   pli    = (int*)(ws + WS_PLI);
  float* hf     = (float*)(ws + WS_HF);
  float* xf     = (float*)(ws + WS_XF);
  float* vf     = (float*)(ws + WS_VF);
  float* Wf     = (float*)(ws + WS_WF);
  u16*   wT     = (u16*)(ws + WS_WT);
  u16*   edge   = (u16*)(ws + WS_EDGE);
  float* atts   = (float*)(ws + WS_ATTS);
  float* dirs   = (float*)(ws + WS_DIRS);
  float* logits = (float*)(ws + WS_LOGITS);
  u16*   prei   = (u16*)(ws + WS_PREI);
  u16*   prej   = (u16*)(ws + WS_PREJ);
  float* hsem   = (float*)(ws + WS_HSEM);
  u16*   xhalf  = (u16*)(ws + WS_XH);
  float* nsq    = (float*)(ws + WS_NSQ);
  float* pvh    = (float*)(ws + WS_PVH);
  int*   jsrt   = (int*)(ws + WS_JSRT);
  u16*   bpk    = (u16*)(ws + WS_BPK);

  hipMemsetAsync(counts, 0, (size_t)N_ATOMS * 4, stream);
  k_prep<<<NBP_HIST, 256, 0, stream>>>(d_in[0], d_in[1], d_in[2], d_in[3],
      d_in[4],  d_in[5],  d_in[6],  d_in[7],  d_in[8],  d_in[9],  d_in[10], d_in[11],
      d_in[12], d_in[13], d_in[14], d_in[15], d_in[16], d_in[17], d_in[18], d_in[19],
      d_in[20], d_in[21], d_in[22], d_in[24], d_in[23],
      hf, xf, vf, pli, Wf, wT, bpk, counts);
  k_atomscan<<<626, 256, 0, stream>>>(hf, Wf, prei, prej, counts, offs, cursor);
  k_scatter<<<P_PAIRS / 256, 256, 0, stream>>>(pli, cursor, isrt, jsrt);
  k_pairm<<<P_PAIRS / 128, 256, 0, stream>>>(xf, Wf, prei, prej, isrt, jsrt, bpk, edge, logits, dirs);
  k_att<<<N_ATOMS / 16, 256, 0, stream>>>(offs, logits, edge, atts, hsem);
  k_gemm3<<<P_PAIRS / 128, 256, 0, stream>>>(edge, atts, wT, xhalf, 0);
  k_comb<<<N_ATOMS / 16, 256, 0, stream>>>(offs, xhalf, dirs, Wf, 0, nsq, pvh);
  k_gemm3<<<P_PAIRS / 128, 256, 0, stream>>>(edge, atts, wT, xhalf, 1);
  k_comb<<<N_ATOMS / 16, 256, 0, stream>>>(offs, xhalf, dirs, Wf, 1, nsq, pvh);
  k_final4<<<N_ATOMS / 4, 256, 0, stream>>>(hf, xf, vf, Wf, hsem, nsq, pvh, (float*)d_out);
}

// Round 9
// 353.137 us; speedup vs baseline: 1.2346x; 1.0705x over previous
//
#include <hip/hip_runtime.h>

typedef unsigned short u16;
typedef unsigned int u32;
typedef __attribute__((ext_vector_type(8))) short short8;
typedef __attribute__((ext_vector_type(4))) float floatx4;

#define P_PAIRS 160000
#define N_ATOMS 10000

#define OFF_WMLP  0      // stored TRANSPOSED: [50][64], (o,k) at o*64+k
#define OFF_BMLP  3200
#define OFF_WE1   3250
#define OFF_BE1   6930
#define OFF_WE2   6962
#define OFF_BE2   7986
#define OFF_WATT  8018
#define OFF_BATT  8242
#define OFF_WN1   8249
#define OFF_BN1   17465
#define OFF_WN2   17497
#define OFF_BN2   18521
#define OFF_WP1   18553
#define OFF_BP1   25721
#define OFF_WP2   25753
#define OFF_BP2   26777
#define OFF_WV1   26809
#define OFF_BV1   27833
#define OFF_WV2   27865
#define OFF_WVMIX 27897
#define WF_TOTAL  28121

__device__ __forceinline__ float b2f(u16 u){ return __uint_as_float(((u32)u) << 16); }
__device__ __forceinline__ u16 f2b(float f){
  u32 u = __float_as_uint(f);
  u32 r = (u + 0x7FFFu + ((u >> 16) & 1u)) >> 16;
  return (u16)r;
}
__device__ __forceinline__ void unpack2(u32 p, float& lo, float& hi){
  lo = __uint_as_float(p << 16);
  hi = __uint_as_float(p & 0xFFFF0000u);
}
__device__ __forceinline__ float siluf(float v){ return v / (1.f + __expf(-v)); }
__device__ __forceinline__ float ldw(const void* p, int o, int bf){
  return bf ? b2f(((const u16*)p)[o]) : ((const float*)p)[o];
}

__global__ void k_code(float* out, float code){
  if (threadIdx.x == 0 && blockIdx.x == 0) out[0] = code;
}

// per-block dtype detection (wave 0 ballot), replaces k_detect dispatch
__device__ __forceinline__ void detect_flags(const u32* hw, const u32* plw, int* s_fl){
  int tid = threadIdx.x;
  if (tid < 64){
    u32 e = (hw[tid] >> 7) & 0xFFu;
    unsigned long long m1 = __ballot(e >= 100u && e <= 140u);
    unsigned long long m2 = __ballot(plw[2*tid+1] == 0u);
    if (tid == 0){
      s_fl[0] = (__popcll(m1) >= 48) ? 1 : 0;
      s_fl[1] = (__popcll(m2) >= 60) ? 1 : 0;
    }
  }
  __syncthreads();
}

// ------------- fused preprocessing: norm + convert + transpose + bpk + hist -
#define NBP_NORM 2735
#define NBP_CONV (NBP_NORM + 110)
#define NBP_TRAN (NBP_CONV + 196)
#define NBP_PB   (NBP_TRAN + 14)
#define NBP_HIST (NBP_PB + 625)

__global__ void k_prep(const void* __restrict__ h_raw, const void* __restrict__ x_raw,
    const void* __restrict__ v_raw, const void* __restrict__ pl_raw,
    const void* w_mlp, const void* b_mlp, const void* w_e1, const void* b_e1,
    const void* w_e2, const void* b_e2, const void* w_att, const void* b_att,
    const void* w_n1, const void* b_n1, const void* w_n2, const void* b_n2,
    const void* w_p1, const void* b_p1, const void* w_p2, const void* b_p2,
    const void* w_v1, const void* b_v1, const void* w_v2, const void* w_vmix,
    const void* wx,
    float* __restrict__ hf, float* __restrict__ xf, float* __restrict__ vf,
    int* __restrict__ pli, float* __restrict__ Wf, u16* __restrict__ wT,
    u16* __restrict__ bpk, int* __restrict__ counts){
  __shared__ int s_fl[2];
  detect_flags((const u32*)h_raw, (const u32*)pl_raw, s_fl);
  int bf = s_fl[0], i64 = s_fl[1];
  int bid = blockIdx.x, tid = threadIdx.x;
  if (bid < NBP_NORM){
    int t = bid * 256 + tid;
    if (t < 320000){
      hf[t] = ldw(h_raw, t, bf);
    } else if (t < 350000){
      int i = t - 320000; xf[i] = ldw(x_raw, i, bf);
    } else if (t < 380000){
      int i = t - 350000; vf[i] = ldw(v_raw, i, bf);
    } else if (t < 700000){
      int k = t - 380000;
      const int* p32 = (const int*)pl_raw;
      pli[k] = i64 ? p32[2*(size_t)k] : p32[k];
    }
  } else if (bid < NBP_CONV){
    int t = (bid - NBP_NORM) * 256 + tid;
    if (t >= WF_TOTAL) return;
    if (t < 3200){
      int k = t / 50, o = t - k * 50;
      Wf[OFF_WMLP + o * 64 + k] = ldw(w_mlp, t, bf);
      return;
    }
    const void* src; int o;
    if      (t < 3250)  { src = b_mlp;  o = t - 3200; }
    else if (t < 6930)  { src = w_e1;   o = t - 3250; }
    else if (t < 6962)  { src = b_e1;   o = t - 6930; }
    else if (t < 7986)  { src = w_e2;   o = t - 6962; }
    else if (t < 8018)  { src = b_e2;   o = t - 7986; }
    else if (t < 8242)  { src = w_att;  o = t - 8018; }
    else if (t < 8249)  { src = b_att;  o = t - 8242; }
    else if (t < 17465) { src = w_n1;   o = t - 8249; }
    else if (t < 17497) { src = b_n1;   o = t - 17465; }
    else if (t < 18521) { src = w_n2;   o = t - 17497; }
    else if (t < 18553) { src = b_n2;   o = t - 18521; }
    else if (t < 25721) { src = w_p1;   o = t - 18553; }
    else if (t < 25753) { src = b_p1;   o = t - 25721; }
    else if (t < 26777) { src = w_p2;   o = t - 25753; }
    else if (t < 26809) { src = b_p2;   o = t - 26777; }
    else if (t < 27833) { src = w_v1;   o = t - 26809; }
    else if (t < 27865) { src = b_v1;   o = t - 27833; }
    else if (t < 27897) { src = w_v2;   o = t - 27865; }
    else                { src = w_vmix; o = t - 27897; }
    Wf[t] = ldw(src, o, bf);
  } else if (bid < NBP_TRAN){
    int t = (bid - NBP_CONV) * 256 + tid;
    if (t >= 224 * 224) return;
    int n = t / 224, k = t - n * 224;
    wT[t] = f2b(ldw(wx, k * 224 + n, bf));
  } else if (bid < NBP_PB){
    // bpk: B1T [32][64] | B2T [32][32] | B3T [16][32]  (bf16, from RAW weights)
    int t = (bid - NBP_TRAN) * 256 + tid;
    if (t >= 3584) return;
    float v = 0.f;
    if (t < 2048){
      int n = t >> 6, k = t & 63;
      if (k < 50)       v = ldw(w_e1, (64 + k) * 32 + n, bf);
      else if (k == 50) v = ldw(w_e1, 114 * 32 + n, bf);
    } else if (t < 3072){
      int e = t - 2048; int n = e >> 5, k = e & 31;
      v = ldw(w_e2, k * 32 + n, bf);
    } else {
      int e = t - 3072; int n = e >> 5, k = e & 31;
      if (n < 7) v = ldw(w_att, k * 7 + n, bf);
    }
    bpk[t] = f2b(v);
  } else {
    int p = (bid - NBP_PB) * 256 + tid;     // hist from raw pairlist
    const int* p32 = (const int*)pl_raw;
    int i = i64 ? p32[2*(size_t)p] : p32[p];
    atomicAdd(&counts[i], 1);
  }
}

// ---------- fused: per-atom projections (625 fat blocks) + scan (1 block) ---
// 16 atoms/block; hs padded [16][33] to avoid same-bank across atoms.
__global__ void k_atomscan(const float* __restrict__ hf, const float* __restrict__ Wf,
    u16* __restrict__ prei, u16* __restrict__ prej,
    const int* __restrict__ counts, int* __restrict__ offs, int* __restrict__ cursor){
  __shared__ float hs[16][33];
  __shared__ int part[256];
  int tid = threadIdx.x;
  if (blockIdx.x < 625){
    int a0 = blockIdx.x * 16;
    for (int e = tid; e < 512; e += 256){
      int a = e >> 5, k = e & 31;
      hs[a][k] = hf[(size_t)(a0 + a) * 32 + k];
    }
    __syncthreads();
    // prei tb (50/atom): b_mlp + h @ Wmlp_top
    for (int e = tid; e < 800; e += 256){
      int a = e / 50, r = e - a * 50;
      const float* wm = Wf + OFF_WMLP + r * 64;
      float acc = Wf[OFF_BMLP + r];
      #pragma unroll
      for (int k = 0; k < 32; ++k) acc += hs[a][k] * wm[k];
      prei[(size_t)(a0 + a) * 88 + 32 + r] = f2b(acc);
    }
    // prej tb (50/atom): h @ Wmlp_bot
    for (int e = tid; e < 800; e += 256){
      int a = e / 50, r = e - a * 50;
      const float* wm = Wf + OFF_WMLP + r * 64 + 32;
      float acc = 0.f;
      #pragma unroll
      for (int k = 0; k < 32; ++k) acc += hs[a][k] * wm[k];
      prej[(size_t)(a0 + a) * 88 + 32 + r] = f2b(acc);
    }
    // prei u (32/atom): b_e1 + h @ WE1[0:32]
    for (int e = tid; e < 512; e += 256){
      int a = e >> 5, o = e & 31;
      float acc = Wf[OFF_BE1 + o];
      #pragma unroll
      for (int k = 0; k < 32; ++k) acc += hs[a][k] * Wf[OFF_WE1 + k * 32 + o];
      prei[(size_t)(a0 + a) * 88 + o] = f2b(acc);
    }
    // prej u (32/atom): h @ WE1[32:64]
    for (int e = tid; e < 512; e += 256){
      int a = e >> 5, o = e & 31;
      float acc = 0.f;
      #pragma unroll
      for (int k = 0; k < 32; ++k) acc += hs[a][k] * Wf[OFF_WE1 + (32 + k) * 32 + o];
      prej[(size_t)(a0 + a) * 88 + o] = f2b(acc);
    }
  } else {
    int sum = 0;
    for (int k = 0; k < 40; ++k){
      int idx = tid * 40 + k;
      if (idx < N_ATOMS) sum += counts[idx];
    }
    part[tid] = sum;
    __syncthreads();
    if (tid == 0){
      int run = 0;
      for (int q = 0; q < 256; ++q){ int tmp = part[q]; part[q] = run; run += tmp; }
    }
    __syncthreads();
    int run = part[tid];
    for (int k = 0; k < 40; ++k){
      int idx = tid * 40 + k;
      if (idx < N_ATOMS){ offs[idx] = run; cursor[idx] = run; run += counts[idx]; }
    }
    if (tid == 0) offs[N_ATOMS] = P_PAIRS;
  }
}

__global__ void k_scatter(const int* __restrict__ pl, int* __restrict__ cursor,
                          int* __restrict__ isrt, int* __restrict__ jsrt){
  int p = blockIdx.x * 256 + threadIdx.x;
  int i = pl[p];
  int pos = atomicAdd(&cursor[i], 1);
  isrt[pos] = i;
  jsrt[pos] = pl[P_PAIRS + p];
}

// ------- per-pair edge model via MFMA: 128 pairs/block, 4 waves -------------
// LDS: UB f32[128][32] | TB u16[128][56] | DD f32[128] | A1 u16[128][72]
//      B1 u16[32][72] | A2 u16[128][40] (silu-u, then eg) | B2 u16[32][40] | B3 u16[16][40]
#define PM_UB   0
#define PM_TB   16384
#define PM_DD   30720
#define PM_A1   31232
#define PM_B1   49664
#define PM_A2   54272
#define PM_B2   64512
#define PM_B3   67072
#define PM_TOT  68352

__global__ __launch_bounds__(256) void k_pairm(const float* __restrict__ x,
    const float* __restrict__ Wf, const u16* __restrict__ prei, const u16* __restrict__ prej,
    const int* __restrict__ isrt, const int* __restrict__ jsrt, const u16* __restrict__ bpk,
    u16* __restrict__ edge, float* __restrict__ logits, float* __restrict__ dirs){
  __shared__ __attribute__((aligned(16))) char smem[PM_TOT];
  float* UB = (float*)(smem + PM_UB);
  u16*   TB = (u16*)(smem + PM_TB);
  float* DD = (float*)(smem + PM_DD);
  u16*   A1 = (u16*)(smem + PM_A1);
  u16*   B1 = (u16*)(smem + PM_B1);
  u16*   A2 = (u16*)(smem + PM_A2);
  u16*   B2 = (u16*)(smem + PM_B2);
  u16*   B3 = (u16*)(smem + PM_B3);
  int tid = threadIdx.x;
  int wave = tid >> 6, lane = tid & 63, l15 = lane & 15, quad = lane >> 4;
  int row0 = blockIdx.x * 128;

  if (tid < 128){
    int s = row0 + tid;
    int i = isrt[s], j = jsrt[s];
    float r0 = x[j*3+0] - x[i*3+0];
    float r1 = x[j*3+1] - x[i*3+1];
    float r2 = x[j*3+2] - x[i*3+2];
    float d = sqrtf(r0*r0 + r1*r1 + r2*r2);
    float rinv = 1.f / (d + 1e-5f);
    dirs[s*3+0] = r0*rinv; dirs[s*3+1] = r1*rinv; dirs[s*3+2] = r2*rinv;
    DD[tid] = d;
    const uint4* pi4 = (const uint4*)(prei + (size_t)i * 88);
    const uint4* pj4 = (const uint4*)(prej + (size_t)j * 88);
    float* ub = UB + tid * 32;
    #pragma unroll
    for (int q = 0; q < 4; ++q){
      uint4 a4 = pi4[q], b4 = pj4[q];
      u32 pa[4] = {a4.x, a4.y, a4.z, a4.w};
      u32 pb[4] = {b4.x, b4.y, b4.z, b4.w};
      #pragma unroll
      for (int w2 = 0; w2 < 4; ++w2){
        float al, ah, bl, bh;
        unpack2(pa[w2], al, ah); unpack2(pb[w2], bl, bh);
        ub[q*8 + w2*2]     = al + bl;
        ub[q*8 + w2*2 + 1] = ah + bh;
      }
    }
    u32* tb = (u32*)TB + tid * 28;
    #pragma unroll
    for (int q = 0; q < 7; ++q){
      uint4 a4 = pi4[4+q], b4 = pj4[4+q];
      u32 pa[4] = {a4.x, a4.y, a4.z, a4.w};
      u32 pb[4] = {b4.x, b4.y, b4.z, b4.w};
      #pragma unroll
      for (int w2 = 0; w2 < 4; ++w2){
        float al, ah, bl, bh;
        unpack2(pa[w2], al, ah); unpack2(pb[w2], bl, bh);
        tb[q*4 + w2] = (u32)f2b(al + bl) | ((u32)f2b(ah + bh) << 16);
      }
    }
  } else {
    int t2 = tid - 128;
    const u32* src = (const u32*)bpk;
    for (int e = t2; e < 1024; e += 128){         // B1T [32][64] -> stride 36 u32
      int n = e >> 5, kp = e & 31;
      ((u32*)B1)[n*36 + kp] = src[e];
    }
    for (int e = t2; e < 512; e += 128){          // B2T [32][32] -> stride 20 u32
      int n = e >> 4, kp = e & 15;
      ((u32*)B2)[n*20 + kp] = src[1024 + e];
    }
    for (int e = t2; e < 256; e += 128){          // B3T [16][32] -> stride 20 u32
      int n = e >> 4, kp = e & 15;
      ((u32*)B3)[n*20 + kp] = src[1536 + e];
    }
  }
  __syncthreads();
  // A1 [128][72-stride]: cols 0..49 filt, col 50 = d, 51..63 = 0
  for (int e = tid; e < 4096; e += 256){
    int r = e >> 5, kp = e & 31;
    int k0 = kp * 2, k1 = k0 + 1;
    float d = DD[r];
    float v0 = 0.f, v1 = 0.f;
    if (k0 < 50){
      float t0 = b2f(TB[r*56 + k0]);
      float c0 = (float)k0 * (5.f/49.f), dd0 = d - c0;
      v0 = t0 * __expf(-10.f * dd0 * dd0);
    } else if (k0 == 50) v0 = d;
    if (k1 < 50){
      float t1 = b2f(TB[r*56 + k1]);
      float c1 = (float)k1 * (5.f/49.f), dd1 = d - c1;
      v1 = t1 * __expf(-10.f * dd1 * dd1);
    }
    ((u32*)A1)[r*36 + kp] = (u32)f2b(v0) | ((u32)f2b(v1) << 16);
  }
  __syncthreads();
  // u = A1 @ B1 + UB  (M=128 N=32 K=64)
  floatx4 au[2][2];
  #pragma unroll
  for (int mt = 0; mt < 2; ++mt)
    #pragma unroll
    for (int nt = 0; nt < 2; ++nt) au[mt][nt] = (floatx4){0.f,0.f,0.f,0.f};
  #pragma unroll
  for (int ks = 0; ks < 2; ++ks){
    int kk = ks * 32;
    short8 a0 = *(const short8*)(A1 + (wave*32 + l15)*72 + kk + quad*8);
    short8 a1 = *(const short8*)(A1 + (wave*32 + 16 + l15)*72 + kk + quad*8);
    #pragma unroll
    for (int nt = 0; nt < 2; ++nt){
      short8 b = *(const short8*)(B1 + (nt*16 + l15)*72 + kk + quad*8);
      au[0][nt] = __builtin_amdgcn_mfma_f32_16x16x32_bf16(a0, b, au[0][nt], 0, 0, 0);
      au[1][nt] = __builtin_amdgcn_mfma_f32_16x16x32_bf16(a1, b, au[1][nt], 0, 0, 0);
    }
  }
  #pragma unroll
  for (int mt = 0; mt < 2; ++mt)
    #pragma unroll
    for (int nt = 0; nt < 2; ++nt)
      #pragma unroll
      for (int reg = 0; reg < 4; ++reg){
        int r = wave*32 + mt*16 + quad*4 + reg;
        int c = nt*16 + l15;
        float uval = au[mt][nt][reg] + UB[r*32 + c];
        A2[r*40 + c] = f2b(siluf(uval));
      }
  __syncthreads();
  // eg = A2 @ B2 (M=128 N=32 K=32)
  floatx4 ae[2][2];
  #pragma unroll
  for (int mt = 0; mt < 2; ++mt)
    #pragma unroll
    for (int nt = 0; nt < 2; ++nt) ae[mt][nt] = (floatx4){0.f,0.f,0.f,0.f};
  {
    short8 a0 = *(const short8*)(A2 + (wave*32 + l15)*40 + quad*8);
    short8 a1 = *(const short8*)(A2 + (wave*32 + 16 + l15)*40 + quad*8);
    #pragma unroll
    for (int nt = 0; nt < 2; ++nt){
      short8 b = *(const short8*)(B2 + (nt*16 + l15)*40 + quad*8);
      ae[0][nt] = __builtin_amdgcn_mfma_f32_16x16x32_bf16(a0, b, ae[0][nt], 0, 0, 0);
      ae[1][nt] = __builtin_amdgcn_mfma_f32_16x16x32_bf16(a1, b, ae[1][nt], 0, 0, 0);
    }
  }
  __syncthreads();    // all A2 (silu-u) reads done before overwrite with eg
  #pragma unroll
  for (int mt = 0; mt < 2; ++mt)
    #pragma unroll
    for (int nt = 0; nt < 2; ++nt)
      #pragma unroll
      for (int reg = 0; reg < 4; ++reg){
        int r = wave*32 + mt*16 + quad*4 + reg;
        int c = nt*16 + l15;
        float ev = ae[mt][nt][reg] + Wf[OFF_BE2 + c];
        A2[r*40 + c] = f2b(ev);
      }
  __syncthreads();
  // edge copy-out (coalesced)
  {
    int r = tid >> 1, p = tid & 1;
    const uint4* srcp = (const uint4*)(A2 + r*40 + p*16);
    uint4* dstp = (uint4*)(edge + (size_t)(row0 + r)*32 + p*16);
    dstp[0] = srcp[0]; dstp[1] = srcp[1];
  }
  // logits = celu(A2 @ B3 + batt)  (N=16, 7 used)
  floatx4 al_[2];
  al_[0] = (floatx4){0.f,0.f,0.f,0.f};
  al_[1] = (floatx4){0.f,0.f,0.f,0.f};
  {
    short8 a0 = *(const short8*)(A2 + (wave*32 + l15)*40 + quad*8);
    short8 a1 = *(const short8*)(A2 + (wave*32 + 16 + l15)*40 + quad*8);
    short8 b = *(const short8*)(B3 + l15*40 + quad*8);
    al_[0] = __builtin_amdgcn_mfma_f32_16x16x32_bf16(a0, b, al_[0], 0, 0, 0);
    al_[1] = __builtin_amdgcn_mfma_f32_16x16x32_bf16(a1, b, al_[1], 0, 0, 0);
  }
  if (l15 < 7){
    float ba = Wf[OFF_BATT + l15];
    #pragma unroll
    for (int mt = 0; mt < 2; ++mt)
      #pragma unroll
      for (int reg = 0; reg < 4; ++reg){
        int r = wave*32 + mt*16 + quad*4 + reg;
        float vv = al_[mt][reg] + ba;
        float cl = vv > 0.f ? vv : 2.f * expm1f(0.5f * vv);
        logits[(size_t)(row0 + r)*7 + l15] = cl;
      }
  }
}

// -------- segment softmax + hsem accumulation (16-lane group per atom) ------
__global__ __launch_bounds__(256) void k_att(const int* __restrict__ offs,
    const float* __restrict__ logits, const u16* __restrict__ edge,
    float* __restrict__ atts, float* __restrict__ hsem){
  int a = blockIdx.x * 16 + (threadIdx.x >> 4);   // N = 625*16
  int lane = threadIdx.x & 15;
  int off = offs[a], end = offs[a+1];
  float m[7];
  #pragma unroll
  for (int hh = 0; hh < 7; ++hh) m[hh] = -1e30f;
  for (int s = off + lane; s < end; s += 16){
    #pragma unroll
    for (int hh = 0; hh < 7; ++hh) m[hh] = fmaxf(m[hh], logits[s*7+hh]);
  }
  #pragma unroll
  for (int hh = 0; hh < 7; ++hh){
    float v = m[hh];
    #pragma unroll
    for (int msk = 8; msk >= 1; msk >>= 1) v = fmaxf(v, __shfl_xor(v, msk));
    m[hh] = v;
  }
  float sm[7] = {0,0,0,0,0,0,0};
  for (int s = off + lane; s < end; s += 16){
    #pragma unroll
    for (int hh = 0; hh < 7; ++hh){
      float e = __expf(logits[s*7+hh] - m[hh]);
      sm[hh] += e;
      atts[s*7+hh] = e;
    }
  }
  #pragma unroll
  for (int hh = 0; hh < 7; ++hh){
    float v = sm[hh];
    #pragma unroll
    for (int msk = 8; msk >= 1; msk >>= 1) v += __shfl_xor(v, msk);
    sm[hh] = 1.f / v;
  }
  for (int s = off + lane; s < end; s += 16){
    #pragma unroll
    for (int hh = 0; hh < 7; ++hh) atts[s*7+hh] *= sm[hh];
  }
  __syncthreads();
  float acc[14] = {0,0,0,0,0,0,0,0,0,0,0,0,0,0};
  for (int s = off; s < end; ++s){
    u32 ev = *(const u32*)(edge + (size_t)s * 32 + lane * 2);
    float e0 = b2f((u16)(ev & 0xFFFFu));
    float e1 = b2f((u16)(ev >> 16));
    const float* ap = atts + (size_t)s * 7;
    #pragma unroll
    for (int hh = 0; hh < 7; ++hh){
      float at = ap[hh];
      acc[hh]     += e0 * at;
      acc[7 + hh] += e1 * at;
    }
  }
  float* hp = hsem + (size_t)a * 224 + lane * 14;
  #pragma unroll
  for (int jj = 0; jj < 14; ++jj) hp[jj] = acc[jj];
}

// -------- MFMA GEMM, M=64 tile, half-width (112 cols), 38.7KB LDS -----------
// LDS: As [64][232]u16 = 29696 (xth [64][120] overlays after MFMA)
//      Bs [112][40]u16 = 8960 @29696 (eL [64][36]=4608 + aL 1792 overlay, dead after pack)
#define G_BS   29696
#define G_EL   29696
#define G_AL   (29696 + 4608)
#define G_TOT  38656

__global__ __launch_bounds__(256, 4) void k_gemm3(const u16* __restrict__ edge,
    const float* __restrict__ atts, const u16* __restrict__ BT,
    u16* __restrict__ xhalf, int half){
  __shared__ __attribute__((aligned(16))) char smem[G_TOT];
  u16*   As  = (u16*)smem;                 // stride 232 u16 (116 u32)
  u16*   xth = (u16*)smem;                 // stride 120 u16, overlays As after MFMA
  u16*   Bs  = (u16*)(smem + G_BS);        // stride 40 u16
  u16*   eL  = (u16*)(smem + G_EL);        // stride 36 u16 (overlay, dead after pack)
  float* aL  = (float*)(smem + G_AL);      // stride 7 floats (overlay)
  int tid = threadIdx.x;
  int wave = tid >> 6, lane = tid & 63, l15 = lane & 15, quad = lane >> 4;
  int row0 = blockIdx.x * 64;
  int nbase = half * 112;

  // stage edge rows (padded stride 36) + atts
  for (int e = tid; e < 512; e += 256){
    int r = e >> 3, q = e & 7;
    *(uint2*)(eL + r*36 + q*4) = *(const uint2*)(edge + (size_t)(row0 + r)*32 + q*4);
  }
  for (int e = tid; e < 448; e += 256) aL[e] = atts[(size_t)row0*7 + e];
  floatx4 acc[7];
  #pragma unroll
  for (int nt = 0; nt < 7; ++nt) acc[nt] = (floatx4){0.f, 0.f, 0.f, 0.f};
  __syncthreads();

  // pack full-K A-tile once: thread t -> row t>>2, quarter (t&3)*56 cols (8 f's)
  {
    int pr = tid >> 2, q = tid & 3;
    u32* asw = (u32*)As + pr*116 + q*28;
    const u16* er = eL + pr*36 + q*8;
    const float* ar = aL + pr*7;
    float av[7];
    #pragma unroll
    for (int hh = 0; hh < 7; ++hh) av[hh] = ar[hh];
    #pragma unroll
    for (int fo2 = 0; fo2 < 4; ++fo2){
      float e0 = b2f(er[2*fo2]);
      float e1 = b2f(er[2*fo2+1]);
      u16 w[14];
      #pragma unroll
      for (int hh = 0; hh < 7; ++hh){
        w[hh]   = f2b(e0 * av[hh]);
        w[7+hh] = f2b(e1 * av[hh]);
      }
      #pragma unroll
      for (int k = 0; k < 7; ++k)
        asw[fo2*7 + k] = (u32)w[2*k] | ((u32)w[2*k+1] << 16);
    }
  }
  __syncthreads();          // As ready; eL/aL dead -> Bs usable

  for (int kt = 0; kt < 7; ++kt){
    // stage Bs (single-buffered, 112 rows x 32 K)
    for (int e = tid; e < 448; e += 256){
      int r = e >> 2, q = e & 3;
      *(uint4*)(Bs + r*40 + q*8) = *(const uint4*)(BT + (size_t)(nbase + r)*224 + kt*32 + q*8);
    }
    __syncthreads();
    int kk = kt * 32;
    short8 a0 = *(const short8*)(As + (wave*16 + l15)*232 + kk + quad*8);
    #pragma unroll
    for (int nt = 0; nt < 7; ++nt){
      short8 b = *(const short8*)(Bs + (nt*16 + l15)*40 + quad*8);
      acc[nt] = __builtin_amdgcn_mfma_f32_16x16x32_bf16(a0, b, acc[nt], 0, 0, 0);
    }
    __syncthreads();        // MFMA reads done before next stage overwrites Bs
  }

  // tanh epilogue -> xth (stride 120), wave-local rows (overlays As; safe after loop barrier)
  #pragma unroll
  for (int nt = 0; nt < 7; ++nt)
    #pragma unroll
    for (int reg = 0; reg < 4; ++reg){
      int r = wave*16 + quad*4 + reg;
      int c = nt*16 + l15;
      float vv = acc[nt][reg];
      vv = fminf(fmaxf(vv, -15.f), 15.f);
      float e2 = __expf(2.f * vv);
      xth[r*120 + c] = f2b((e2 - 1.f) / (e2 + 1.f));
    }
  __syncthreads();
  // coalesced copy-out: 64 rows x 14 uint4
  for (int e = tid; e < 896; e += 256){
    int r = e / 14, w = e - r * 14;
    *(uint4*)(xhalf + (size_t)(row0 + r)*112 + w*8) = *(const uint4*)(xth + r*120 + w*8);
  }
}

// -------- atom-centric comb reduction: xhalf -> nsq half + pv partial -------
__global__ __launch_bounds__(256) void k_comb(const int* __restrict__ offs,
    const u16* __restrict__ xhalf, const float* __restrict__ dirs,
    const float* __restrict__ Wf, int half,
    float* __restrict__ nsq, float* __restrict__ pvh){
  int a = blockIdx.x * 16 + (threadIdx.x >> 4);
  int lane = threadIdx.x & 15;
  int off = offs[a], end = offs[a+1];
  float c0[7] = {0,0,0,0,0,0,0}, c1[7] = {0,0,0,0,0,0,0}, c2[7] = {0,0,0,0,0,0,0};
  for (int s = off; s < end; ++s){
    float d0 = dirs[s*3+0], d1 = dirs[s*3+1], d2 = dirs[s*3+2];
    const u16* xr = xhalf + (size_t)s * 112 + lane;
    #pragma unroll
    for (int k = 0; k < 7; ++k){
      float xm = b2f(xr[k*16]);
      c0[k] += d0 * xm; c1[k] += d1 * xm; c2[k] += d2 * xm;
    }
  }
  float inv = 1.f / fmaxf((float)(end - off), 1.f);
  float pv0 = 0.f, pv1 = 0.f, pv2 = 0.f;
  #pragma unroll
  for (int k = 0; k < 7; ++k){
    float m0 = c0[k]*inv, m1 = c1[k]*inv, m2 = c2[k]*inv;
    int c = half*112 + k*16 + lane;
    nsq[(size_t)a*224 + c] = m0*m0 + m1*m1 + m2*m2;
    float wv = Wf[OFF_WVMIX + c];
    pv0 += wv*m0; pv1 += wv*m1; pv2 += wv*m2;
  }
  #pragma unroll
  for (int m = 8; m >= 1; m >>= 1){
    pv0 += __shfl_xor(pv0, m); pv1 += __shfl_xor(pv1, m); pv2 += __shfl_xor(pv2, m);
  }
  if (lane == 0){
    float* pp = pvh + (size_t)half*30000 + (size_t)a*3;
    pp[0] = pv0; pp[1] = pv1; pp[2] = pv2;
  }
}

// ---------------- final: wave per atom, precomputed hsem/nsq/pv -------------
__global__ __launch_bounds__(256) void k_final4(const float* __restrict__ h,
    const float* __restrict__ x, const float* __restrict__ v,
    const float* __restrict__ Wf, const float* __restrict__ hsem,
    const float* __restrict__ nsq, const float* __restrict__ pvh,
    float* __restrict__ out){
  __shared__ float s_in[4][288];
  __shared__ float s_nsq[4][224];
  __shared__ float s_u1[4][32], s_g[4][32], s_un[4][32];
  int wv_ = threadIdx.x >> 6, lane = threadIdx.x & 63;
  int a = blockIdx.x * 4 + wv_;
  if (lane < 56){
    int c4 = lane * 4;
    float4 hs = *(const float4*)(hsem + (size_t)a*224 + c4);
    float4 nq = *(const float4*)(nsq + (size_t)a*224 + c4);
    s_in[wv_][32 + c4+0] = hs.x; s_in[wv_][32 + c4+1] = hs.y;
    s_in[wv_][32 + c4+2] = hs.z; s_in[wv_][32 + c4+3] = hs.w;
    s_nsq[wv_][c4+0] = nq.x; s_nsq[wv_][c4+1] = nq.y;
    s_nsq[wv_][c4+2] = nq.z; s_nsq[wv_][c4+3] = nq.w;
  } else {
    int k4 = (lane - 56) * 4;
    float4 hv = *(const float4*)(h + (size_t)a*32 + k4);
    s_in[wv_][k4+0] = hv.x; s_in[wv_][k4+1] = hv.y;
    s_in[wv_][k4+2] = hv.z; s_in[wv_][k4+3] = hv.w;
  }
  __syncthreads();
  int o = lane & 31, kh = lane >> 5;
  {
    float u = 0.f;
    const float* q = &s_nsq[wv_][kh*112];
    const float* w = Wf + OFF_WP1 + (kh*112)*32 + o;
    #pragma unroll 4
    for (int kk = 0; kk < 112; ++kk) u += q[kk] * w[kk*32];
    u += __shfl_xor(u, 32);
    if (lane < 32) s_u1[wv_][o] = siluf(u + Wf[OFF_BP1 + o]);
  }
  {
    float g = 0.f;
    const float* q = &s_in[wv_][kh*16];
    const float* w = Wf + OFF_WV1 + (kh*16)*32 + o;
    #pragma unroll
    for (int kk = 0; kk < 16; ++kk) g += q[kk] * w[kk*32];
    g += __shfl_xor(g, 32);
    if (lane < 32) s_g[wv_][o] = siluf(g + Wf[OFF_BV1 + o]);
  }
  __syncthreads();
  float zpart = (lane < 32) ? s_g[wv_][lane] * Wf[OFF_WV2 + lane] : 0.f;
  #pragma unroll
  for (int m = 32; m >= 1; m >>= 1) zpart += __shfl_xor(zpart, m);
  float sc = 2.f / (1.f + __expf(-zpart));
  {
    float u = 0.f;
    const float* q = &s_u1[wv_][kh*16];
    const float* w = Wf + OFF_WP2 + (kh*16)*32 + o;
    #pragma unroll
    for (int kk = 0; kk < 16; ++kk) u += q[kk] * w[kk*32];
    u += __shfl_xor(u, 32);
    if (lane < 32) s_in[wv_][256 + o] = siluf(u + Wf[OFF_BP2 + o]);
  }
  __syncthreads();
  {
    float u = 0.f;
    const float* q = &s_in[wv_][kh*144];
    const float* w = Wf + OFF_WN1 + (kh*144)*32 + o;
    #pragma unroll 4
    for (int kk = 0; kk < 144; ++kk) u += q[kk] * w[kk*32];
    u += __shfl_xor(u, 32);
    if (lane < 32) s_un[wv_][o] = siluf(u + Wf[OFF_BN1 + o]);
  }
  __syncthreads();
  if (lane < 32){
    float u = Wf[OFF_BN2 + lane];
    #pragma unroll
    for (int k = 0; k < 32; ++k) u += s_un[wv_][k] * Wf[OFF_WN2 + k*32 + lane];
    out[a*32 + lane] = s_in[wv_][lane] + siluf(u);
  }
  if (lane < 3){
    float pv = pvh[(size_t)a*3 + lane] + pvh[30000 + (size_t)a*3 + lane];
    float vup = sc * v[a*3+lane] + pv;
    float xup = x[a*3+lane] + vup;
    out[N_ATOMS*32 + a*3 + lane] = xup;
    out[N_ATOMS*32 + N_ATOMS*3 + a*3 + lane] = vup;
  }
}

// ---------------- workspace layout ----------------
static constexpr size_t al256(size_t x){ return (x + 255) & ~(size_t)255; }
static constexpr size_t WS_FLAGS   = 0;
static constexpr size_t WS_COUNTS  = al256(WS_FLAGS + 8);
static constexpr size_t WS_OFFSETS = al256(WS_COUNTS + (size_t)N_ATOMS * 4);
static constexpr size_t WS_CURSOR  = al256(WS_OFFSETS + (size_t)(N_ATOMS + 1) * 4);
static constexpr size_t WS_PERM    = al256(WS_CURSOR + (size_t)N_ATOMS * 4);   // isrt
static constexpr size_t WS_PLI     = al256(WS_PERM + (size_t)P_PAIRS * 4);
static constexpr size_t WS_HF      = al256(WS_PLI + (size_t)2 * P_PAIRS * 4);
static constexpr size_t WS_XF      = al256(WS_HF + (size_t)N_ATOMS * 32 * 4);
static constexpr size_t WS_VF      = al256(WS_XF + (size_t)N_ATOMS * 3 * 4);
static constexpr size_t WS_WF      = al256(WS_VF + (size_t)N_ATOMS * 3 * 4);
static constexpr size_t WS_WT      = al256(WS_WF + (size_t)WF_TOTAL * 4);
static constexpr size_t WS_EDGE    = al256(WS_WT + (size_t)224 * 224 * 2);
static constexpr size_t WS_ATTS    = al256(WS_EDGE + (size_t)P_PAIRS * 32 * 2);
static constexpr size_t WS_DIRS    = al256(WS_ATTS + (size_t)P_PAIRS * 7 * 4);
static constexpr size_t WS_LOGITS  = al256(WS_DIRS + (size_t)P_PAIRS * 3 * 4);
static constexpr size_t WS_PREI    = al256(WS_LOGITS + (size_t)P_PAIRS * 7 * 4);
static constexpr size_t WS_PREJ    = al256(WS_PREI + (size_t)N_ATOMS * 88 * 2);
static constexpr size_t WS_HSEM    = WS_LOGITS + 4480000;
static constexpr size_t WS_XH      = WS_HSEM + (size_t)N_ATOMS * 224 * 4;
static constexpr size_t WS_NSQ     = WS_XH + (size_t)P_PAIRS * 112 * 2;
static constexpr size_t WS_PVH     = WS_NSQ + (size_t)N_ATOMS * 224 * 4;
static constexpr size_t WS_JSRT    = al256(WS_PVH + (size_t)2 * 30000 * 4);
static constexpr size_t WS_BPK     = al256(WS_JSRT + (size_t)P_PAIRS * 4);
static constexpr size_t WS_END     = WS_BPK + 3584 * 2;
static_assert(WS_PREJ + (size_t)N_ATOMS * 88 * 2 <= WS_XH, "pre tables before xhalf");
static_assert(WS_END <= WS_LOGITS + (size_t)P_PAIRS * 224 * 2, "within round-1-proven footprint");
static_assert(WS_HSEM % 256 == 0 && WS_XH % 256 == 0 && WS_NSQ % 256 == 0 && WS_PVH % 256 == 0, "alignment");

extern "C" void kernel_launch(void* const* d_in, const int* in_sizes, int n_in,
                              void* d_out, int out_size, void* d_ws, size_t ws_size,
                              hipStream_t stream){
  (void)in_sizes; (void)n_in;
  if (out_size != 380000 || ws_size < WS_END){
    k_code<<<1, 64, 0, stream>>>((float*)d_out, 14000.f);
    return;
  }
  char* ws = (char*)d_ws;
  int*   counts = (int*)(ws + WS_COUNTS);
  int*   offs   = (int*)(ws + WS_OFFSETS);
  int*   cursor = (int*)(ws + WS_CURSOR);
  int*   isrt   = (int*)(ws + WS_PERM);
  int*   pli    = (int*)(ws + WS_PLI);
  float* hf     = (float*)(ws + WS_HF);
  float* xf     = (float*)(ws + WS_XF);
  float* vf     = (float*)(ws + WS_VF);
  float* Wf     = (float*)(ws + WS_WF);
  u16*   wT     = (u16*)(ws + WS_WT);
  u16*   edge   = (u16*)(ws + WS_EDGE);
  float* atts   = (float*)(ws + WS_ATTS);
  float* dirs   = (float*)(ws + WS_DIRS);
  float* logits = (float*)(ws + WS_LOGITS);
  u16*   prei   = (u16*)(ws + WS_PREI);
  u16*   prej   = (u16*)(ws + WS_PREJ);
  float* hsem   = (float*)(ws + WS_HSEM);
  u16*   xhalf  = (u16*)(ws + WS_XH);
  float* nsq    = (float*)(ws + WS_NSQ);
  float* pvh    = (float*)(ws + WS_PVH);
  int*   jsrt   = (int*)(ws + WS_JSRT);
  u16*   bpk    = (u16*)(ws + WS_BPK);

  hipMemsetAsync(counts, 0, (size_t)N_ATOMS * 4, stream);
  k_prep<<<NBP_HIST, 256, 0, stream>>>(d_in[0], d_in[1], d_in[2], d_in[3],
      d_in[4],  d_in[5],  d_in[6],  d_in[7],  d_in[8],  d_in[9],  d_in[10], d_in[11],
      d_in[12], d_in[13], d_in[14], d_in[15], d_in[16], d_in[17], d_in[18], d_in[19],
      d_in[20], d_in[21], d_in[22], d_in[24], d_in[23],
      hf, xf, vf, pli, Wf, wT, bpk, counts);
  k_atomscan<<<626, 256, 0, stream>>>(hf, Wf, prei, prej, counts, offs, cursor);
  k_scatter<<<P_PAIRS / 256, 256, 0, stream>>>(pli, cursor, isrt, jsrt);
  k_pairm<<<P_PAIRS / 128, 256, 0, stream>>>(xf, Wf, prei, prej, isrt, jsrt, bpk, edge, logits, dirs);
  k_att<<<N_ATOMS / 16, 256, 0, stream>>>(offs, logits, edge, atts, hsem);
  k_gemm3<<<P_PAIRS / 64, 256, 0, stream>>>(edge, atts, wT, xhalf, 0);
  k_comb<<<N_ATOMS / 16, 256, 0, stream>>>(offs, xhalf, dirs, Wf, 0, nsq, pvh);
  k_gemm3<<<P_PAIRS / 64, 256, 0, stream>>>(edge, atts, wT, xhalf, 1);
  k_comb<<<N_ATOMS / 16, 256, 0, stream>>>(offs, xhalf, dirs, Wf, 1, nsq, pvh);
  k_final4<<<N_ATOMS / 4, 256, 0, stream>>>(hf, xf, vf, Wf, hsem, nsq, pvh, (float*)d_out);
}

// Round 10
// 343.109 us; speedup vs baseline: 1.2707x; 1.0292x over previous
//
#include <hip/hip_runtime.h>

typedef unsigned short u16;
typedef unsigned int u32;
typedef __attribute__((ext_vector_type(8))) short short8;
typedef __attribute__((ext_vector_type(4))) float floatx4;

#define P_PAIRS 160000
#define N_ATOMS 10000

#define OFF_WMLP  0      // stored TRANSPOSED: [50][64], (o,k) at o*64+k
#define OFF_BMLP  3200
#define OFF_WE1   3250
#define OFF_BE1   6930
#define OFF_WE2   6962
#define OFF_BE2   7986
#define OFF_WATT  8018
#define OFF_BATT  8242
#define OFF_WN1   8249
#define OFF_BN1   17465
#define OFF_WN2   17497
#define OFF_BN2   18521
#define OFF_WP1   18553
#define OFF_BP1   25721
#define OFF_WP2   25753
#define OFF_BP2   26777
#define OFF_WV1   26809
#define OFF_BV1   27833
#define OFF_WV2   27865
#define OFF_WVMIX 27897
#define WF_TOTAL  28121

__device__ __forceinline__ float b2f(u16 u){ return __uint_as_float(((u32)u) << 16); }
__device__ __forceinline__ u16 f2b(float f){
  u32 u = __float_as_uint(f);
  u32 r = (u + 0x7FFFu + ((u >> 16) & 1u)) >> 16;
  return (u16)r;
}
__device__ __forceinline__ void unpack2(u32 p, float& lo, float& hi){
  lo = __uint_as_float(p << 16);
  hi = __uint_as_float(p & 0xFFFF0000u);
}
__device__ __forceinline__ float siluf(float v){ return v / (1.f + __expf(-v)); }
__device__ __forceinline__ float ldw(const void* p, int o, int bf){
  return bf ? b2f(((const u16*)p)[o]) : ((const float*)p)[o];
}

__global__ void k_code(float* out, float code){
  if (threadIdx.x == 0 && blockIdx.x == 0) out[0] = code;
}

// per-block dtype detection (wave 0 ballot), replaces k_detect dispatch
__device__ __forceinline__ void detect_flags(const u32* hw, const u32* plw, int* s_fl){
  int tid = threadIdx.x;
  if (tid < 64){
    u32 e = (hw[tid] >> 7) & 0xFFu;
    unsigned long long m1 = __ballot(e >= 100u && e <= 140u);
    unsigned long long m2 = __ballot(plw[2*tid+1] == 0u);
    if (tid == 0){
      s_fl[0] = (__popcll(m1) >= 48) ? 1 : 0;
      s_fl[1] = (__popcll(m2) >= 60) ? 1 : 0;
    }
  }
  __syncthreads();
}

// ------------- fused preprocessing: norm + convert + transpose + bpk + hist -
#define NBP_NORM 2735
#define NBP_CONV (NBP_NORM + 110)
#define NBP_TRAN (NBP_CONV + 196)
#define NBP_PB   (NBP_TRAN + 14)
#define NBP_HIST (NBP_PB + 625)

__global__ void k_prep(const void* __restrict__ h_raw, const void* __restrict__ x_raw,
    const void* __restrict__ v_raw, const void* __restrict__ pl_raw,
    const void* w_mlp, const void* b_mlp, const void* w_e1, const void* b_e1,
    const void* w_e2, const void* b_e2, const void* w_att, const void* b_att,
    const void* w_n1, const void* b_n1, const void* w_n2, const void* b_n2,
    const void* w_p1, const void* b_p1, const void* w_p2, const void* b_p2,
    const void* w_v1, const void* b_v1, const void* w_v2, const void* w_vmix,
    const void* wx,
    float* __restrict__ hf, float* __restrict__ xf, float* __restrict__ vf,
    int* __restrict__ pli, float* __restrict__ Wf, u16* __restrict__ wT,
    u16* __restrict__ bpk, int* __restrict__ counts){
  __shared__ int s_fl[2];
  detect_flags((const u32*)h_raw, (const u32*)pl_raw, s_fl);
  int bf = s_fl[0], i64 = s_fl[1];
  int bid = blockIdx.x, tid = threadIdx.x;
  if (bid < NBP_NORM){
    int t = bid * 256 + tid;
    if (t < 320000){
      hf[t] = ldw(h_raw, t, bf);
    } else if (t < 350000){
      int i = t - 320000; xf[i] = ldw(x_raw, i, bf);
    } else if (t < 380000){
      int i = t - 350000; vf[i] = ldw(v_raw, i, bf);
    } else if (t < 700000){
      int k = t - 380000;
      const int* p32 = (const int*)pl_raw;
      pli[k] = i64 ? p32[2*(size_t)k] : p32[k];
    }
  } else if (bid < NBP_CONV){
    int t = (bid - NBP_NORM) * 256 + tid;
    if (t >= WF_TOTAL) return;
    if (t < 3200){
      int k = t / 50, o = t - k * 50;
      Wf[OFF_WMLP + o * 64 + k] = ldw(w_mlp, t, bf);
      return;
    }
    const void* src; int o;
    if      (t < 3250)  { src = b_mlp;  o = t - 3200; }
    else if (t < 6930)  { src = w_e1;   o = t - 3250; }
    else if (t < 6962)  { src = b_e1;   o = t - 6930; }
    else if (t < 7986)  { src = w_e2;   o = t - 6962; }
    else if (t < 8018)  { src = b_e2;   o = t - 7986; }
    else if (t < 8242)  { src = w_att;  o = t - 8018; }
    else if (t < 8249)  { src = b_att;  o = t - 8242; }
    else if (t < 17465) { src = w_n1;   o = t - 8249; }
    else if (t < 17497) { src = b_n1;   o = t - 17465; }
    else if (t < 18521) { src = w_n2;   o = t - 17497; }
    else if (t < 18553) { src = b_n2;   o = t - 18521; }
    else if (t < 25721) { src = w_p1;   o = t - 18553; }
    else if (t < 25753) { src = b_p1;   o = t - 25721; }
    else if (t < 26777) { src = w_p2;   o = t - 25753; }
    else if (t < 26809) { src = b_p2;   o = t - 26777; }
    else if (t < 27833) { src = w_v1;   o = t - 26809; }
    else if (t < 27865) { src = b_v1;   o = t - 27833; }
    else if (t < 27897) { src = w_v2;   o = t - 27865; }
    else                { src = w_vmix; o = t - 27897; }
    Wf[t] = ldw(src, o, bf);
  } else if (bid < NBP_TRAN){
    int t = (bid - NBP_CONV) * 256 + tid;
    if (t >= 224 * 224) return;
    int n = t / 224, k = t - n * 224;
    wT[t] = f2b(ldw(wx, k * 224 + n, bf));
  } else if (bid < NBP_PB){
    // bpk: B1T [32][64] | B2T [32][32] | B3T [16][32]  (bf16, from RAW weights)
    int t = (bid - NBP_TRAN) * 256 + tid;
    if (t >= 3584) return;
    float v = 0.f;
    if (t < 2048){
      int n = t >> 6, k = t & 63;
      if (k < 50)       v = ldw(w_e1, (64 + k) * 32 + n, bf);
      else if (k == 50) v = ldw(w_e1, 114 * 32 + n, bf);
    } else if (t < 3072){
      int e = t - 2048; int n = e >> 5, k = e & 31;
      v = ldw(w_e2, k * 32 + n, bf);
    } else {
      int e = t - 3072; int n = e >> 5, k = e & 31;
      if (n < 7) v = ldw(w_att, k * 7 + n, bf);
    }
    bpk[t] = f2b(v);
  } else {
    int p = (bid - NBP_PB) * 256 + tid;     // hist from raw pairlist
    const int* p32 = (const int*)pl_raw;
    int i = i64 ? p32[2*(size_t)p] : p32[p];
    atomicAdd(&counts[i], 1);
  }
}

// ---------- fused: per-atom projections (625 fat blocks) + scan (1 block) ---
// 16 atoms/block; hs padded [16][33] to avoid same-bank across atoms.
__global__ void k_atomscan(const float* __restrict__ hf, const float* __restrict__ Wf,
    u16* __restrict__ prei, u16* __restrict__ prej,
    const int* __restrict__ counts, int* __restrict__ offs, int* __restrict__ cursor){
  __shared__ float hs[16][33];
  __shared__ int part[256];
  int tid = threadIdx.x;
  if (blockIdx.x < 625){
    int a0 = blockIdx.x * 16;
    for (int e = tid; e < 512; e += 256){
      int a = e >> 5, k = e & 31;
      hs[a][k] = hf[(size_t)(a0 + a) * 32 + k];
    }
    __syncthreads();
    // prei tb (50/atom): b_mlp + h @ Wmlp_top
    for (int e = tid; e < 800; e += 256){
      int a = e / 50, r = e - a * 50;
      const float* wm = Wf + OFF_WMLP + r * 64;
      float acc = Wf[OFF_BMLP + r];
      #pragma unroll
      for (int k = 0; k < 32; ++k) acc += hs[a][k] * wm[k];
      prei[(size_t)(a0 + a) * 88 + 32 + r] = f2b(acc);
    }
    // prej tb (50/atom): h @ Wmlp_bot
    for (int e = tid; e < 800; e += 256){
      int a = e / 50, r = e - a * 50;
      const float* wm = Wf + OFF_WMLP + r * 64 + 32;
      float acc = 0.f;
      #pragma unroll
      for (int k = 0; k < 32; ++k) acc += hs[a][k] * wm[k];
      prej[(size_t)(a0 + a) * 88 + 32 + r] = f2b(acc);
    }
    // prei u (32/atom): b_e1 + h @ WE1[0:32]
    for (int e = tid; e < 512; e += 256){
      int a = e >> 5, o = e & 31;
      float acc = Wf[OFF_BE1 + o];
      #pragma unroll
      for (int k = 0; k < 32; ++k) acc += hs[a][k] * Wf[OFF_WE1 + k * 32 + o];
      prei[(size_t)(a0 + a) * 88 + o] = f2b(acc);
    }
    // prej u (32/atom): h @ WE1[32:64]
    for (int e = tid; e < 512; e += 256){
      int a = e >> 5, o = e & 31;
      float acc = 0.f;
      #pragma unroll
      for (int k = 0; k < 32; ++k) acc += hs[a][k] * Wf[OFF_WE1 + (32 + k) * 32 + o];
      prej[(size_t)(a0 + a) * 88 + o] = f2b(acc);
    }
  } else {
    int sum = 0;
    for (int k = 0; k < 40; ++k){
      int idx = tid * 40 + k;
      if (idx < N_ATOMS) sum += counts[idx];
    }
    part[tid] = sum;
    __syncthreads();
    if (tid == 0){
      int run = 0;
      for (int q = 0; q < 256; ++q){ int tmp = part[q]; part[q] = run; run += tmp; }
    }
    __syncthreads();
    int run = part[tid];
    for (int k = 0; k < 40; ++k){
      int idx = tid * 40 + k;
      if (idx < N_ATOMS){ offs[idx] = run; cursor[idx] = run; run += counts[idx]; }
    }
    if (tid == 0) offs[N_ATOMS] = P_PAIRS;
  }
}

__global__ void k_scatter(const int* __restrict__ pl, int* __restrict__ cursor,
                          int* __restrict__ isrt, int* __restrict__ jsrt){
  int p = blockIdx.x * 256 + threadIdx.x;
  int i = pl[p];
  int pos = atomicAdd(&cursor[i], 1);
  isrt[pos] = i;
  jsrt[pos] = pl[P_PAIRS + p];
}

// ------- per-pair edge model via MFMA: 128 pairs/block, 4 waves -------------
// LDS: UB f32[128][32] | TB u16[128][56] | DD f32[128] | A1 u16[128][72]
//      B1 u16[32][72] | A2 u16[128][40] (silu-u, then eg) | B2 u16[32][40] | B3 u16[16][40]
#define PM_UB   0
#define PM_TB   16384
#define PM_DD   30720
#define PM_A1   31232
#define PM_B1   49664
#define PM_A2   54272
#define PM_B2   64512
#define PM_B3   67072
#define PM_TOT  68352

__global__ __launch_bounds__(256) void k_pairm(const float* __restrict__ x,
    const float* __restrict__ Wf, const u16* __restrict__ prei, const u16* __restrict__ prej,
    const int* __restrict__ isrt, const int* __restrict__ jsrt, const u16* __restrict__ bpk,
    u16* __restrict__ edge, float* __restrict__ logits, float* __restrict__ dirs){
  __shared__ __attribute__((aligned(16))) char smem[PM_TOT];
  float* UB = (float*)(smem + PM_UB);
  u16*   TB = (u16*)(smem + PM_TB);
  float* DD = (float*)(smem + PM_DD);
  u16*   A1 = (u16*)(smem + PM_A1);
  u16*   B1 = (u16*)(smem + PM_B1);
  u16*   A2 = (u16*)(smem + PM_A2);
  u16*   B2 = (u16*)(smem + PM_B2);
  u16*   B3 = (u16*)(smem + PM_B3);
  int tid = threadIdx.x;
  int wave = tid >> 6, lane = tid & 63, l15 = lane & 15, quad = lane >> 4;
  int row0 = blockIdx.x * 128;

  if (tid < 128){
    int s = row0 + tid;
    int i = isrt[s], j = jsrt[s];
    float r0 = x[j*3+0] - x[i*3+0];
    float r1 = x[j*3+1] - x[i*3+1];
    float r2 = x[j*3+2] - x[i*3+2];
    float d = sqrtf(r0*r0 + r1*r1 + r2*r2);
    float rinv = 1.f / (d + 1e-5f);
    dirs[s*3+0] = r0*rinv; dirs[s*3+1] = r1*rinv; dirs[s*3+2] = r2*rinv;
    DD[tid] = d;
    const uint4* pi4 = (const uint4*)(prei + (size_t)i * 88);
    const uint4* pj4 = (const uint4*)(prej + (size_t)j * 88);
    float* ub = UB + tid * 32;
    #pragma unroll
    for (int q = 0; q < 4; ++q){
      uint4 a4 = pi4[q], b4 = pj4[q];
      u32 pa[4] = {a4.x, a4.y, a4.z, a4.w};
      u32 pb[4] = {b4.x, b4.y, b4.z, b4.w};
      #pragma unroll
      for (int w2 = 0; w2 < 4; ++w2){
        float al, ah, bl, bh;
        unpack2(pa[w2], al, ah); unpack2(pb[w2], bl, bh);
        ub[q*8 + w2*2]     = al + bl;
        ub[q*8 + w2*2 + 1] = ah + bh;
      }
    }
    u32* tb = (u32*)TB + tid * 28;
    #pragma unroll
    for (int q = 0; q < 7; ++q){
      uint4 a4 = pi4[4+q], b4 = pj4[4+q];
      u32 pa[4] = {a4.x, a4.y, a4.z, a4.w};
      u32 pb[4] = {b4.x, b4.y, b4.z, b4.w};
      #pragma unroll
      for (int w2 = 0; w2 < 4; ++w2){
        float al, ah, bl, bh;
        unpack2(pa[w2], al, ah); unpack2(pb[w2], bl, bh);
        tb[q*4 + w2] = (u32)f2b(al + bl) | ((u32)f2b(ah + bh) << 16);
      }
    }
  } else {
    int t2 = tid - 128;
    const u32* src = (const u32*)bpk;
    for (int e = t2; e < 1024; e += 128){         // B1T [32][64] -> stride 36 u32
      int n = e >> 5, kp = e & 31;
      ((u32*)B1)[n*36 + kp] = src[e];
    }
    for (int e = t2; e < 512; e += 128){          // B2T [32][32] -> stride 20 u32
      int n = e >> 4, kp = e & 15;
      ((u32*)B2)[n*20 + kp] = src[1024 + e];
    }
    for (int e = t2; e < 256; e += 128){          // B3T [16][32] -> stride 20 u32
      int n = e >> 4, kp = e & 15;
      ((u32*)B3)[n*20 + kp] = src[1536 + e];
    }
  }
  __syncthreads();
  // A1 [128][72-stride]: cols 0..49 filt, col 50 = d, 51..63 = 0
  for (int e = tid; e < 4096; e += 256){
    int r = e >> 5, kp = e & 31;
    int k0 = kp * 2, k1 = k0 + 1;
    float d = DD[r];
    float v0 = 0.f, v1 = 0.f;
    if (k0 < 50){
      float t0 = b2f(TB[r*56 + k0]);
      float c0 = (float)k0 * (5.f/49.f), dd0 = d - c0;
      v0 = t0 * __expf(-10.f * dd0 * dd0);
    } else if (k0 == 50) v0 = d;
    if (k1 < 50){
      float t1 = b2f(TB[r*56 + k1]);
      float c1 = (float)k1 * (5.f/49.f), dd1 = d - c1;
      v1 = t1 * __expf(-10.f * dd1 * dd1);
    }
    ((u32*)A1)[r*36 + kp] = (u32)f2b(v0) | ((u32)f2b(v1) << 16);
  }
  __syncthreads();
  // u = A1 @ B1 + UB  (M=128 N=32 K=64)
  floatx4 au[2][2];
  #pragma unroll
  for (int mt = 0; mt < 2; ++mt)
    #pragma unroll
    for (int nt = 0; nt < 2; ++nt) au[mt][nt] = (floatx4){0.f,0.f,0.f,0.f};
  #pragma unroll
  for (int ks = 0; ks < 2; ++ks){
    int kk = ks * 32;
    short8 a0 = *(const short8*)(A1 + (wave*32 + l15)*72 + kk + quad*8);
    short8 a1 = *(const short8*)(A1 + (wave*32 + 16 + l15)*72 + kk + quad*8);
    #pragma unroll
    for (int nt = 0; nt < 2; ++nt){
      short8 b = *(const short8*)(B1 + (nt*16 + l15)*72 + kk + quad*8);
      au[0][nt] = __builtin_amdgcn_mfma_f32_16x16x32_bf16(a0, b, au[0][nt], 0, 0, 0);
      au[1][nt] = __builtin_amdgcn_mfma_f32_16x16x32_bf16(a1, b, au[1][nt], 0, 0, 0);
    }
  }
  #pragma unroll
  for (int mt = 0; mt < 2; ++mt)
    #pragma unroll
    for (int nt = 0; nt < 2; ++nt)
      #pragma unroll
      for (int reg = 0; reg < 4; ++reg){
        int r = wave*32 + mt*16 + quad*4 + reg;
        int c = nt*16 + l15;
        float uval = au[mt][nt][reg] + UB[r*32 + c];
        A2[r*40 + c] = f2b(siluf(uval));
      }
  __syncthreads();
  // eg = A2 @ B2 (M=128 N=32 K=32)
  floatx4 ae[2][2];
  #pragma unroll
  for (int mt = 0; mt < 2; ++mt)
    #pragma unroll
    for (int nt = 0; nt < 2; ++nt) ae[mt][nt] = (floatx4){0.f,0.f,0.f,0.f};
  {
    short8 a0 = *(const short8*)(A2 + (wave*32 + l15)*40 + quad*8);
    short8 a1 = *(const short8*)(A2 + (wave*32 + 16 + l15)*40 + quad*8);
    #pragma unroll
    for (int nt = 0; nt < 2; ++nt){
      short8 b = *(const short8*)(B2 + (nt*16 + l15)*40 + quad*8);
      ae[0][nt] = __builtin_amdgcn_mfma_f32_16x16x32_bf16(a0, b, ae[0][nt], 0, 0, 0);
      ae[1][nt] = __builtin_amdgcn_mfma_f32_16x16x32_bf16(a1, b, ae[1][nt], 0, 0, 0);
    }
  }
  __syncthreads();    // all A2 (silu-u) reads done before overwrite with eg
  #pragma unroll
  for (int mt = 0; mt < 2; ++mt)
    #pragma unroll
    for (int nt = 0; nt < 2; ++nt)
      #pragma unroll
      for (int reg = 0; reg < 4; ++reg){
        int r = wave*32 + mt*16 + quad*4 + reg;
        int c = nt*16 + l15;
        float ev = ae[mt][nt][reg] + Wf[OFF_BE2 + c];
        A2[r*40 + c] = f2b(ev);
      }
  __syncthreads();
  // edge copy-out (coalesced)
  {
    int r = tid >> 1, p = tid & 1;
    const uint4* srcp = (const uint4*)(A2 + r*40 + p*16);
    uint4* dstp = (uint4*)(edge + (size_t)(row0 + r)*32 + p*16);
    dstp[0] = srcp[0]; dstp[1] = srcp[1];
  }
  // logits = celu(A2 @ B3 + batt)  (N=16, 7 used)
  floatx4 al_[2];
  al_[0] = (floatx4){0.f,0.f,0.f,0.f};
  al_[1] = (floatx4){0.f,0.f,0.f,0.f};
  {
    short8 a0 = *(const short8*)(A2 + (wave*32 + l15)*40 + quad*8);
    short8 a1 = *(const short8*)(A2 + (wave*32 + 16 + l15)*40 + quad*8);
    short8 b = *(const short8*)(B3 + l15*40 + quad*8);
    al_[0] = __builtin_amdgcn_mfma_f32_16x16x32_bf16(a0, b, al_[0], 0, 0, 0);
    al_[1] = __builtin_amdgcn_mfma_f32_16x16x32_bf16(a1, b, al_[1], 0, 0, 0);
  }
  if (l15 < 7){
    float ba = Wf[OFF_BATT + l15];
    #pragma unroll
    for (int mt = 0; mt < 2; ++mt)
      #pragma unroll
      for (int reg = 0; reg < 4; ++reg){
        int r = wave*32 + mt*16 + quad*4 + reg;
        float vv = al_[mt][reg] + ba;
        float cl = vv > 0.f ? vv : 2.f * expm1f(0.5f * vv);
        logits[(size_t)(row0 + r)*7 + l15] = cl;
      }
  }
}

// -------- segment softmax + hsem accumulation (16-lane group per atom) ------
__global__ __launch_bounds__(256) void k_att(const int* __restrict__ offs,
    const float* __restrict__ logits, const u16* __restrict__ edge,
    float* __restrict__ atts, float* __restrict__ hsem){
  int a = blockIdx.x * 16 + (threadIdx.x >> 4);   // N = 625*16
  int lane = threadIdx.x & 15;
  int off = offs[a], end = offs[a+1];
  float m[7];
  #pragma unroll
  for (int hh = 0; hh < 7; ++hh) m[hh] = -1e30f;
  for (int s = off + lane; s < end; s += 16){
    #pragma unroll
    for (int hh = 0; hh < 7; ++hh) m[hh] = fmaxf(m[hh], logits[s*7+hh]);
  }
  #pragma unroll
  for (int hh = 0; hh < 7; ++hh){
    float v = m[hh];
    #pragma unroll
    for (int msk = 8; msk >= 1; msk >>= 1) v = fmaxf(v, __shfl_xor(v, msk));
    m[hh] = v;
  }
  float sm[7] = {0,0,0,0,0,0,0};
  for (int s = off + lane; s < end; s += 16){
    #pragma unroll
    for (int hh = 0; hh < 7; ++hh){
      float e = __expf(logits[s*7+hh] - m[hh]);
      sm[hh] += e;
      atts[s*7+hh] = e;
    }
  }
  #pragma unroll
  for (int hh = 0; hh < 7; ++hh){
    float v = sm[hh];
    #pragma unroll
    for (int msk = 8; msk >= 1; msk >>= 1) v += __shfl_xor(v, msk);
    sm[hh] = 1.f / v;
  }
  for (int s = off + lane; s < end; s += 16){
    #pragma unroll
    for (int hh = 0; hh < 7; ++hh) atts[s*7+hh] *= sm[hh];
  }
  __syncthreads();
  float acc[14] = {0,0,0,0,0,0,0,0,0,0,0,0,0,0};
  for (int s = off; s < end; ++s){
    u32 ev = *(const u32*)(edge + (size_t)s * 32 + lane * 2);
    float e0 = b2f((u16)(ev & 0xFFFFu));
    float e1 = b2f((u16)(ev >> 16));
    const float* ap = atts + (size_t)s * 7;
    #pragma unroll
    for (int hh = 0; hh < 7; ++hh){
      float at = ap[hh];
      acc[hh]     += e0 * at;
      acc[7 + hh] += e1 * at;
    }
  }
  float* hp = hsem + (size_t)a * 224 + lane * 14;
  #pragma unroll
  for (int jj = 0; jj < 14; ++jj) hp[jj] = acc[jj];
}

// -------- MFMA GEMM, M=64 tile, half-width (112 cols), 38.7KB LDS -----------
// LDS: As [64][232]u16 = 29696 (xth [64][120] overlays after MFMA)
//      Bs [112][40]u16 = 8960 @29696 (eL [64][36]=4608 + aL 1792 overlay, dead after pack)
#define G_BS   29696
#define G_EL   29696
#define G_AL   (29696 + 4608)
#define G_TOT  38656

__global__ __launch_bounds__(256, 4) void k_gemm3(const u16* __restrict__ edge,
    const float* __restrict__ atts, const u16* __restrict__ BT,
    u16* __restrict__ xhalf, int half){
  __shared__ __attribute__((aligned(16))) char smem[G_TOT];
  u16*   As  = (u16*)smem;                 // stride 232 u16 (116 u32)
  u16*   xth = (u16*)smem;                 // stride 120 u16, overlays As after MFMA
  u16*   Bs  = (u16*)(smem + G_BS);        // stride 40 u16
  u16*   eL  = (u16*)(smem + G_EL);        // stride 36 u16 (overlay, dead after pack)
  float* aL  = (float*)(smem + G_AL);      // stride 7 floats (overlay)
  int tid = threadIdx.x;
  int wave = tid >> 6, lane = tid & 63, l15 = lane & 15, quad = lane >> 4;
  int row0 = blockIdx.x * 64;
  int nbase = half * 112;

  // stage edge rows (padded stride 36) + atts
  for (int e = tid; e < 512; e += 256){
    int r = e >> 3, q = e & 7;
    *(uint2*)(eL + r*36 + q*4) = *(const uint2*)(edge + (size_t)(row0 + r)*32 + q*4);
  }
  for (int e = tid; e < 448; e += 256) aL[e] = atts[(size_t)row0*7 + e];
  floatx4 acc[7];
  #pragma unroll
  for (int nt = 0; nt < 7; ++nt) acc[nt] = (floatx4){0.f, 0.f, 0.f, 0.f};
  __syncthreads();

  // pack full-K A-tile once: thread t -> row t>>2, quarter (t&3)*56 cols (8 f's)
  {
    int pr = tid >> 2, q = tid & 3;
    u32* asw = (u32*)As + pr*116 + q*28;
    const u16* er = eL + pr*36 + q*8;
    const float* ar = aL + pr*7;
    float av[7];
    #pragma unroll
    for (int hh = 0; hh < 7; ++hh) av[hh] = ar[hh];
    #pragma unroll
    for (int fo2 = 0; fo2 < 4; ++fo2){
      float e0 = b2f(er[2*fo2]);
      float e1 = b2f(er[2*fo2+1]);
      u16 w[14];
      #pragma unroll
      for (int hh = 0; hh < 7; ++hh){
        w[hh]   = f2b(e0 * av[hh]);
        w[7+hh] = f2b(e1 * av[hh]);
      }
      #pragma unroll
      for (int k = 0; k < 7; ++k)
        asw[fo2*7 + k] = (u32)w[2*k] | ((u32)w[2*k+1] << 16);
    }
  }
  __syncthreads();          // As ready; eL/aL dead -> Bs usable

  for (int kt = 0; kt < 7; ++kt){
    // stage Bs (single-buffered, 112 rows x 32 K)
    for (int e = tid; e < 448; e += 256){
      int r = e >> 2, q = e & 3;
      *(uint4*)(Bs + r*40 + q*8) = *(const uint4*)(BT + (size_t)(nbase + r)*224 + kt*32 + q*8);
    }
    __syncthreads();
    int kk = kt * 32;
    short8 a0 = *(const short8*)(As + (wave*16 + l15)*232 + kk + quad*8);
    #pragma unroll
    for (int nt = 0; nt < 7; ++nt){
      short8 b = *(const short8*)(Bs + (nt*16 + l15)*40 + quad*8);
      acc[nt] = __builtin_amdgcn_mfma_f32_16x16x32_bf16(a0, b, acc[nt], 0, 0, 0);
    }
    __syncthreads();        // MFMA reads done before next stage overwrites Bs
  }

  // tanh epilogue -> xth (stride 120), wave-local rows (overlays As; safe after loop barrier)
  #pragma unroll
  for (int nt = 0; nt < 7; ++nt)
    #pragma unroll
    for (int reg = 0; reg < 4; ++reg){
      int r = wave*16 + quad*4 + reg;
      int c = nt*16 + l15;
      float vv = acc[nt][reg];
      vv = fminf(fmaxf(vv, -15.f), 15.f);
      float e2 = __expf(2.f * vv);
      xth[r*120 + c] = f2b((e2 - 1.f) / (e2 + 1.f));
    }
  __syncthreads();
  // coalesced copy-out: 64 rows x 14 uint4
  for (int e = tid; e < 896; e += 256){
    int r = e / 14, w = e - r * 14;
    *(uint4*)(xhalf + (size_t)(row0 + r)*112 + w*8) = *(const uint4*)(xth + r*120 + w*8);
  }
}

// -------- atom-centric comb reduction: xhalf -> nsq half + pv partial -------
__global__ __launch_bounds__(256) void k_comb(const int* __restrict__ offs,
    const u16* __restrict__ xhalf, const float* __restrict__ dirs,
    const float* __restrict__ Wf, int half,
    float* __restrict__ nsq, float* __restrict__ pvh){
  int a = blockIdx.x * 16 + (threadIdx.x >> 4);
  int lane = threadIdx.x & 15;
  int off = offs[a], end = offs[a+1];
  float c0[7] = {0,0,0,0,0,0,0}, c1[7] = {0,0,0,0,0,0,0}, c2[7] = {0,0,0,0,0,0,0};
  for (int s = off; s < end; ++s){
    float d0 = dirs[s*3+0], d1 = dirs[s*3+1], d2 = dirs[s*3+2];
    const u16* xr = xhalf + (size_t)s * 112 + lane;
    #pragma unroll
    for (int k = 0; k < 7; ++k){
      float xm = b2f(xr[k*16]);
      c0[k] += d0 * xm; c1[k] += d1 * xm; c2[k] += d2 * xm;
    }
  }
  float inv = 1.f / fmaxf((float)(end - off), 1.f);
  float pv0 = 0.f, pv1 = 0.f, pv2 = 0.f;
  #pragma unroll
  for (int k = 0; k < 7; ++k){
    float m0 = c0[k]*inv, m1 = c1[k]*inv, m2 = c2[k]*inv;
    int c = half*112 + k*16 + lane;
    nsq[(size_t)a*224 + c] = m0*m0 + m1*m1 + m2*m2;
    float wv = Wf[OFF_WVMIX + c];
    pv0 += wv*m0; pv1 += wv*m1; pv2 += wv*m2;
  }
  #pragma unroll
  for (int m = 8; m >= 1; m >>= 1){
    pv0 += __shfl_xor(pv0, m); pv1 += __shfl_xor(pv1, m); pv2 += __shfl_xor(pv2, m);
  }
  if (lane == 0){
    float* pp = pvh + (size_t)half*30000 + (size_t)a*3;
    pp[0] = pv0; pp[1] = pv1; pp[2] = pv2;
  }
}

// ------- final: 16 atoms/block, all 256 threads per phase, 2 atoms/thread ---
__global__ __launch_bounds__(256) void k_final4(const float* __restrict__ h,
    const float* __restrict__ x, const float* __restrict__ v,
    const float* __restrict__ Wf, const float* __restrict__ hsem,
    const float* __restrict__ nsq, const float* __restrict__ pvh,
    float* __restrict__ out){
  __shared__ float s_nsq[16][225];   // padded: stride 225 mod 32 = 1
  __shared__ float s_in[16][289];    // [0:32)=h, [32:256)=hsem, [256:288)=sp
  __shared__ float s_u1[16][33];
  __shared__ float s_un[16][33];
  __shared__ float s_sc[16];
  int tid = threadIdx.x;
  int a0 = blockIdx.x * 16;
  // staged loads (coalesced float4)
  for (int e = tid; e < 896; e += 256){        // nsq: 16 atoms x 56 float4
    int a = e / 56, q = e - a * 56;
    float4 t = *(const float4*)(nsq + (size_t)(a0 + a) * 224 + q * 4);
    s_nsq[a][q*4+0] = t.x; s_nsq[a][q*4+1] = t.y;
    s_nsq[a][q*4+2] = t.z; s_nsq[a][q*4+3] = t.w;
  }
  for (int e = tid; e < 896; e += 256){        // hsem -> s_in[32:256)
    int a = e / 56, q = e - a * 56;
    float4 t = *(const float4*)(hsem + (size_t)(a0 + a) * 224 + q * 4);
    s_in[a][32 + q*4+0] = t.x; s_in[a][32 + q*4+1] = t.y;
    s_in[a][32 + q*4+2] = t.z; s_in[a][32 + q*4+3] = t.w;
  }
  for (int e = tid; e < 128; e += 256){        // h -> s_in[0:32)
    int a = e >> 3, q = e & 7;
    float4 t = *(const float4*)(h + (size_t)(a0 + a) * 32 + q * 4);
    s_in[a][q*4+0] = t.x; s_in[a][q*4+1] = t.y;
    s_in[a][q*4+2] = t.z; s_in[a][q*4+3] = t.w;
  }
  __syncthreads();
  int o = tid & 31, g5 = tid >> 5;             // 8 groups of 32; atoms {g5, g5+8}
  int aA = g5, aB = g5 + 8;
  // p1: u1 = silu(BP1 + nsq @ WP1), K=224
  {
    float uA = Wf[OFF_BP1 + o], uB = uA;
    const float* w = Wf + OFF_WP1 + o;
    #pragma unroll 8
    for (int kk = 0; kk < 224; ++kk){
      float wv = w[kk*32];
      uA += s_nsq[aA][kk] * wv;
      uB += s_nsq[aB][kk] * wv;
    }
    s_u1[aA][o] = siluf(uA);
    s_u1[aB][o] = siluf(uB);
  }
  // g = silu(BV1 + h @ WV1); z = sum(g * WV2); sc = 2*sigmoid(z)
  {
    float gA = Wf[OFF_BV1 + o], gB = gA;
    const float* w = Wf + OFF_WV1 + o;
    #pragma unroll
    for (int kk = 0; kk < 32; ++kk){
      float wv = w[kk*32];
      gA += s_in[aA][kk] * wv;
      gB += s_in[aB][kk] * wv;
    }
    float wv2 = Wf[OFF_WV2 + o];
    float zA = siluf(gA) * wv2, zB = siluf(gB) * wv2;
    #pragma unroll
    for (int m = 16; m >= 1; m >>= 1){
      zA += __shfl_xor(zA, m); zB += __shfl_xor(zB, m);
    }
    if (o == 0){
      s_sc[aA] = 2.f / (1.f + __expf(-zA));
      s_sc[aB] = 2.f / (1.f + __expf(-zB));
    }
  }
  __syncthreads();
  // p2: sp = silu(BP2 + u1 @ WP2) -> s_in[256:288)
  {
    float uA = Wf[OFF_BP2 + o], uB = uA;
    const float* w = Wf + OFF_WP2 + o;
    #pragma unroll
    for (int kk = 0; kk < 32; ++kk){
      float wv = w[kk*32];
      uA += s_u1[aA][kk] * wv;
      uB += s_u1[aB][kk] * wv;
    }
    s_in[aA][256 + o] = siluf(uA);
    s_in[aB][256 + o] = siluf(uB);
  }
  __syncthreads();
  // n1: un = silu(BN1 + [h|hsem|sp] @ WN1), K=288
  {
    float uA = Wf[OFF_BN1 + o], uB = uA;
    const float* w = Wf + OFF_WN1 + o;
    #pragma unroll 8
    for (int kk = 0; kk < 288; ++kk){
      float wv = w[kk*32];
      uA += s_in[aA][kk] * wv;
      uB += s_in[aB][kk] * wv;
    }
    s_un[aA][o] = siluf(uA);
    s_un[aB][o] = siluf(uB);
  }
  __syncthreads();
  // n2: out_h = h + silu(BN2 + un @ WN2)
  {
    float uA = Wf[OFF_BN2 + o], uB = uA;
    const float* w = Wf + OFF_WN2 + o;
    #pragma unroll
    for (int kk = 0; kk < 32; ++kk){
      float wv = w[kk*32];
      uA += s_un[aA][kk] * wv;
      uB += s_un[aB][kk] * wv;
    }
    out[(size_t)(a0 + aA)*32 + o] = s_in[aA][o] + siluf(uA);
    out[(size_t)(a0 + aB)*32 + o] = s_in[aB][o] + siluf(uB);
  }
  // v/x updates: 48 threads, one (atom, axis) each
  if (tid < 48){
    int a = tid / 3, c = tid - a * 3;
    int ga = a0 + a;
    float pv = pvh[(size_t)ga*3 + c] + pvh[30000 + (size_t)ga*3 + c];
    float vup = s_sc[a] * v[ga*3 + c] + pv;
    float xup = x[ga*3 + c] + vup;
    out[N_ATOMS*32 + (size_t)ga*3 + c] = xup;
    out[N_ATOMS*32 + N_ATOMS*3 + (size_t)ga*3 + c] = vup;
  }
}

// ---------------- workspace layout ----------------
static constexpr size_t al256(size_t x){ return (x + 255) & ~(size_t)255; }
static constexpr size_t WS_FLAGS   = 0;
static constexpr size_t WS_COUNTS  = al256(WS_FLAGS + 8);
static constexpr size_t WS_OFFSETS = al256(WS_COUNTS + (size_t)N_ATOMS * 4);
static constexpr size_t WS_CURSOR  = al256(WS_OFFSETS + (size_t)(N_ATOMS + 1) * 4);
static constexpr size_t WS_PERM    = al256(WS_CURSOR + (size_t)N_ATOMS * 4);   // isrt
static constexpr size_t WS_PLI     = al256(WS_PERM + (size_t)P_PAIRS * 4);
static constexpr size_t WS_HF      = al256(WS_PLI + (size_t)2 * P_PAIRS * 4);
static constexpr size_t WS_XF      = al256(WS_HF + (size_t)N_ATOMS * 32 * 4);
static constexpr size_t WS_VF      = al256(WS_XF + (size_t)N_ATOMS * 3 * 4);
static constexpr size_t WS_WF      = al256(WS_VF + (size_t)N_ATOMS * 3 * 4);
static constexpr size_t WS_WT      = al256(WS_WF + (size_t)WF_TOTAL * 4);
static constexpr size_t WS_EDGE    = al256(WS_WT + (size_t)224 * 224 * 2);
static constexpr size_t WS_ATTS    = al256(WS_EDGE + (size_t)P_PAIRS * 32 * 2);
static constexpr size_t WS_DIRS    = al256(WS_ATTS + (size_t)P_PAIRS * 7 * 4);
static constexpr size_t WS_LOGITS  = al256(WS_DIRS + (size_t)P_PAIRS * 3 * 4);
static constexpr size_t WS_PREI    = al256(WS_LOGITS + (size_t)P_PAIRS * 7 * 4);
static constexpr size_t WS_PREJ    = al256(WS_PREI + (size_t)N_ATOMS * 88 * 2);
static constexpr size_t WS_HSEM    = WS_LOGITS + 4480000;
static constexpr size_t WS_XH      = WS_HSEM + (size_t)N_ATOMS * 224 * 4;
static constexpr size_t WS_NSQ     = WS_XH + (size_t)P_PAIRS * 112 * 2;
static constexpr size_t WS_PVH     = WS_NSQ + (size_t)N_ATOMS * 224 * 4;
static constexpr size_t WS_JSRT    = al256(WS_PVH + (size_t)2 * 30000 * 4);
static constexpr size_t WS_BPK     = al256(WS_JSRT + (size_t)P_PAIRS * 4);
static constexpr size_t WS_END     = WS_BPK + 3584 * 2;
static_assert(WS_PREJ + (size_t)N_ATOMS * 88 * 2 <= WS_XH, "pre tables before xhalf");
static_assert(WS_END <= WS_LOGITS + (size_t)P_PAIRS * 224 * 2, "within round-1-proven footprint");
static_assert(WS_HSEM % 256 == 0 && WS_XH % 256 == 0 && WS_NSQ % 256 == 0 && WS_PVH % 256 == 0, "alignment");

extern "C" void kernel_launch(void* const* d_in, const int* in_sizes, int n_in,
                              void* d_out, int out_size, void* d_ws, size_t ws_size,
                              hipStream_t stream){
  (void)in_sizes; (void)n_in;
  if (out_size != 380000 || ws_size < WS_END){
    k_code<<<1, 64, 0, stream>>>((float*)d_out, 14000.f);
    return;
  }
  char* ws = (char*)d_ws;
  int*   counts = (int*)(ws + WS_COUNTS);
  int*   offs   = (int*)(ws + WS_OFFSETS);
  int*   cursor = (int*)(ws + WS_CURSOR);
  int*   isrt   = (int*)(ws + WS_PERM);
  int*   pli    = (int*)(ws + WS_PLI);
  float* hf     = (float*)(ws + WS_HF);
  float* xf     = (float*)(ws + WS_XF);
  float* vf     = (float*)(ws + WS_VF);
  float* Wf     = (float*)(ws + WS_WF);
  u16*   wT     = (u16*)(ws + WS_WT);
  u16*   edge   = (u16*)(ws + WS_EDGE);
  float* atts   = (float*)(ws + WS_ATTS);
  float* dirs   = (float*)(ws + WS_DIRS);
  float* logits = (float*)(ws + WS_LOGITS);
  u16*   prei   = (u16*)(ws + WS_PREI);
  u16*   prej   = (u16*)(ws + WS_PREJ);
  float* hsem   = (float*)(ws + WS_HSEM);
  u16*   xhalf  = (u16*)(ws + WS_XH);
  float* nsq    = (float*)(ws + WS_NSQ);
  float* pvh    = (float*)(ws + WS_PVH);
  int*   jsrt   = (int*)(ws + WS_JSRT);
  u16*   bpk    = (u16*)(ws + WS_BPK);

  hipMemsetAsync(counts, 0, (size_t)N_ATOMS * 4, stream);
  k_prep<<<NBP_HIST, 256, 0, stream>>>(d_in[0], d_in[1], d_in[2], d_in[3],
      d_in[4],  d_in[5],  d_in[6],  d_in[7],  d_in[8],  d_in[9],  d_in[10], d_in[11],
      d_in[12], d_in[13], d_in[14], d_in[15], d_in[16], d_in[17], d_in[18], d_in[19],
      d_in[20], d_in[21], d_in[22], d_in[24], d_in[23],
      hf, xf, vf, pli, Wf, wT, bpk, counts);
  k_atomscan<<<626, 256, 0, stream>>>(hf, Wf, prei, prej, counts, offs, cursor);
  k_scatter<<<P_PAIRS / 256, 256, 0, stream>>>(pli, cursor, isrt, jsrt);
  k_pairm<<<P_PAIRS / 128, 256, 0, stream>>>(xf, Wf, prei, prej, isrt, jsrt, bpk, edge, logits, dirs);
  k_att<<<N_ATOMS / 16, 256, 0, stream>>>(offs, logits, edge, atts, hsem);
  k_gemm3<<<P_PAIRS / 64, 256, 0, stream>>>(edge, atts, wT, xhalf, 0);
  k_comb<<<N_ATOMS / 16, 256, 0, stream>>>(offs, xhalf, dirs, Wf, 0, nsq, pvh);
  k_gemm3<<<P_PAIRS / 64, 256, 0, stream>>>(edge, atts, wT, xhalf, 1);
  k_comb<<<N_ATOMS / 16, 256, 0, stream>>>(offs, xhalf, dirs, Wf, 1, nsq, pvh);
  k_final4<<<625, 256, 0, stream>>>(hf, xf, vf, Wf, hsem, nsq, pvh, (float*)d_out);
}

// Round 11
// 312.205 us; speedup vs baseline: 1.3964x; 1.0990x over previous
//
#include <hip/hip_runtime.h>

typedef unsigned short u16;
typedef unsigned int u32;
typedef __attribute__((ext_vector_type(8))) short short8;
typedef __attribute__((ext_vector_type(4))) float floatx4;

#define P_PAIRS 160000
#define N_ATOMS 10000

#define OFF_WMLP  0      // stored TRANSPOSED: [50][64], (o,k) at o*64+k
#define OFF_BMLP  3200
#define OFF_WE1   3250
#define OFF_BE1   6930
#define OFF_WE2   6962
#define OFF_BE2   7986
#define OFF_WATT  8018
#define OFF_BATT  8242
#define OFF_WN1   8249
#define OFF_BN1   17465
#define OFF_WN2   17497
#define OFF_BN2   18521
#define OFF_WP1   18553
#define OFF_BP1   25721
#define OFF_WP2   25753
#define OFF_BP2   26777
#define OFF_WV1   26809
#define OFF_BV1   27833
#define OFF_WV2   27865
#define OFF_WVMIX 27897
#define WF_TOTAL  28121

__device__ __forceinline__ float b2f(u16 u){ return __uint_as_float(((u32)u) << 16); }
__device__ __forceinline__ u16 f2b(float f){
  u32 u = __float_as_uint(f);
  u32 r = (u + 0x7FFFu + ((u >> 16) & 1u)) >> 16;
  return (u16)r;
}
__device__ __forceinline__ void unpack2(u32 p, float& lo, float& hi){
  lo = __uint_as_float(p << 16);
  hi = __uint_as_float(p & 0xFFFF0000u);
}
__device__ __forceinline__ float siluf(float v){ return v / (1.f + __expf(-v)); }
__device__ __forceinline__ float ldw(const void* p, int o, int bf){
  return bf ? b2f(((const u16*)p)[o]) : ((const float*)p)[o];
}

__global__ void k_code(float* out, float code){
  if (threadIdx.x == 0 && blockIdx.x == 0) out[0] = code;
}

// per-block dtype detection (wave 0 ballot)
__device__ __forceinline__ void detect_flags(const u32* hw, const u32* plw, int* s_fl){
  int tid = threadIdx.x;
  if (tid < 64){
    u32 e = (hw[tid] >> 7) & 0xFFu;
    unsigned long long m1 = __ballot(e >= 100u && e <= 140u);
    unsigned long long m2 = __ballot(plw[2*tid+1] == 0u);
    if (tid == 0){
      s_fl[0] = (__popcll(m1) >= 48) ? 1 : 0;
      s_fl[1] = (__popcll(m2) >= 60) ? 1 : 0;
    }
  }
  __syncthreads();
}

// ------------- fused preprocessing: norm + convert + transpose + bpk + hist -
#define NBP_NORM 2735
#define NBP_CONV (NBP_NORM + 110)
#define NBP_TRAN (NBP_CONV + 196)
#define NBP_PB   (NBP_TRAN + 14)
#define NBP_HIST (NBP_PB + 625)

__global__ void k_prep(const void* __restrict__ h_raw, const void* __restrict__ x_raw,
    const void* __restrict__ v_raw, const void* __restrict__ pl_raw,
    const void* w_mlp, const void* b_mlp, const void* w_e1, const void* b_e1,
    const void* w_e2, const void* b_e2, const void* w_att, const void* b_att,
    const void* w_n1, const void* b_n1, const void* w_n2, const void* b_n2,
    const void* w_p1, const void* b_p1, const void* w_p2, const void* b_p2,
    const void* w_v1, const void* b_v1, const void* w_v2, const void* w_vmix,
    const void* wx,
    float* __restrict__ hf, float* __restrict__ xf, float* __restrict__ vf,
    int* __restrict__ pli, float* __restrict__ Wf, u16* __restrict__ wT,
    u16* __restrict__ bpk, int* __restrict__ counts){
  __shared__ int s_fl[2];
  detect_flags((const u32*)h_raw, (const u32*)pl_raw, s_fl);
  int bf = s_fl[0], i64 = s_fl[1];
  int bid = blockIdx.x, tid = threadIdx.x;
  if (bid < NBP_NORM){
    int t = bid * 256 + tid;
    if (t < 320000){
      hf[t] = ldw(h_raw, t, bf);
    } else if (t < 350000){
      int i = t - 320000; xf[i] = ldw(x_raw, i, bf);
    } else if (t < 380000){
      int i = t - 350000; vf[i] = ldw(v_raw, i, bf);
    } else if (t < 700000){
      int k = t - 380000;
      const int* p32 = (const int*)pl_raw;
      pli[k] = i64 ? p32[2*(size_t)k] : p32[k];
    }
  } else if (bid < NBP_CONV){
    int t = (bid - NBP_NORM) * 256 + tid;
    if (t >= WF_TOTAL) return;
    if (t < 3200){
      int k = t / 50, o = t - k * 50;
      Wf[OFF_WMLP + o * 64 + k] = ldw(w_mlp, t, bf);
      return;
    }
    const void* src; int o;
    if      (t < 3250)  { src = b_mlp;  o = t - 3200; }
    else if (t < 6930)  { src = w_e1;   o = t - 3250; }
    else if (t < 6962)  { src = b_e1;   o = t - 6930; }
    else if (t < 7986)  { src = w_e2;   o = t - 6962; }
    else if (t < 8018)  { src = b_e2;   o = t - 7986; }
    else if (t < 8242)  { src = w_att;  o = t - 8018; }
    else if (t < 8249)  { src = b_att;  o = t - 8242; }
    else if (t < 17465) { src = w_n1;   o = t - 8249; }
    else if (t < 17497) { src = b_n1;   o = t - 17465; }
    else if (t < 18521) { src = w_n2;   o = t - 17497; }
    else if (t < 18553) { src = b_n2;   o = t - 18521; }
    else if (t < 25721) { src = w_p1;   o = t - 18553; }
    else if (t < 25753) { src = b_p1;   o = t - 25721; }
    else if (t < 26777) { src = w_p2;   o = t - 25753; }
    else if (t < 26809) { src = b_p2;   o = t - 26777; }
    else if (t < 27833) { src = w_v1;   o = t - 26809; }
    else if (t < 27865) { src = b_v1;   o = t - 27833; }
    else if (t < 27897) { src = w_v2;   o = t - 27865; }
    else                { src = w_vmix; o = t - 27897; }
    Wf[t] = ldw(src, o, bf);
  } else if (bid < NBP_TRAN){
    int t = (bid - NBP_CONV) * 256 + tid;
    if (t >= 224 * 224) return;
    int n = t / 224, k = t - n * 224;
    wT[t] = f2b(ldw(wx, k * 224 + n, bf));
  } else if (bid < NBP_PB){
    // bpk: B1T [32][64] | B2T [32][32] | B3T [16][32]  (bf16, from RAW weights)
    int t = (bid - NBP_TRAN) * 256 + tid;
    if (t >= 3584) return;
    float v = 0.f;
    if (t < 2048){
      int n = t >> 6, k = t & 63;
      if (k < 50)       v = ldw(w_e1, (64 + k) * 32 + n, bf);
      else if (k == 50) v = ldw(w_e1, 114 * 32 + n, bf);
    } else if (t < 3072){
      int e = t - 2048; int n = e >> 5, k = e & 31;
      v = ldw(w_e2, k * 32 + n, bf);
    } else {
      int e = t - 3072; int n = e >> 5, k = e & 31;
      if (n < 7) v = ldw(w_att, k * 7 + n, bf);
    }
    bpk[t] = f2b(v);
  } else {
    int p = (bid - NBP_PB) * 256 + tid;     // hist from raw pairlist
    const int* p32 = (const int*)pl_raw;
    int i = i64 ? p32[2*(size_t)p] : p32[p];
    atomicAdd(&counts[i], 1);
  }
}

// ---------- fused: per-atom projections (625 fat blocks) + scan (1 block) ---
__global__ void k_atomscan(const float* __restrict__ hf, const float* __restrict__ Wf,
    u16* __restrict__ prei, u16* __restrict__ prej,
    const int* __restrict__ counts, int* __restrict__ offs, int* __restrict__ cursor){
  __shared__ float hs[16][33];
  __shared__ int part[256];
  int tid = threadIdx.x;
  if (blockIdx.x < 625){
    int a0 = blockIdx.x * 16;
    for (int e = tid; e < 512; e += 256){
      int a = e >> 5, k = e & 31;
      hs[a][k] = hf[(size_t)(a0 + a) * 32 + k];
    }
    __syncthreads();
    for (int e = tid; e < 800; e += 256){
      int a = e / 50, r = e - a * 50;
      const float* wm = Wf + OFF_WMLP + r * 64;
      float acc = Wf[OFF_BMLP + r];
      #pragma unroll
      for (int k = 0; k < 32; ++k) acc += hs[a][k] * wm[k];
      prei[(size_t)(a0 + a) * 88 + 32 + r] = f2b(acc);
    }
    for (int e = tid; e < 800; e += 256){
      int a = e / 50, r = e - a * 50;
      const float* wm = Wf + OFF_WMLP + r * 64 + 32;
      float acc = 0.f;
      #pragma unroll
      for (int k = 0; k < 32; ++k) acc += hs[a][k] * wm[k];
      prej[(size_t)(a0 + a) * 88 + 32 + r] = f2b(acc);
    }
    for (int e = tid; e < 512; e += 256){
      int a = e >> 5, o = e & 31;
      float acc = Wf[OFF_BE1 + o];
      #pragma unroll
      for (int k = 0; k < 32; ++k) acc += hs[a][k] * Wf[OFF_WE1 + k * 32 + o];
      prei[(size_t)(a0 + a) * 88 + o] = f2b(acc);
    }
    for (int e = tid; e < 512; e += 256){
      int a = e >> 5, o = e & 31;
      float acc = 0.f;
      #pragma unroll
      for (int k = 0; k < 32; ++k) acc += hs[a][k] * Wf[OFF_WE1 + (32 + k) * 32 + o];
      prej[(size_t)(a0 + a) * 88 + o] = f2b(acc);
    }
  } else {
    int sum = 0;
    for (int k = 0; k < 40; ++k){
      int idx = tid * 40 + k;
      if (idx < N_ATOMS) sum += counts[idx];
    }
    part[tid] = sum;
    __syncthreads();
    if (tid == 0){
      int run = 0;
      for (int q = 0; q < 256; ++q){ int tmp = part[q]; part[q] = run; run += tmp; }
    }
    __syncthreads();
    int run = part[tid];
    for (int k = 0; k < 40; ++k){
      int idx = tid * 40 + k;
      if (idx < N_ATOMS){ offs[idx] = run; cursor[idx] = run; run += counts[idx]; }
    }
    if (tid == 0) offs[N_ATOMS] = P_PAIRS;
  }
}

__global__ void k_scatter(const int* __restrict__ pl, int* __restrict__ cursor,
                          int* __restrict__ isrt, int* __restrict__ jsrt){
  int p = blockIdx.x * 256 + threadIdx.x;
  int i = pl[p];
  int pos = atomicAdd(&cursor[i], 1);
  isrt[pos] = i;
  jsrt[pos] = pl[P_PAIRS + p];
}

// ------- per-pair edge model via MFMA: 128 pairs/block, 4 waves -------------
#define PM_UB   0
#define PM_TB   16384
#define PM_DD   30720
#define PM_A1   31232
#define PM_B1   49664
#define PM_A2   54272
#define PM_B2   64512
#define PM_B3   67072
#define PM_TOT  68352

__global__ __launch_bounds__(256) void k_pairm(const float* __restrict__ x,
    const float* __restrict__ Wf, const u16* __restrict__ prei, const u16* __restrict__ prej,
    const int* __restrict__ isrt, const int* __restrict__ jsrt, const u16* __restrict__ bpk,
    u16* __restrict__ edge, float* __restrict__ logits, float* __restrict__ dirs){
  __shared__ __attribute__((aligned(16))) char smem[PM_TOT];
  float* UB = (float*)(smem + PM_UB);
  u16*   TB = (u16*)(smem + PM_TB);
  float* DD = (float*)(smem + PM_DD);
  u16*   A1 = (u16*)(smem + PM_A1);
  u16*   B1 = (u16*)(smem + PM_B1);
  u16*   A2 = (u16*)(smem + PM_A2);
  u16*   B2 = (u16*)(smem + PM_B2);
  u16*   B3 = (u16*)(smem + PM_B3);
  int tid = threadIdx.x;
  int wave = tid >> 6, lane = tid & 63, l15 = lane & 15, quad = lane >> 4;
  int row0 = blockIdx.x * 128;

  if (tid < 128){
    int s = row0 + tid;
    int i = isrt[s], j = jsrt[s];
    float r0 = x[j*3+0] - x[i*3+0];
    float r1 = x[j*3+1] - x[i*3+1];
    float r2 = x[j*3+2] - x[i*3+2];
    float d = sqrtf(r0*r0 + r1*r1 + r2*r2);
    float rinv = 1.f / (d + 1e-5f);
    dirs[s*3+0] = r0*rinv; dirs[s*3+1] = r1*rinv; dirs[s*3+2] = r2*rinv;
    DD[tid] = d;
    const uint4* pi4 = (const uint4*)(prei + (size_t)i * 88);
    const uint4* pj4 = (const uint4*)(prej + (size_t)j * 88);
    float* ub = UB + tid * 32;
    #pragma unroll
    for (int q = 0; q < 4; ++q){
      uint4 a4 = pi4[q], b4 = pj4[q];
      u32 pa[4] = {a4.x, a4.y, a4.z, a4.w};
      u32 pb[4] = {b4.x, b4.y, b4.z, b4.w};
      #pragma unroll
      for (int w2 = 0; w2 < 4; ++w2){
        float al, ah, bl, bh;
        unpack2(pa[w2], al, ah); unpack2(pb[w2], bl, bh);
        ub[q*8 + w2*2]     = al + bl;
        ub[q*8 + w2*2 + 1] = ah + bh;
      }
    }
    u32* tb = (u32*)TB + tid * 28;
    #pragma unroll
    for (int q = 0; q < 7; ++q){
      uint4 a4 = pi4[4+q], b4 = pj4[4+q];
      u32 pa[4] = {a4.x, a4.y, a4.z, a4.w};
      u32 pb[4] = {b4.x, b4.y, b4.z, b4.w};
      #pragma unroll
      for (int w2 = 0; w2 < 4; ++w2){
        float al, ah, bl, bh;
        unpack2(pa[w2], al, ah); unpack2(pb[w2], bl, bh);
        tb[q*4 + w2] = (u32)f2b(al + bl) | ((u32)f2b(ah + bh) << 16);
      }
    }
  } else {
    int t2 = tid - 128;
    const u32* src = (const u32*)bpk;
    for (int e = t2; e < 1024; e += 128){         // B1T [32][64] -> stride 36 u32
      int n = e >> 5, kp = e & 31;
      ((u32*)B1)[n*36 + kp] = src[e];
    }
    for (int e = t2; e < 512; e += 128){          // B2T [32][32] -> stride 20 u32
      int n = e >> 4, kp = e & 15;
      ((u32*)B2)[n*20 + kp] = src[1024 + e];
    }
    for (int e = t2; e < 256; e += 128){          // B3T [16][32] -> stride 20 u32
      int n = e >> 4, kp = e & 15;
      ((u32*)B3)[n*20 + kp] = src[1536 + e];
    }
  }
  __syncthreads();
  // A1 [128][72-stride]: cols 0..49 filt, col 50 = d, 51..63 = 0
  for (int e = tid; e < 4096; e += 256){
    int r = e >> 5, kp = e & 31;
    int k0 = kp * 2, k1 = k0 + 1;
    float d = DD[r];
    float v0 = 0.f, v1 = 0.f;
    if (k0 < 50){
      float t0 = b2f(TB[r*56 + k0]);
      float c0 = (float)k0 * (5.f/49.f), dd0 = d - c0;
      v0 = t0 * __expf(-10.f * dd0 * dd0);
    } else if (k0 == 50) v0 = d;
    if (k1 < 50){
      float t1 = b2f(TB[r*56 + k1]);
      float c1 = (float)k1 * (5.f/49.f), dd1 = d - c1;
      v1 = t1 * __expf(-10.f * dd1 * dd1);
    }
    ((u32*)A1)[r*36 + kp] = (u32)f2b(v0) | ((u32)f2b(v1) << 16);
  }
  __syncthreads();
  // u = A1 @ B1 + UB  (M=128 N=32 K=64)
  floatx4 au[2][2];
  #pragma unroll
  for (int mt = 0; mt < 2; ++mt)
    #pragma unroll
    for (int nt = 0; nt < 2; ++nt) au[mt][nt] = (floatx4){0.f,0.f,0.f,0.f};
  #pragma unroll
  for (int ks = 0; ks < 2; ++ks){
    int kk = ks * 32;
    short8 a0 = *(const short8*)(A1 + (wave*32 + l15)*72 + kk + quad*8);
    short8 a1 = *(const short8*)(A1 + (wave*32 + 16 + l15)*72 + kk + quad*8);
    #pragma unroll
    for (int nt = 0; nt < 2; ++nt){
      short8 b = *(const short8*)(B1 + (nt*16 + l15)*72 + kk + quad*8);
      au[0][nt] = __builtin_amdgcn_mfma_f32_16x16x32_bf16(a0, b, au[0][nt], 0, 0, 0);
      au[1][nt] = __builtin_amdgcn_mfma_f32_16x16x32_bf16(a1, b, au[1][nt], 0, 0, 0);
    }
  }
  #pragma unroll
  for (int mt = 0; mt < 2; ++mt)
    #pragma unroll
    for (int nt = 0; nt < 2; ++nt)
      #pragma unroll
      for (int reg = 0; reg < 4; ++reg){
        int r = wave*32 + mt*16 + quad*4 + reg;
        int c = nt*16 + l15;
        float uval = au[mt][nt][reg] + UB[r*32 + c];
        A2[r*40 + c] = f2b(siluf(uval));
      }
  __syncthreads();
  // eg = A2 @ B2 (M=128 N=32 K=32)
  floatx4 ae[2][2];
  #pragma unroll
  for (int mt = 0; mt < 2; ++mt)
    #pragma unroll
    for (int nt = 0; nt < 2; ++nt) ae[mt][nt] = (floatx4){0.f,0.f,0.f,0.f};
  {
    short8 a0 = *(const short8*)(A2 + (wave*32 + l15)*40 + quad*8);
    short8 a1 = *(const short8*)(A2 + (wave*32 + 16 + l15)*40 + quad*8);
    #pragma unroll
    for (int nt = 0; nt < 2; ++nt){
      short8 b = *(const short8*)(B2 + (nt*16 + l15)*40 + quad*8);
      ae[0][nt] = __builtin_amdgcn_mfma_f32_16x16x32_bf16(a0, b, ae[0][nt], 0, 0, 0);
      ae[1][nt] = __builtin_amdgcn_mfma_f32_16x16x32_bf16(a1, b, ae[1][nt], 0, 0, 0);
    }
  }
  __syncthreads();    // all A2 (silu-u) reads done before overwrite with eg
  #pragma unroll
  for (int mt = 0; mt < 2; ++mt)
    #pragma unroll
    for (int nt = 0; nt < 2; ++nt)
      #pragma unroll
      for (int reg = 0; reg < 4; ++reg){
        int r = wave*32 + mt*16 + quad*4 + reg;
        int c = nt*16 + l15;
        float ev = ae[mt][nt][reg] + Wf[OFF_BE2 + c];
        A2[r*40 + c] = f2b(ev);
      }
  __syncthreads();
  // edge copy-out (coalesced)
  {
    int r = tid >> 1, p = tid & 1;
    const uint4* srcp = (const uint4*)(A2 + r*40 + p*16);
    uint4* dstp = (uint4*)(edge + (size_t)(row0 + r)*32 + p*16);
    dstp[0] = srcp[0]; dstp[1] = srcp[1];
  }
  // logits = celu(A2 @ B3 + batt)  (N=16, 7 used)
  floatx4 al_[2];
  al_[0] = (floatx4){0.f,0.f,0.f,0.f};
  al_[1] = (floatx4){0.f,0.f,0.f,0.f};
  {
    short8 a0 = *(const short8*)(A2 + (wave*32 + l15)*40 + quad*8);
    short8 a1 = *(const short8*)(A2 + (wave*32 + 16 + l15)*40 + quad*8);
    short8 b = *(const short8*)(B3 + l15*40 + quad*8);
    al_[0] = __builtin_amdgcn_mfma_f32_16x16x32_bf16(a0, b, al_[0], 0, 0, 0);
    al_[1] = __builtin_amdgcn_mfma_f32_16x16x32_bf16(a1, b, al_[1], 0, 0, 0);
  }
  if (l15 < 7){
    float ba = Wf[OFF_BATT + l15];
    #pragma unroll
    for (int mt = 0; mt < 2; ++mt)
      #pragma unroll
      for (int reg = 0; reg < 4; ++reg){
        int r = wave*32 + mt*16 + quad*4 + reg;
        float vv = al_[mt][reg] + ba;
        float cl = vv > 0.f ? vv : 2.f * expm1f(0.5f * vv);
        logits[(size_t)(row0 + r)*7 + l15] = cl;
      }
  }
}

// -------- segment softmax + hsem accumulation (16-lane group per atom) ------
__global__ __launch_bounds__(256) void k_att(const int* __restrict__ offs,
    const float* __restrict__ logits, const u16* __restrict__ edge,
    float* __restrict__ atts, float* __restrict__ hsem){
  int a = blockIdx.x * 16 + (threadIdx.x >> 4);   // N = 625*16
  int lane = threadIdx.x & 15;
  int off = offs[a], end = offs[a+1];
  float m[7];
  #pragma unroll
  for (int hh = 0; hh < 7; ++hh) m[hh] = -1e30f;
  for (int s = off + lane; s < end; s += 16){
    #pragma unroll
    for (int hh = 0; hh < 7; ++hh) m[hh] = fmaxf(m[hh], logits[s*7+hh]);
  }
  #pragma unroll
  for (int hh = 0; hh < 7; ++hh){
    float v = m[hh];
    #pragma unroll
    for (int msk = 8; msk >= 1; msk >>= 1) v = fmaxf(v, __shfl_xor(v, msk));
    m[hh] = v;
  }
  float sm[7] = {0,0,0,0,0,0,0};
  for (int s = off + lane; s < end; s += 16){
    #pragma unroll
    for (int hh = 0; hh < 7; ++hh){
      float e = __expf(logits[s*7+hh] - m[hh]);
      sm[hh] += e;
      atts[s*7+hh] = e;
    }
  }
  #pragma unroll
  for (int hh = 0; hh < 7; ++hh){
    float v = sm[hh];
    #pragma unroll
    for (int msk = 8; msk >= 1; msk >>= 1) v += __shfl_xor(v, msk);
    sm[hh] = 1.f / v;
  }
  for (int s = off + lane; s < end; s += 16){
    #pragma unroll
    for (int hh = 0; hh < 7; ++hh) atts[s*7+hh] *= sm[hh];
  }
  __syncthreads();
  float acc[14] = {0,0,0,0,0,0,0,0,0,0,0,0,0,0};
  for (int s = off; s < end; ++s){
    u32 ev = *(const u32*)(edge + (size_t)s * 32 + lane * 2);
    float e0 = b2f((u16)(ev & 0xFFFFu));
    float e1 = b2f((u16)(ev >> 16));
    const float* ap = atts + (size_t)s * 7;
    #pragma unroll
    for (int hh = 0; hh < 7; ++hh){
      float at = ap[hh];
      acc[hh]     += e0 * at;
      acc[7 + hh] += e1 * at;
    }
  }
  float* hp = hsem + (size_t)a * 224 + lane * 14;
  #pragma unroll
  for (int jj = 0; jj < 14; ++jj) hp[jj] = acc[jj];
}

// -------- MFMA GEMM, M=64 tile, half-width (112 cols), 38.7KB LDS -----------
// mode >= 0: single half (grid 2500, row0 = bid*64), writes xh0/xh1 by half.
// mode <  0: both halves (grid 5000, half = bid&1, row0 = (bid>>1)*64) — pairs
//            of consecutive blocks share edge/atts rows (L2 reuse).
#define G_BS   29696
#define G_EL   29696
#define G_AL   (29696 + 4608)
#define G_TOT  38656

__global__ __launch_bounds__(256, 4) void k_gemm3(const u16* __restrict__ edge,
    const float* __restrict__ atts, const u16* __restrict__ BT,
    u16* __restrict__ xh0, u16* __restrict__ xh1, int mode){
  __shared__ __attribute__((aligned(16))) char smem[G_TOT];
  u16*   As  = (u16*)smem;                 // stride 232 u16 (116 u32)
  u16*   xth = (u16*)smem;                 // stride 120 u16, overlays As after MFMA
  u16*   Bs  = (u16*)(smem + G_BS);        // stride 40 u16
  u16*   eL  = (u16*)(smem + G_EL);        // stride 36 u16 (overlay, dead after pack)
  float* aL  = (float*)(smem + G_AL);      // stride 7 floats (overlay)
  int tid = threadIdx.x;
  int wave = tid >> 6, lane = tid & 63, l15 = lane & 15, quad = lane >> 4;
  int bid = blockIdx.x;
  int half, rblk;
  if (mode < 0){ half = bid & 1; rblk = bid >> 1; }
  else         { half = mode;    rblk = bid; }
  u16* xhalf = half ? xh1 : xh0;
  int row0 = rblk * 64;
  int nbase = half * 112;

  // stage edge rows (padded stride 36) + atts
  for (int e = tid; e < 512; e += 256){
    int r = e >> 3, q = e & 7;
    *(uint2*)(eL + r*36 + q*4) = *(const uint2*)(edge + (size_t)(row0 + r)*32 + q*4);
  }
  for (int e = tid; e < 448; e += 256) aL[e] = atts[(size_t)row0*7 + e];
  floatx4 acc[7];
  #pragma unroll
  for (int nt = 0; nt < 7; ++nt) acc[nt] = (floatx4){0.f, 0.f, 0.f, 0.f};
  __syncthreads();

  // pack full-K A-tile once: thread t -> row t>>2, quarter (t&3)*56 cols
  {
    int pr = tid >> 2, q = tid & 3;
    u32* asw = (u32*)As + pr*116 + q*28;
    const u16* er = eL + pr*36 + q*8;
    const float* ar = aL + pr*7;
    float av[7];
    #pragma unroll
    for (int hh = 0; hh < 7; ++hh) av[hh] = ar[hh];
    #pragma unroll
    for (int fo2 = 0; fo2 < 4; ++fo2){
      float e0 = b2f(er[2*fo2]);
      float e1 = b2f(er[2*fo2+1]);
      u16 w[14];
      #pragma unroll
      for (int hh = 0; hh < 7; ++hh){
        w[hh]   = f2b(e0 * av[hh]);
        w[7+hh] = f2b(e1 * av[hh]);
      }
      #pragma unroll
      for (int k = 0; k < 7; ++k)
        asw[fo2*7 + k] = (u32)w[2*k] | ((u32)w[2*k+1] << 16);
    }
  }
  __syncthreads();          // As ready; eL/aL dead -> Bs usable

  for (int kt = 0; kt < 7; ++kt){
    for (int e = tid; e < 448; e += 256){
      int r = e >> 2, q = e & 3;
      *(uint4*)(Bs + r*40 + q*8) = *(const uint4*)(BT + (size_t)(nbase + r)*224 + kt*32 + q*8);
    }
    __syncthreads();
    int kk = kt * 32;
    short8 a0 = *(const short8*)(As + (wave*16 + l15)*232 + kk + quad*8);
    #pragma unroll
    for (int nt = 0; nt < 7; ++nt){
      short8 b = *(const short8*)(Bs + (nt*16 + l15)*40 + quad*8);
      acc[nt] = __builtin_amdgcn_mfma_f32_16x16x32_bf16(a0, b, acc[nt], 0, 0, 0);
    }
    __syncthreads();        // MFMA reads done before next stage overwrites Bs
  }

  // tanh epilogue -> xth (stride 120), wave-local rows
  #pragma unroll
  for (int nt = 0; nt < 7; ++nt)
    #pragma unroll
    for (int reg = 0; reg < 4; ++reg){
      int r = wave*16 + quad*4 + reg;
      int c = nt*16 + l15;
      float vv = acc[nt][reg];
      vv = fminf(fmaxf(vv, -15.f), 15.f);
      float e2 = __expf(2.f * vv);
      xth[r*120 + c] = f2b((e2 - 1.f) / (e2 + 1.f));
    }
  __syncthreads();
  for (int e = tid; e < 896; e += 256){
    int r = e / 14, w = e - r * 14;
    *(uint4*)(xhalf + (size_t)(row0 + r)*112 + w*8) = *(const uint4*)(xth + r*120 + w*8);
  }
}

// -------- atom-centric comb reduction (fallback path) -----------------------
__global__ __launch_bounds__(256) void k_comb(const int* __restrict__ offs,
    const u16* __restrict__ xhalf, const float* __restrict__ dirs,
    const float* __restrict__ Wf, int half,
    float* __restrict__ nsq, float* __restrict__ pvh){
  int a = blockIdx.x * 16 + (threadIdx.x >> 4);
  int lane = threadIdx.x & 15;
  int off = offs[a], end = offs[a+1];
  float c0[7] = {0,0,0,0,0,0,0}, c1[7] = {0,0,0,0,0,0,0}, c2[7] = {0,0,0,0,0,0,0};
  for (int s = off; s < end; ++s){
    float d0 = dirs[s*3+0], d1 = dirs[s*3+1], d2 = dirs[s*3+2];
    const u16* xr = xhalf + (size_t)s * 112 + lane;
    #pragma unroll
    for (int k = 0; k < 7; ++k){
      float xm = b2f(xr[k*16]);
      c0[k] += d0 * xm; c1[k] += d1 * xm; c2[k] += d2 * xm;
    }
  }
  float inv = 1.f / fmaxf((float)(end - off), 1.f);
  float pv0 = 0.f, pv1 = 0.f, pv2 = 0.f;
  #pragma unroll
  for (int k = 0; k < 7; ++k){
    float m0 = c0[k]*inv, m1 = c1[k]*inv, m2 = c2[k]*inv;
    int c = half*112 + k*16 + lane;
    nsq[(size_t)a*224 + c] = m0*m0 + m1*m1 + m2*m2;
    float wv = Wf[OFF_WVMIX + c];
    pv0 += wv*m0; pv1 += wv*m1; pv2 += wv*m2;
  }
  #pragma unroll
  for (int m = 8; m >= 1; m >>= 1){
    pv0 += __shfl_xor(pv0, m); pv1 += __shfl_xor(pv1, m); pv2 += __shfl_xor(pv2, m);
  }
  if (lane == 0){
    float* pp = pvh + (size_t)half*30000 + (size_t)a*3;
    pp[0] = pv0; pp[1] = pv1; pp[2] = pv2;
  }
}

// ------- final (fallback path): 16 atoms/block, 2 atoms/thread --------------
__global__ __launch_bounds__(256) void k_final4(const float* __restrict__ h,
    const float* __restrict__ x, const float* __restrict__ v,
    const float* __restrict__ Wf, const float* __restrict__ hsem,
    const float* __restrict__ nsq, const float* __restrict__ pvh,
    float* __restrict__ out){
  __shared__ float s_nsq[16][225];
  __shared__ float s_in[16][289];
  __shared__ float s_u1[16][33];
  __shared__ float s_un[16][33];
  __shared__ float s_sc[16];
  int tid = threadIdx.x;
  int a0 = blockIdx.x * 16;
  for (int e = tid; e < 896; e += 256){
    int a = e / 56, q = e - a * 56;
    float4 t = *(const float4*)(nsq + (size_t)(a0 + a) * 224 + q * 4);
    s_nsq[a][q*4+0] = t.x; s_nsq[a][q*4+1] = t.y;
    s_nsq[a][q*4+2] = t.z; s_nsq[a][q*4+3] = t.w;
  }
  for (int e = tid; e < 896; e += 256){
    int a = e / 56, q = e - a * 56;
    float4 t = *(const float4*)(hsem + (size_t)(a0 + a) * 224 + q * 4);
    s_in[a][32 + q*4+0] = t.x; s_in[a][32 + q*4+1] = t.y;
    s_in[a][32 + q*4+2] = t.z; s_in[a][32 + q*4+3] = t.w;
  }
  for (int e = tid; e < 128; e += 256){
    int a = e >> 3, q = e & 7;
    float4 t = *(const float4*)(h + (size_t)(a0 + a) * 32 + q * 4);
    s_in[a][q*4+0] = t.x; s_in[a][q*4+1] = t.y;
    s_in[a][q*4+2] = t.z; s_in[a][q*4+3] = t.w;
  }
  __syncthreads();
  int o = tid & 31, g5 = tid >> 5;
  int aA = g5, aB = g5 + 8;
  {
    float uA = Wf[OFF_BP1 + o], uB = uA;
    const float* w = Wf + OFF_WP1 + o;
    #pragma unroll 8
    for (int kk = 0; kk < 224; ++kk){
      float wv = w[kk*32];
      uA += s_nsq[aA][kk] * wv;
      uB += s_nsq[aB][kk] * wv;
    }
    s_u1[aA][o] = siluf(uA);
    s_u1[aB][o] = siluf(uB);
  }
  {
    float gA = Wf[OFF_BV1 + o], gB = gA;
    const float* w = Wf + OFF_WV1 + o;
    #pragma unroll
    for (int kk = 0; kk < 32; ++kk){
      float wv = w[kk*32];
      gA += s_in[aA][kk] * wv;
      gB += s_in[aB][kk] * wv;
    }
    float wv2 = Wf[OFF_WV2 + o];
    float zA = siluf(gA) * wv2, zB = siluf(gB) * wv2;
    #pragma unroll
    for (int m = 16; m >= 1; m >>= 1){
      zA += __shfl_xor(zA, m); zB += __shfl_xor(zB, m);
    }
    if (o == 0){
      s_sc[aA] = 2.f / (1.f + __expf(-zA));
      s_sc[aB] = 2.f / (1.f + __expf(-zB));
    }
  }
  __syncthreads();
  {
    float uA = Wf[OFF_BP2 + o], uB = uA;
    const float* w = Wf + OFF_WP2 + o;
    #pragma unroll
    for (int kk = 0; kk < 32; ++kk){
      float wv = w[kk*32];
      uA += s_u1[aA][kk] * wv;
      uB += s_u1[aB][kk] * wv;
    }
    s_in[aA][256 + o] = siluf(uA);
    s_in[aB][256 + o] = siluf(uB);
  }
  __syncthreads();
  {
    float uA = Wf[OFF_BN1 + o], uB = uA;
    const float* w = Wf + OFF_WN1 + o;
    #pragma unroll 8
    for (int kk = 0; kk < 288; ++kk){
      float wv = w[kk*32];
      uA += s_in[aA][kk] * wv;
      uB += s_in[aB][kk] * wv;
    }
    s_un[aA][o] = siluf(uA);
    s_un[aB][o] = siluf(uB);
  }
  __syncthreads();
  {
    float uA = Wf[OFF_BN2 + o], uB = uA;
    const float* w = Wf + OFF_WN2 + o;
    #pragma unroll
    for (int kk = 0; kk < 32; ++kk){
      float wv = w[kk*32];
      uA += s_un[aA][kk] * wv;
      uB += s_un[aB][kk] * wv;
    }
    out[(size_t)(a0 + aA)*32 + o] = s_in[aA][o] + siluf(uA);
    out[(size_t)(a0 + aB)*32 + o] = s_in[aB][o] + siluf(uB);
  }
  if (tid < 48){
    int a = tid / 3, c = tid - a * 3;
    int ga = a0 + a;
    float pv = pvh[(size_t)ga*3 + c] + pvh[30000 + (size_t)ga*3 + c];
    float vup = s_sc[a] * v[ga*3 + c] + pv;
    float xup = x[ga*3 + c] + vup;
    out[N_ATOMS*32 + (size_t)ga*3 + c] = xup;
    out[N_ATOMS*32 + N_ATOMS*3 + (size_t)ga*3 + c] = vup;
  }
}

// ------- fused comb(both halves) + final (fast path) ------------------------
// 625 blocks x 256 threads; comb phase: thread = (atom a=tid>>4, lane=tid&15).
__global__ __launch_bounds__(256) void k_combf(const int* __restrict__ offs,
    const u16* __restrict__ xh0, const u16* __restrict__ xh1,
    const float* __restrict__ dirs, const float* __restrict__ h,
    const float* __restrict__ x, const float* __restrict__ v,
    const float* __restrict__ Wf, const float* __restrict__ hsem,
    float* __restrict__ out){
  __shared__ float s_nsq[16][225];
  __shared__ float s_in[16][289];
  __shared__ float s_u1[16][33];
  __shared__ float s_un[16][33];
  __shared__ float s_sc[16];
  __shared__ float s_pv[16][3];
  int tid = threadIdx.x;
  int a0 = blockIdx.x * 16;
  // stage h/hsem (independent of comb)
  for (int e = tid; e < 896; e += 256){
    int a = e / 56, q = e - a * 56;
    float4 t = *(const float4*)(hsem + (size_t)(a0 + a) * 224 + q * 4);
    s_in[a][32 + q*4+0] = t.x; s_in[a][32 + q*4+1] = t.y;
    s_in[a][32 + q*4+2] = t.z; s_in[a][32 + q*4+3] = t.w;
  }
  for (int e = tid; e < 128; e += 256){
    int a = e >> 3, q = e & 7;
    float4 t = *(const float4*)(h + (size_t)(a0 + a) * 32 + q * 4);
    s_in[a][q*4+0] = t.x; s_in[a][q*4+1] = t.y;
    s_in[a][q*4+2] = t.z; s_in[a][q*4+3] = t.w;
  }
  // comb phase: both halves
  {
    int a = tid >> 4, lane = tid & 15;
    int off = offs[a0 + a], end = offs[a0 + a + 1];
    float c0A[7] = {0,0,0,0,0,0,0}, c1A[7] = {0,0,0,0,0,0,0}, c2A[7] = {0,0,0,0,0,0,0};
    float c0B[7] = {0,0,0,0,0,0,0}, c1B[7] = {0,0,0,0,0,0,0}, c2B[7] = {0,0,0,0,0,0,0};
    for (int s = off; s < end; ++s){
      float d0 = dirs[s*3+0], d1 = dirs[s*3+1], d2 = dirs[s*3+2];
      const u16* xra = xh0 + (size_t)s * 112 + lane;
      const u16* xrb = xh1 + (size_t)s * 112 + lane;
      #pragma unroll
      for (int k = 0; k < 7; ++k){
        float xa = b2f(xra[k*16]);
        float xb = b2f(xrb[k*16]);
        c0A[k] += d0 * xa; c1A[k] += d1 * xa; c2A[k] += d2 * xa;
        c0B[k] += d0 * xb; c1B[k] += d1 * xb; c2B[k] += d2 * xb;
      }
    }
    float inv = 1.f / fmaxf((float)(end - off), 1.f);
    float pv0 = 0.f, pv1 = 0.f, pv2 = 0.f;
    #pragma unroll
    for (int k = 0; k < 7; ++k){
      {
        float m0 = c0A[k]*inv, m1 = c1A[k]*inv, m2 = c2A[k]*inv;
        int c = k*16 + lane;
        s_nsq[a][c] = m0*m0 + m1*m1 + m2*m2;
        float wv = Wf[OFF_WVMIX + c];
        pv0 += wv*m0; pv1 += wv*m1; pv2 += wv*m2;
      }
      {
        float m0 = c0B[k]*inv, m1 = c1B[k]*inv, m2 = c2B[k]*inv;
        int c = 112 + k*16 + lane;
        s_nsq[a][c] = m0*m0 + m1*m1 + m2*m2;
        float wv = Wf[OFF_WVMIX + c];
        pv0 += wv*m0; pv1 += wv*m1; pv2 += wv*m2;
      }
    }
    #pragma unroll
    for (int m = 8; m >= 1; m >>= 1){
      pv0 += __shfl_xor(pv0, m); pv1 += __shfl_xor(pv1, m); pv2 += __shfl_xor(pv2, m);
    }
    if (lane == 0){ s_pv[a][0] = pv0; s_pv[a][1] = pv1; s_pv[a][2] = pv2; }
  }
  __syncthreads();
  int o = tid & 31, g5 = tid >> 5;
  int aA = g5, aB = g5 + 8;
  {
    float uA = Wf[OFF_BP1 + o], uB = uA;
    const float* w = Wf + OFF_WP1 + o;
    #pragma unroll 8
    for (int kk = 0; kk < 224; ++kk){
      float wv = w[kk*32];
      uA += s_nsq[aA][kk] * wv;
      uB += s_nsq[aB][kk] * wv;
    }
    s_u1[aA][o] = siluf(uA);
    s_u1[aB][o] = siluf(uB);
  }
  {
    float gA = Wf[OFF_BV1 + o], gB = gA;
    const float* w = Wf + OFF_WV1 + o;
    #pragma unroll
    for (int kk = 0; kk < 32; ++kk){
      float wv = w[kk*32];
      gA += s_in[aA][kk] * wv;
      gB += s_in[aB][kk] * wv;
    }
    float wv2 = Wf[OFF_WV2 + o];
    float zA = siluf(gA) * wv2, zB = siluf(gB) * wv2;
    #pragma unroll
    for (int m = 16; m >= 1; m >>= 1){
      zA += __shfl_xor(zA, m); zB += __shfl_xor(zB, m);
    }
    if (o == 0){
      s_sc[aA] = 2.f / (1.f + __expf(-zA));
      s_sc[aB] = 2.f / (1.f + __expf(-zB));
    }
  }
  __syncthreads();
  {
    float uA = Wf[OFF_BP2 + o], uB = uA;
    const float* w = Wf + OFF_WP2 + o;
    #pragma unroll
    for (int kk = 0; kk < 32; ++kk){
      float wv = w[kk*32];
      uA += s_u1[aA][kk] * wv;
      uB += s_u1[aB][kk] * wv;
    }
    s_in[aA][256 + o] = siluf(uA);
    s_in[aB][256 + o] = siluf(uB);
  }
  __syncthreads();
  {
    float uA = Wf[OFF_BN1 + o], uB = uA;
    const float* w = Wf + OFF_WN1 + o;
    #pragma unroll 8
    for (int kk = 0; kk < 288; ++kk){
      float wv = w[kk*32];
      uA += s_in[aA][kk] * wv;
      uB += s_in[aB][kk] * wv;
    }
    s_un[aA][o] = siluf(uA);
    s_un[aB][o] = siluf(uB);
  }
  __syncthreads();
  {
    float uA = Wf[OFF_BN2 + o], uB = uA;
    const float* w = Wf + OFF_WN2 + o;
    #pragma unroll
    for (int kk = 0; kk < 32; ++kk){
      float wv = w[kk*32];
      uA += s_un[aA][kk] * wv;
      uB += s_un[aB][kk] * wv;
    }
    out[(size_t)(a0 + aA)*32 + o] = s_in[aA][o] + siluf(uA);
    out[(size_t)(a0 + aB)*32 + o] = s_in[aB][o] + siluf(uB);
  }
  if (tid < 48){
    int a = tid / 3, c = tid - a * 3;
    int ga = a0 + a;
    float vup = s_sc[a] * v[ga*3 + c] + s_pv[a][c];
    float xup = x[ga*3 + c] + vup;
    out[N_ATOMS*32 + (size_t)ga*3 + c] = xup;
    out[N_ATOMS*32 + N_ATOMS*3 + (size_t)ga*3 + c] = vup;
  }
}

// ---------------- workspace layout ----------------
static constexpr size_t al256(size_t x){ return (x + 255) & ~(size_t)255; }
static constexpr size_t WS_FLAGS   = 0;
static constexpr size_t WS_COUNTS  = al256(WS_FLAGS + 8);
static constexpr size_t WS_OFFSETS = al256(WS_COUNTS + (size_t)N_ATOMS * 4);
static constexpr size_t WS_CURSOR  = al256(WS_OFFSETS + (size_t)(N_ATOMS + 1) * 4);
static constexpr size_t WS_PERM    = al256(WS_CURSOR + (size_t)N_ATOMS * 4);   // isrt
static constexpr size_t WS_PLI     = al256(WS_PERM + (size_t)P_PAIRS * 4);
static constexpr size_t WS_HF      = al256(WS_PLI + (size_t)2 * P_PAIRS * 4);
static constexpr size_t WS_XF      = al256(WS_HF + (size_t)N_ATOMS * 32 * 4);
static constexpr size_t WS_VF      = al256(WS_XF + (size_t)N_ATOMS * 3 * 4);
static constexpr size_t WS_WF      = al256(WS_VF + (size_t)N_ATOMS * 3 * 4);
static constexpr size_t WS_WT      = al256(WS_WF + (size_t)WF_TOTAL * 4);
static constexpr size_t WS_EDGE    = al256(WS_WT + (size_t)224 * 224 * 2);
static constexpr size_t WS_ATTS    = al256(WS_EDGE + (size_t)P_PAIRS * 32 * 2);
static constexpr size_t WS_DIRS    = al256(WS_ATTS + (size_t)P_PAIRS * 7 * 4);
static constexpr size_t WS_LOGITS  = al256(WS_DIRS + (size_t)P_PAIRS * 3 * 4);
// SMALL (fallback, round-10-proven) layout:
static constexpr size_t WS_PREI    = al256(WS_LOGITS + (size_t)P_PAIRS * 7 * 4);
static constexpr size_t WS_PREJ    = al256(WS_PREI + (size_t)N_ATOMS * 88 * 2);
static constexpr size_t WS_HSEM    = WS_LOGITS + 4480000;
static constexpr size_t WS_XH      = WS_HSEM + (size_t)N_ATOMS * 224 * 4;
static constexpr size_t WS_NSQ     = WS_XH + (size_t)P_PAIRS * 112 * 2;
static constexpr size_t WS_PVH     = WS_NSQ + (size_t)N_ATOMS * 224 * 4;
static constexpr size_t WS_JSRT    = al256(WS_PVH + (size_t)2 * 30000 * 4);
static constexpr size_t WS_BPK     = al256(WS_JSRT + (size_t)P_PAIRS * 4);
static constexpr size_t WS_END     = WS_BPK + 3584 * 2;
// BIG (fast path) layout: two xhalf buffers, no nsq/pvh.
static constexpr size_t WB_XH0     = WS_XH;                                     // reuse
static constexpr size_t WB_XH1     = WB_XH0 + (size_t)P_PAIRS * 112 * 2;
static constexpr size_t WB_JSRT    = al256(WB_XH1 + (size_t)P_PAIRS * 112 * 2);
static constexpr size_t WB_BPK     = al256(WB_JSRT + (size_t)P_PAIRS * 4);
static constexpr size_t WB_END     = WB_BPK + 3584 * 2;
static_assert(WS_PREJ + (size_t)N_ATOMS * 88 * 2 <= WS_XH, "pre tables before xhalf");
static_assert(WS_END <= WS_LOGITS + (size_t)P_PAIRS * 224 * 2, "fallback within proven footprint");
static_assert(WS_HSEM % 256 == 0 && WS_XH % 256 == 0 && WS_NSQ % 256 == 0 && WS_PVH % 256 == 0, "alignment");
static_assert(WB_XH1 % 256 == 0, "alignment");

extern "C" void kernel_launch(void* const* d_in, const int* in_sizes, int n_in,
                              void* d_out, int out_size, void* d_ws, size_t ws_size,
                              hipStream_t stream){
  (void)in_sizes; (void)n_in;
  if (out_size != 380000 || ws_size < WS_END){
    k_code<<<1, 64, 0, stream>>>((float*)d_out, 14000.f);
    return;
  }
  char* ws = (char*)d_ws;
  int*   counts = (int*)(ws + WS_COUNTS);
  int*   offs   = (int*)(ws + WS_OFFSETS);
  int*   cursor = (int*)(ws + WS_CURSOR);
  int*   isrt   = (int*)(ws + WS_PERM);
  int*   pli    = (int*)(ws + WS_PLI);
  float* hf     = (float*)(ws + WS_HF);
  float* xf     = (float*)(ws + WS_XF);
  float* vf     = (float*)(ws + WS_VF);
  float* Wf     = (float*)(ws + WS_WF);
  u16*   wT     = (u16*)(ws + WS_WT);
  u16*   edge   = (u16*)(ws + WS_EDGE);
  float* atts   = (float*)(ws + WS_ATTS);
  float* dirs   = (float*)(ws + WS_DIRS);
  float* logits = (float*)(ws + WS_LOGITS);
  u16*   prei   = (u16*)(ws + WS_PREI);
  u16*   prej   = (u16*)(ws + WS_PREJ);
  float* hsem   = (float*)(ws + WS_HSEM);

  bool big = (ws_size >= WB_END);
  u16*   xh0  = (u16*)(ws + WB_XH0);
  u16*   xh1  = big ? (u16*)(ws + WB_XH1) : xh0;
  int*   jsrt = big ? (int*)(ws + WB_JSRT) : (int*)(ws + WS_JSRT);
  u16*   bpk  = big ? (u16*)(ws + WB_BPK) : (u16*)(ws + WS_BPK);
  float* nsq  = (float*)(ws + WS_NSQ);
  float* pvh  = (float*)(ws + WS_PVH);

  hipMemsetAsync(counts, 0, (size_t)N_ATOMS * 4, stream);
  k_prep<<<NBP_HIST, 256, 0, stream>>>(d_in[0], d_in[1], d_in[2], d_in[3],
      d_in[4],  d_in[5],  d_in[6],  d_in[7],  d_in[8],  d_in[9],  d_in[10], d_in[11],
      d_in[12], d_in[13], d_in[14], d_in[15], d_in[16], d_in[17], d_in[18], d_in[19],
      d_in[20], d_in[21], d_in[22], d_in[24], d_in[23],
      hf, xf, vf, pli, Wf, wT, bpk, counts);
  k_atomscan<<<626, 256, 0, stream>>>(hf, Wf, prei, prej, counts, offs, cursor);
  k_scatter<<<P_PAIRS / 256, 256, 0, stream>>>(pli, cursor, isrt, jsrt);
  k_pairm<<<P_PAIRS / 128, 256, 0, stream>>>(xf, Wf, prei, prej, isrt, jsrt, bpk, edge, logits, dirs);
  k_att<<<N_ATOMS / 16, 256, 0, stream>>>(offs, logits, edge, atts, hsem);
  if (big){
    k_gemm3<<<2 * (P_PAIRS / 64), 256, 0, stream>>>(edge, atts, wT, xh0, xh1, -1);
    k_combf<<<625, 256, 0, stream>>>(offs, xh0, xh1, dirs, hf, xf, vf, Wf, hsem, (float*)d_out);
  } else {
    k_gemm3<<<P_PAIRS / 64, 256, 0, stream>>>(edge, atts, wT, xh0, xh0, 0);
    k_comb<<<N_ATOMS / 16, 256, 0, stream>>>(offs, xh0, dirs, Wf, 0, nsq, pvh);
    k_gemm3<<<P_PAIRS / 64, 256, 0, stream>>>(edge, atts, wT, xh0, xh0, 1);
    k_comb<<<N_ATOMS / 16, 256, 0, stream>>>(offs, xh0, dirs, Wf, 1, nsq, pvh);
    k_final4<<<625, 256, 0, stream>>>(hf, xf, vf, Wf, hsem, nsq, pvh, (float*)d_out);
  }
}